// Round 2
// baseline (1951.846 us; speedup 1.0000x reference)
//
#include <hip/hip_runtime.h>
#include <cstdint>
#include <cstddef>

namespace {

constexpr int B_ = 4, NC_ = 4095, N_ = 4096, DIN_ = 64, D_ = 128, H_ = 4, K_ = 6;
constexpr int DH_ = 32, HR_ = 16, NRBF_ = 16;
constexpr int XROW_ = 6 + DIN_;   // 70
constexpr int ROWS_ = B_ * N_;    // 16384

__device__ __forceinline__ float sigm(float x) { return 1.f / (1.f + expf(-x)); }
__device__ __forceinline__ float silu(float x) { return x / (1.f + expf(-x)); }

// ---------------- pos build: pos[b,0]=0, pos[b,n]=X[b,n-1,0:3] ----------------
__global__ void k_prep(const float* __restrict__ X, float* __restrict__ pos)
{
    int g = blockIdx.x * 256 + threadIdx.x;
    if (g >= ROWS_) return;
    int b = g >> 12, n = g & (N_ - 1);
    float px = 0.f, py = 0.f, pz = 0.f;
    if (n > 0) {
        const float* xr = X + (size_t)(b * NC_ + n - 1) * XROW_;
        px = xr[0]; py = xr[1]; pz = xr[2];
    }
    pos[g * 3 + 0] = px; pos[g * 3 + 1] = py; pos[g * 3 + 2] = pz;
}

// ---------------- embed: x0 = feats @ W_embed + b_embed ----------------
__global__ void k_embed(const float* __restrict__ X, const float* __restrict__ W,
                        const float* __restrict__ bias, float* __restrict__ x0)
{
    int g = blockIdx.x * 256 + threadIdx.x;
    if (g >= ROWS_ * D_) return;
    int c = g & (D_ - 1);
    int row = g >> 7;
    int b = row >> 12, n = row & (N_ - 1);
    float a = bias[c];
    if (n > 0) {
        const float* xr = X + (size_t)(b * NC_ + n - 1) * XROW_ + 6;
        for (int k = 0; k < DIN_; ++k) a += xr[k] * W[k * D_ + c];
    }
    x0[g] = a;
}

// ---------------- KNN: one wave per query, top-6 by (d2,idx) ----------------
__device__ __forceinline__ unsigned long long shflxor64(unsigned long long v, int mask)
{
    int lo = __shfl_xor((int)(unsigned)(v & 0xffffffffull), mask, 64);
    int hi = __shfl_xor((int)(unsigned)(v >> 32), mask, 64);
    return ((unsigned long long)(unsigned)hi << 32) | (unsigned)lo;
}

__global__ __launch_bounds__(256) void k_knn(const float* __restrict__ pos, int* __restrict__ idxv)
{
    const int wave = (blockIdx.x << 2) | (threadIdx.x >> 6);
    const int lane = threadIdx.x & 63;
    const int b = wave >> 12, i = wave & (N_ - 1);
    const float* pb = pos + (size_t)b * N_ * 3;
    const float qx = pb[i * 3], qy = pb[i * 3 + 1], qz = pb[i * 3 + 2];

    unsigned long long a0 = ~0ull, a1 = ~0ull, a2 = ~0ull, a3 = ~0ull, a4 = ~0ull, a5 = ~0ull;
    for (int j = lane; j < N_; j += 64) {
        if (j == i) continue;
        float dx = pb[j * 3] - qx, dy = pb[j * 3 + 1] - qy, dz = pb[j * 3 + 2] - qz;
        float d2 = dx * dx + dy * dy + dz * dz;
        unsigned long long key = ((unsigned long long)__float_as_uint(d2) << 32) | (unsigned)j;
        if (key < a5) {
            a5 = key;
            unsigned long long t;
            if (a5 < a4) { t = a5; a5 = a4; a4 = t; }
            if (a4 < a3) { t = a4; a4 = a3; a3 = t; }
            if (a3 < a2) { t = a3; a3 = a2; a2 = t; }
            if (a2 < a1) { t = a2; a2 = a1; a1 = t; }
            if (a1 < a0) { t = a1; a1 = a0; a0 = t; }
        }
    }
    #pragma unroll
    for (int k = 0; k < K_; ++k) {
        unsigned long long m = a0;
        #pragma unroll
        for (int off = 1; off < 64; off <<= 1) {
            unsigned long long o = shflxor64(m, off);
            if (o < m) m = o;
        }
        if (a0 == m) { a0 = a1; a1 = a2; a2 = a3; a3 = a4; a4 = a5; a5 = ~0ull; }
        if (lane == 0) idxv[wave * K_ + k] = (int)(unsigned)(m & 0xffffffffull);
    }
}

// ---------------- geom: u, rbf per edge ----------------
__global__ void k_geom(const float* __restrict__ pos, const int* __restrict__ idxv,
                       float* __restrict__ uv, float* __restrict__ rbfv)
{
    int g = blockIdx.x * 256 + threadIdx.x;
    if (g >= ROWS_ * K_) return;
    int b = g / (N_ * K_);
    int rem = g - b * N_ * K_;
    int n = rem / K_;
    int j = idxv[g];
    const float* pb = pos + (size_t)b * N_ * 3;
    float rx = pb[j * 3] - pb[n * 3];
    float ry = pb[j * 3 + 1] - pb[n * 3 + 1];
    float rz = pb[j * 3 + 2] - pb[n * 3 + 2];
    float dist = sqrtf(rx * rx + ry * ry + rz * rz + 1e-8f);
    float inv = 1.f / dist;
    uv[g * 3 + 0] = rx * inv; uv[g * 3 + 1] = ry * inv; uv[g * 3 + 2] = rz * inv;
    for (int r = 0; r < NRBF_; ++r) {
        float t = (dist - (4.0f / 15.0f) * r) * 4.0f;  // /0.25
        rbfv[g * NRBF_ + r] = expf(-t * t);
    }
}

// ---------------- LayerNorm ----------------
__global__ __launch_bounds__(128) void k_ln(const float* __restrict__ x,
                                            const float* __restrict__ s, const float* __restrict__ bb,
                                            float* __restrict__ o)
{
    int row = blockIdx.x, tid = threadIdx.x;
    __shared__ float red[D_];
    float v = x[(size_t)row * D_ + tid];
    red[tid] = v; __syncthreads();
    for (int st = 64; st > 0; st >>= 1) { if (tid < st) red[tid] += red[tid + st]; __syncthreads(); }
    float m = red[0] * (1.f / D_);
    __syncthreads();
    float d = v - m;
    red[tid] = d * d; __syncthreads();
    for (int st = 64; st > 0; st >>= 1) { if (tid < st) red[tid] += red[tid + st]; __syncthreads(); }
    float var = red[0] * (1.f / D_);
    o[(size_t)row * D_ + tid] = d / sqrtf(var + 1e-5f) * s[tid] + bb[tid];
}

// ---------------- generic GEMM: out = act(in@W + bias) [+ out] ----------------
// ACT: 0 none, 1 silu, 2 sigmoid
template <int KD, int CD, int ACT, bool ACC, bool HASB>
__global__ __launch_bounds__(256) void k_gemm(const float* __restrict__ in, const float* __restrict__ W,
                                              const float* __restrict__ bias, float* __restrict__ out, int R)
{
    int g = blockIdx.x * 256 + threadIdx.x;
    if (g >= R * CD) return;
    int c = g % CD;
    int r = g / CD;
    const float* inr = in + (size_t)r * KD;
    float a = 0.f;
    #pragma unroll 4
    for (int k = 0; k < KD; ++k) a += inr[k] * W[k * CD + c];
    if (HASB) a += bias[c];
    if (ACT == 1) a = silu(a);
    if (ACT == 2) a = sigm(a);
    if (ACC) a += out[g];
    out[g] = a;
}

// ---------------- fused attention + x1 message ----------------
__global__ __launch_bounds__(256) void k_attn(
    const float* __restrict__ qb, const float* __restrict__ kb, const float* __restrict__ vb,
    const int* __restrict__ idxv, const float* __restrict__ rbfv, const float* __restrict__ uv,
    const float* __restrict__ x1,
    const float* __restrict__ rw1, const float* __restrict__ rb1,
    const float* __restrict__ rw2, const float* __restrict__ rb2,
    const float* __restrict__ Wvv,
    float* __restrict__ out0, float* __restrict__ out1)
{
    const int row = blockIdx.x;
    const int b = row >> 12;
    const int tid = threadIdx.x;

    __shared__ float sQ[D_], sK[K_][D_], sV[K_][D_], sRad[K_][2 * D_];
    __shared__ float sX1[K_][D_ * 3], sXw[H_][D_ * 3];
    __shared__ float sHid[K_][HR_], sLog[H_][K_], sAttn[H_][K_], sU[K_][3];
    __shared__ int sJ[K_];

    if (tid < D_) sQ[tid] = qb[(size_t)row * D_ + tid];
    if (tid < K_) sJ[tid] = idxv[row * K_ + tid];
    if (tid >= 128 && tid < 128 + K_ * 3) {
        int t = tid - 128;
        sU[t / 3][t % 3] = uv[(size_t)row * K_ * 3 + t];
    }
    __syncthreads();

    for (int t = tid; t < K_ * D_; t += 256) {
        int k = t >> 7, d = t & (D_ - 1);
        int src = (b * N_ + sJ[k]) * D_ + d;
        sK[k][d] = kb[src];
        sV[k][d] = vb[src];
    }
    for (int t = tid; t < K_ * D_ * 3; t += 256) {
        int k = t / 384, r = t - k * 384;
        sX1[k][r] = x1[(size_t)(b * N_ + sJ[k]) * 384 + r];
    }
    // edge MLP hidden
    if (tid < K_ * HR_) {
        int k = tid >> 4, hh = tid & 15;
        float a = rb1[hh];
        const float* rb = rbfv + (size_t)(row * K_ + k) * NRBF_;
        for (int r = 0; r < NRBF_; ++r) a += rb[r] * rw1[r * HR_ + hh];
        sHid[k][hh] = silu(a);
    }
    __syncthreads();
    // rad = hidden @ rw2 + rb2  (256 outputs per edge)
    for (int t = tid; t < K_ * 2 * D_; t += 256) {
        int k = t >> 8, c = t & (2 * D_ - 1);
        float a = rb2[c];
        for (int hh = 0; hh < HR_; ++hh) a += sHid[k][hh] * rw2[hh * 2 * D_ + c];
        sRad[k][c] = a;
    }
    __syncthreads();
    // logits
    if (tid < H_ * K_) {
        int h = tid / K_, k = tid - h * K_;
        float dq = 0.f, bs = 0.f;
        for (int dh = 0; dh < DH_; ++dh) {
            dq += sQ[h * DH_ + dh] * sK[k][h * DH_ + dh];
            bs += sRad[k][h * DH_ + dh];
        }
        sLog[h][k] = dq / 5.656854249492380195f + bs * (1.f / DH_);
    }
    __syncthreads();
    if (tid < H_) {
        float mx = sLog[tid][0];
        for (int k = 1; k < K_; ++k) mx = fmaxf(mx, sLog[tid][k]);
        float e[K_], sm = 0.f;
        for (int k = 0; k < K_; ++k) { e[k] = expf(sLog[tid][k] - mx); sm += e[k]; }
        for (int k = 0; k < K_; ++k) sAttn[tid][k] = e[k] / sm;
    }
    __syncthreads();
    // out0
    if (tid < D_) {
        int h = tid >> 5;
        float o = 0.f;
        for (int k = 0; k < K_; ++k) {
            float rv = sRad[k][D_ + tid];
            o += sAttn[h][k] * sV[k][tid] * silu(rv);
        }
        out0[(size_t)row * D_ + tid] = o;
    }
    // xw[h][d][c] = sum_k attn[h][k] * x1j[k][d][c]
    for (int t = tid; t < H_ * D_ * 3; t += 256) {
        int h = t / 384, r = t - h * 384;
        float a = 0.f;
        for (int k = 0; k < K_; ++k) a += sAttn[h][k] * sX1[k][r];
        sXw[h][r] = a;
    }
    __syncthreads();
    // out1[e][c] = sum_d xw[h(e)][d][c]*Wvv[d][e] + sum_k attn*rv*u
    for (int t = tid; t < D_ * 3; t += 256) {
        int e = t / 3, c = t - e * 3, h = e >> 5;
        float a = 0.f;
        for (int d = 0; d < D_; ++d) a += sXw[h][d * 3 + c] * Wvv[d * D_ + e];
        float ra = 0.f;
        for (int k = 0; k < K_; ++k) ra += sAttn[h][k] * sRad[k][D_ + e] * sU[k][c];
        out1[(size_t)row * 384 + t] = a + ra;
    }
}

// ---------------- x1 = (x1 + out1 @ Wov) * gate ----------------
__global__ __launch_bounds__(256) void k_x1up(const float* __restrict__ o1,
                                              const float* __restrict__ Wov,
                                              const float* __restrict__ gate,
                                              float* __restrict__ x1)
{
    const int row = blockIdx.x;
    const int tid = threadIdx.x;
    __shared__ float sO[D_ * 3], sG[D_];
    if (tid < D_) sG[tid] = gate[(size_t)row * D_ + tid];
    for (int t = tid; t < D_ * 3; t += 256) sO[t] = o1[(size_t)row * 384 + t];
    __syncthreads();
    for (int t = tid; t < D_ * 3; t += 256) {
        int e = t / 3, c = t - e * 3;
        float a = x1[(size_t)row * 384 + t];
        for (int d = 0; d < D_; ++d) a += sO[d * 3 + c] * Wov[d * D_ + e];
        x1[(size_t)row * 384 + t] = a * sG[e];
    }
}

// ---------------- state head ----------------
__global__ void k_state(const float* __restrict__ x0, const float* __restrict__ W,
                        const float* __restrict__ bias, float* __restrict__ out)
{
    int g = blockIdx.x * 256 + threadIdx.x;
    if (g >= B_ * NC_ * DIN_) return;
    int c = g & 63;
    int rr = g >> 6;
    int b = rr / NC_, n = rr - b * NC_;
    const float* xr = x0 + (size_t)(b * N_ + n + 1) * D_;
    float a = bias[c];
    for (int d = 0; d < D_; ++d) a += xr[d] * W[d * DIN_ + c];
    out[g] = a;
}

// ---------------- force head ----------------
__global__ void k_force1(const float* __restrict__ x1, const float* __restrict__ W,
                         const float* __restrict__ bias, float* __restrict__ frc)
{
    int g = blockIdx.x * 256 + threadIdx.x;
    if (g >= B_ * NC_ * 3) return;
    int c = g % 3;
    int rr = g / 3;
    int b = rr / NC_, n = rr - b * NC_;
    const float* xr = x1 + (size_t)(b * N_ + n + 1) * 384;
    float a = bias[0];
    for (int d = 0; d < D_; ++d) a += xr[d * 3 + c] * W[d];
    frc[g] = a;
}

__global__ __launch_bounds__(256) void k_fsum(const float* __restrict__ frc, float* __restrict__ fsum)
{
    int b = blockIdx.x / 3, c = blockIdx.x % 3;
    __shared__ float red[256];
    float a = 0.f;
    for (int n = threadIdx.x; n < NC_; n += 256) a += frc[(b * NC_ + n) * 3 + c];
    red[threadIdx.x] = a; __syncthreads();
    for (int st = 128; st > 0; st >>= 1) { if (threadIdx.x < st) red[threadIdx.x] += red[threadIdx.x + st]; __syncthreads(); }
    if (threadIdx.x == 0) fsum[blockIdx.x] = red[0] / (float)NC_;
}

__global__ void k_force2(const float* __restrict__ frc, const float* __restrict__ fsum,
                         float* __restrict__ out)
{
    int g = blockIdx.x * 256 + threadIdx.x;
    if (g >= B_ * NC_ * 3) return;
    int c = g % 3;
    int b = g / (NC_ * 3);
    out[g] = frc[g] - fsum[b * 3 + c];
}

} // namespace

extern "C" void kernel_launch(void* const* d_in, const int* in_sizes, int n_in,
                              void* d_out, int out_size, void* d_ws, size_t ws_size,
                              hipStream_t stream)
{
    const float* X       = (const float*)d_in[0];
    const float* W_embed = (const float*)d_in[1];
    const float* b_embed = (const float*)d_in[2];
    const float* Wq      = (const float*)d_in[3];
    const float* Wk      = (const float*)d_in[4];
    const float* Wv      = (const float*)d_in[5];
    const float* Wvv     = (const float*)d_in[6];
    const float* rw1     = (const float*)d_in[7];
    const float* rb1     = (const float*)d_in[8];
    const float* rw2     = (const float*)d_in[9];
    const float* rb2     = (const float*)d_in[10];
    const float* Wo      = (const float*)d_in[11];
    const float* Wov     = (const float*)d_in[12];
    const float* ff_w1   = (const float*)d_in[13];
    const float* ff_b1   = (const float*)d_in[14];
    const float* ff_w2   = (const float*)d_in[15];
    const float* ff_b2   = (const float*)d_in[16];
    const float* gate_w  = (const float*)d_in[17];
    const float* gate_b  = (const float*)d_in[18];
    const float* ln1_s   = (const float*)d_in[19];
    const float* ln1_b   = (const float*)d_in[20];
    const float* ln2_s   = (const float*)d_in[21];
    const float* ln2_b   = (const float*)d_in[22];
    const float* W_state = (const float*)d_in[23];
    const float* b_state = (const float*)d_in[24];
    const float* W_force = (const float*)d_in[25];
    const float* b_force = (const float*)d_in[26];
    (void)in_sizes; (void)n_in; (void)out_size; (void)ws_size;

    float* out = (float*)d_out;

    float* w = (float*)d_ws;
    float* pos  = w;                    // 49152
    int*   idxv = (int*)(w + 49152);    // 98304
    float* uv   = w + 147456;           // 294912
    float* rbfv = w + 442368;           // 1572864
    float* x0   = w + 2015232;          // 2097152
    float* hb   = w + 4112384;          // 2097152
    float* qb   = w + 6209536;          // 2097152
    float* kb   = w + 8306688;          // 2097152
    float* vb   = w + 10403840;         // 2097152
    float* o0   = w + 12500992;         // 2097152
    float* o1   = w + 14598144;         // 6291456
    float* x1   = w + 20889600;         // 6291456
    float* t1   = w + 27181056;         // 4194304
    float* gb   = w + 31375360;         // 2097152
    float* frc  = w + 33472512;         // 49140
    float* fsum = w + 33521652;         // 12

    hipMemsetAsync(x1, 0, (size_t)ROWS_ * 384 * sizeof(float), stream);

    k_prep<<<(ROWS_ + 255) / 256, 256, 0, stream>>>(X, pos);
    k_embed<<<(ROWS_ * D_ + 255) / 256, 256, 0, stream>>>(X, W_embed, b_embed, x0);
    k_knn<<<ROWS_ / 4, 256, 0, stream>>>(pos, idxv);
    k_geom<<<(ROWS_ * K_ + 255) / 256, 256, 0, stream>>>(pos, idxv, uv, rbfv);

    for (int l = 0; l < 2; ++l) {
        const float* Wq_l  = Wq + l * D_ * D_;
        const float* Wk_l  = Wk + l * D_ * D_;
        const float* Wv_l  = Wv + l * D_ * D_;
        const float* Wvv_l = Wvv + l * D_ * D_;
        const float* Wo_l  = Wo + l * D_ * D_;
        const float* Wov_l = Wov + l * D_ * D_;
        const float* rw1_l = rw1 + l * NRBF_ * HR_;
        const float* rb1_l = rb1 + l * HR_;
        const float* rw2_l = rw2 + l * HR_ * 2 * D_;
        const float* rb2_l = rb2 + l * 2 * D_;
        const float* fw1_l = ff_w1 + l * D_ * 2 * D_;
        const float* fb1_l = ff_b1 + l * 2 * D_;
        const float* fw2_l = ff_w2 + l * 2 * D_ * D_;
        const float* fb2_l = ff_b2 + l * D_;
        const float* gw_l  = gate_w + l * D_ * D_;
        const float* gb_l  = gate_b + l * D_;

        // h = LN1(x0)
        k_ln<<<ROWS_, 128, 0, stream>>>(x0, ln1_s + l * D_, ln1_b + l * D_, hb);
        // q,k,v
        k_gemm<128, 128, 0, false, false><<<(ROWS_ * 128 + 255) / 256, 256, 0, stream>>>(hb, Wq_l, nullptr, qb, ROWS_);
        k_gemm<128, 128, 0, false, false><<<(ROWS_ * 128 + 255) / 256, 256, 0, stream>>>(hb, Wk_l, nullptr, kb, ROWS_);
        k_gemm<128, 128, 0, false, false><<<(ROWS_ * 128 + 255) / 256, 256, 0, stream>>>(hb, Wv_l, nullptr, vb, ROWS_);
        // attention + x1 message
        k_attn<<<ROWS_, 256, 0, stream>>>(qb, kb, vb, idxv, rbfv, uv, x1,
                                          rw1_l, rb1_l, rw2_l, rb2_l, Wvv_l, o0, o1);
        // x0 += out0 @ Wo
        k_gemm<128, 128, 0, true, false><<<(ROWS_ * 128 + 255) / 256, 256, 0, stream>>>(o0, Wo_l, nullptr, x0, ROWS_);
        // h2 = LN2(x0)
        k_ln<<<ROWS_, 128, 0, stream>>>(x0, ln2_s + l * D_, ln2_b + l * D_, hb);
        // ff
        k_gemm<128, 256, 1, false, true><<<(ROWS_ * 256 + 255) / 256, 256, 0, stream>>>(hb, fw1_l, fb1_l, t1, ROWS_);
        k_gemm<256, 128, 0, true, true><<<(ROWS_ * 128 + 255) / 256, 256, 0, stream>>>(t1, fw2_l, fb2_l, x0, ROWS_);
        // gate
        k_gemm<128, 128, 2, false, true><<<(ROWS_ * 128 + 255) / 256, 256, 0, stream>>>(hb, gw_l, gb_l, gb, ROWS_);
        // x1 = (x1 + out1 @ Wov) * gate
        k_x1up<<<ROWS_, 256, 0, stream>>>(o1, Wov_l, gb, x1);
    }

    k_state<<<(B_ * NC_ * DIN_ + 255) / 256, 256, 0, stream>>>(x0, W_state, b_state, out);
    k_force1<<<(B_ * NC_ * 3 + 255) / 256, 256, 0, stream>>>(x1, W_force, b_force, frc);
    k_fsum<<<12, 256, 0, stream>>>(frc, fsum);
    k_force2<<<(B_ * NC_ * 3 + 255) / 256, 256, 0, stream>>>(frc, fsum, out + (size_t)B_ * NC_ * DIN_);
}

// Round 3
// 716.843 us; speedup vs baseline: 2.7228x; 2.7228x over previous
//
#include <hip/hip_runtime.h>
#include <cstdint>
#include <cstddef>

namespace {

constexpr int B_ = 4, NC_ = 4095, N_ = 4096, DIN_ = 64, D_ = 128, K_ = 6;
constexpr int XROW_ = 6 + DIN_;   // 70
constexpr int ROWS_ = B_ * N_;    // 16384

__device__ __forceinline__ float sigm(float x) { return 1.f / (1.f + expf(-x)); }
__device__ __forceinline__ float silu(float x) { return x / (1.f + expf(-x)); }

// ---------------- pos build ----------------
__global__ void k_prep(const float* __restrict__ X, float* __restrict__ pos)
{
    int g = blockIdx.x * 256 + threadIdx.x;
    if (g >= ROWS_) return;
    int b = g >> 12, n = g & (N_ - 1);
    float px = 0.f, py = 0.f, pz = 0.f;
    if (n > 0) {
        const float* xr = X + (size_t)(b * NC_ + n - 1) * XROW_;
        px = xr[0]; py = xr[1]; pz = xr[2];
    }
    pos[g * 3 + 0] = px; pos[g * 3 + 1] = py; pos[g * 3 + 2] = pz;
}

// ---------------- feats build (for embed GEMM) ----------------
__global__ void k_feats(const float* __restrict__ X, float* __restrict__ feats)
{
    int g = blockIdx.x * 256 + threadIdx.x;
    if (g >= ROWS_ * DIN_) return;
    int c = g & 63, row = g >> 6;
    int b = row >> 12, n = row & (N_ - 1);
    feats[g] = (n > 0) ? X[(size_t)(b * NC_ + n - 1) * XROW_ + 6 + c] : 0.f;
}

// ---------------- KNN: one wave per query, top-6 by (d2,idx) ----------------
__device__ __forceinline__ unsigned long long shflxor64(unsigned long long v, int mask)
{
    int lo = __shfl_xor((int)(unsigned)(v & 0xffffffffull), mask, 64);
    int hi = __shfl_xor((int)(unsigned)(v >> 32), mask, 64);
    return ((unsigned long long)(unsigned)hi << 32) | (unsigned)lo;
}

__global__ __launch_bounds__(256) void k_knn(const float* __restrict__ pos, int* __restrict__ idxv)
{
    const int wave = (blockIdx.x << 2) | (threadIdx.x >> 6);
    const int lane = threadIdx.x & 63;
    const int b = wave >> 12, i = wave & (N_ - 1);
    const float* pb = pos + (size_t)b * N_ * 3;
    const float qx = pb[i * 3], qy = pb[i * 3 + 1], qz = pb[i * 3 + 2];

    unsigned long long a0 = ~0ull, a1 = ~0ull, a2 = ~0ull, a3 = ~0ull, a4 = ~0ull, a5 = ~0ull;
    for (int j = lane; j < N_; j += 64) {
        if (j == i) continue;
        float dx = pb[j * 3] - qx, dy = pb[j * 3 + 1] - qy, dz = pb[j * 3 + 2] - qz;
        float d2 = dx * dx + dy * dy + dz * dz;
        unsigned long long key = ((unsigned long long)__float_as_uint(d2) << 32) | (unsigned)j;
        if (key < a5) {
            a5 = key;
            unsigned long long t;
            if (a5 < a4) { t = a5; a5 = a4; a4 = t; }
            if (a4 < a3) { t = a4; a4 = a3; a3 = t; }
            if (a3 < a2) { t = a3; a3 = a2; a2 = t; }
            if (a2 < a1) { t = a2; a2 = a1; a1 = t; }
            if (a1 < a0) { t = a1; a1 = a0; a0 = t; }
        }
    }
    #pragma unroll
    for (int k = 0; k < K_; ++k) {
        unsigned long long m = a0;
        #pragma unroll
        for (int off = 1; off < 64; off <<= 1) {
            unsigned long long o = shflxor64(m, off);
            if (o < m) m = o;
        }
        if (a0 == m) { a0 = a1; a1 = a2; a2 = a3; a3 = a4; a4 = a5; a5 = ~0ull; }
        if (lane == 0) idxv[wave * K_ + k] = (int)(unsigned)(m & 0xffffffffull);
    }
}

// ---------------- geom: u, rbf per edge ----------------
__global__ void k_geom(const float* __restrict__ pos, const int* __restrict__ idxv,
                       float* __restrict__ uv, float* __restrict__ rbfv)
{
    int g = blockIdx.x * 256 + threadIdx.x;
    if (g >= ROWS_ * K_) return;
    int b = g / (N_ * K_);
    int rem = g - b * N_ * K_;
    int n = rem / K_;
    int j = idxv[g];
    const float* pb = pos + (size_t)b * N_ * 3;
    float rx = pb[j * 3] - pb[n * 3];
    float ry = pb[j * 3 + 1] - pb[n * 3 + 1];
    float rz = pb[j * 3 + 2] - pb[n * 3 + 2];
    float dist = sqrtf(rx * rx + ry * ry + rz * rz + 1e-8f);
    float inv = 1.f / dist;
    uv[g * 3 + 0] = rx * inv; uv[g * 3 + 1] = ry * inv; uv[g * 3 + 2] = rz * inv;
    for (int r = 0; r < 16; ++r) {
        float t = (dist - (4.0f / 15.0f) * r) * 4.0f;
        rbfv[g * 16 + r] = expf(-t * t);
    }
}

// ---------------- LayerNorm: wave per row ----------------
__global__ __launch_bounds__(256) void k_ln(const float* __restrict__ x,
                                            const float* __restrict__ s, const float* __restrict__ bb,
                                            float* __restrict__ o)
{
    int w = threadIdx.x >> 6, lane = threadIdx.x & 63;
    size_t row = (size_t)blockIdx.x * 4 + w;
    const float* xr = x + row * 128;
    float v0 = xr[lane], v1 = xr[lane + 64];
    float sm = v0 + v1, sq = v0 * v0 + v1 * v1;
    #pragma unroll
    for (int off = 32; off; off >>= 1) {
        sm += __shfl_xor(sm, off, 64);
        sq += __shfl_xor(sq, off, 64);
    }
    float m = sm * (1.f / 128.f);
    float var = sq * (1.f / 128.f) - m * m;
    float inv = 1.f / sqrtf(var + 1e-5f);
    o[row * 128 + lane]      = (v0 - m) * inv * s[lane]      + bb[lane];
    o[row * 128 + lane + 64] = (v1 - m) * inv * s[lane + 64] + bb[lane + 64];
}

// ---------------- concat Wq|Wk|Wv -> Wcat [128][384] ----------------
__global__ void k_catw(const float* __restrict__ Wq, const float* __restrict__ Wk,
                       const float* __restrict__ Wv, float* __restrict__ Wcat)
{
    int i = blockIdx.x * 256 + threadIdx.x;
    if (i >= 128 * 384) return;
    int k = i / 384, c = i - k * 384;
    float v;
    if (c < 128)      v = Wq[k * 128 + c];
    else if (c < 256) v = Wk[k * 128 + c - 128];
    else              v = Wv[k * 128 + c - 256];
    Wcat[i] = v;
}

// ---------------- tiled fp32 GEMM ----------------
// C[m][n] = post( A[m][0:KD] @ W[:, n0:n0+BN] ), thread = 4x4 outputs.
// post: +bias (HASB), ACT (1=silu, 2=sigmoid), +C_old (ACC), *gate (GATEMUL, gate row = m/3)
template<int KD, int BM, int BN, int ACT, bool ACC, bool HASB, bool GATEMUL>
__global__ __launch_bounds__((BM / 4) * (BN / 4)) void k_tgemm(
    const float* __restrict__ A, const float* __restrict__ W, const float* __restrict__ bias,
    const float* __restrict__ gate, float* __restrict__ C, int ldw, int ldc)
{
    constexpr int NTX = BN / 4, NTY = BM / 4, NTHR = NTX * NTY;
    constexpr int ASTR = BM + 4, WSTR = BN + 4;
    __shared__ __align__(16) float As[32 * ASTR];
    __shared__ __align__(16) float Ws[32 * WSTR];
    const int tid = threadIdx.x;
    const int tx = tid % NTX, ty = tid / NTX;
    const int m0 = blockIdx.x * BM, n0 = blockIdx.y * BN;
    float acc[4][4] = {};
    for (int k0 = 0; k0 < KD; k0 += 32) {
        __syncthreads();
        for (int id = tid; id < BM * 8; id += NTHR) {
            int rrow = id >> 3, kq = id & 7;
            float4 a4 = *(const float4*)&A[(size_t)(m0 + rrow) * KD + k0 + kq * 4];
            As[(kq * 4 + 0) * ASTR + rrow] = a4.x;
            As[(kq * 4 + 1) * ASTR + rrow] = a4.y;
            As[(kq * 4 + 2) * ASTR + rrow] = a4.z;
            As[(kq * 4 + 3) * ASTR + rrow] = a4.w;
        }
        for (int id = tid; id < 8 * BN; id += NTHR) {
            int kr = id / (BN / 4), cq = id - kr * (BN / 4);
            *(float4*)&Ws[kr * WSTR + cq * 4] =
                *(const float4*)&W[(size_t)(k0 + kr) * ldw + n0 + cq * 4];
        }
        __syncthreads();
        #pragma unroll 8
        for (int k = 0; k < 32; ++k) {
            float4 a4 = *(const float4*)&As[k * ASTR + ty * 4];
            float4 w4 = *(const float4*)&Ws[k * WSTR + tx * 4];
            float av[4] = {a4.x, a4.y, a4.z, a4.w};
            float wv[4] = {w4.x, w4.y, w4.z, w4.w};
            #pragma unroll
            for (int r = 0; r < 4; ++r)
                #pragma unroll
                for (int j = 0; j < 4; ++j)
                    acc[r][j] += av[r] * wv[j];
        }
    }
    float bv[4] = {0.f, 0.f, 0.f, 0.f};
    if (HASB) {
        #pragma unroll
        for (int j = 0; j < 4; ++j) bv[j] = bias[n0 + tx * 4 + j];
    }
    #pragma unroll
    for (int r = 0; r < 4; ++r) {
        int m = m0 + ty * 4 + r;
        float* cp = &C[(size_t)m * ldc + n0 + tx * 4];
        float v[4];
        #pragma unroll
        for (int j = 0; j < 4; ++j) {
            float a = acc[r][j] + bv[j];
            if (ACT == 1) a = silu(a);
            if (ACT == 2) a = sigm(a);
            v[j] = a;
        }
        if (ACC) {
            float4 old = *(const float4*)cp;
            v[0] += old.x; v[1] += old.y; v[2] += old.z; v[3] += old.w;
        }
        if (GATEMUL) {
            const float* gp = &gate[(size_t)(m / 3) * 128 + n0 + tx * 4];
            #pragma unroll
            for (int j = 0; j < 4; ++j) v[j] *= gp[j];
        }
        float4 res = {v[0], v[1], v[2], v[3]};
        *(float4*)cp = res;
    }
}

// ---------------- fused attention (light) ----------------
// qkvb: [row][384] = q|k|v ; x1,o1: [row][c(3)][128] ; o0: [row][128]
__global__ __launch_bounds__(256) void k_attn(
    const float* __restrict__ qkvb, const int* __restrict__ idxv,
    const float* __restrict__ rbfv, const float* __restrict__ uv,
    const float* __restrict__ x1,
    const float* __restrict__ rw1, const float* __restrict__ rb1,
    const float* __restrict__ rw2, const float* __restrict__ rb2,
    const float* __restrict__ Wvv,
    float* __restrict__ o0, float* __restrict__ o1)
{
    const int row = blockIdx.x, b = row >> 12, tid = threadIdx.x;
    __shared__ float sHid[6][16];
    __shared__ __align__(16) float sRad[6][256];
    __shared__ __align__(16) float sXw[12][128];
    __shared__ __align__(16) float sQ[128];
    __shared__ float sU[6][3], sLog[24], sAttn[24];
    __shared__ int sJ[6];

    // p0: stage q, idx, u; edge-MLP hidden
    if (tid < 128) sQ[tid] = qkvb[(size_t)row * 384 + tid];
    else if (tid < 134) sJ[tid - 128] = idxv[row * 6 + (tid - 128)];
    else if (tid < 152) { int t = tid - 134; sU[t / 3][t % 3] = uv[(size_t)row * 18 + t]; }
    else if (tid >= 160) {
        int t = tid - 160, k = t >> 4, hh = t & 15;
        float a = rb1[hh];
        const float* rb = rbfv + (size_t)(row * 6 + k) * 16;
        #pragma unroll
        for (int r = 0; r < 16; ++r) a += rb[r] * rw1[r * 16 + hh];
        sHid[k][hh] = silu(a);
    }
    __syncthreads();
    // p1: rad
    for (int it = tid; it < 1536; it += 256) {
        int k = it >> 8, c = it & 255;
        float a = rb2[c];
        #pragma unroll
        for (int hh = 0; hh < 16; ++hh) a += sHid[k][hh] * rw2[hh * 256 + c];
        sRad[k][c] = a;
    }
    __syncthreads();
    // p2: logits (24 groups of 8 lanes)
    if (tid < 192) {
        int g = tid >> 3, o = tid & 7;
        int h = g / 6, k = g - h * 6;
        float4 q4 = *(const float4*)&sQ[h * 32 + o * 4];
        float4 k4 = *(const float4*)&qkvb[(size_t)(b * N_ + sJ[k]) * 384 + 128 + h * 32 + o * 4];
        float4 r4 = *(const float4*)&sRad[k][h * 32 + o * 4];
        float p = (q4.x * k4.x + q4.y * k4.y + q4.z * k4.z + q4.w * k4.w) * 0.17677669529663687f
                + (r4.x + r4.y + r4.z + r4.w) * 0.03125f;
        p += __shfl_down(p, 4, 8);
        p += __shfl_down(p, 2, 8);
        p += __shfl_down(p, 1, 8);
        if (o == 0) sLog[g] = p;
    }
    __syncthreads();
    // p3: softmax
    if (tid < 4) {
        float mx = sLog[tid * 6];
        #pragma unroll
        for (int k = 1; k < 6; ++k) mx = fmaxf(mx, sLog[tid * 6 + k]);
        float e[6], smv = 0.f;
        #pragma unroll
        for (int k = 0; k < 6; ++k) { e[k] = expf(sLog[tid * 6 + k] - mx); smv += e[k]; }
        float inv = 1.f / smv;
        #pragma unroll
        for (int k = 0; k < 6; ++k) sAttn[tid * 6 + k] = e[k] * inv;
    }
    __syncthreads();
    // p4: out0 + xw
    if (tid < 128) {
        int d = tid, h = d >> 5;
        float o = 0.f;
        #pragma unroll
        for (int k = 0; k < 6; ++k) {
            float vv = qkvb[(size_t)(b * N_ + sJ[k]) * 384 + 256 + d];
            o += sAttn[h * 6 + k] * vv * silu(sRad[k][128 + d]);
        }
        o0[(size_t)row * 128 + d] = o;
    }
    for (int it = tid; it < 384; it += 256) {
        int c = it >> 7, d = it & 127;
        float a0 = 0.f, a1 = 0.f, a2 = 0.f, a3 = 0.f;
        #pragma unroll
        for (int k = 0; k < 6; ++k) {
            float vv = x1[(size_t)(b * N_ + sJ[k]) * 384 + c * 128 + d];
            a0 += sAttn[0 + k] * vv;
            a1 += sAttn[6 + k] * vv;
            a2 += sAttn[12 + k] * vv;
            a3 += sAttn[18 + k] * vv;
        }
        sXw[0 + c][d] = a0; sXw[3 + c][d] = a1; sXw[6 + c][d] = a2; sXw[9 + c][d] = a3;
    }
    __syncthreads();
    // p5: out1 = xw @ Wvv (head-block) + attn*rv*u
    if (tid < 96) {
        int c = tid >> 5, eg = tid & 31, e0 = eg * 4, h = eg >> 3;
        float4 acc = {0.f, 0.f, 0.f, 0.f};
        const float* xr = sXw[h * 3 + c];
        #pragma unroll 4
        for (int d = 0; d < 128; ++d) {
            float xv = xr[d];
            float4 w4 = *(const float4*)&Wvv[d * 128 + e0];
            acc.x += xv * w4.x; acc.y += xv * w4.y; acc.z += xv * w4.z; acc.w += xv * w4.w;
        }
        #pragma unroll
        for (int k = 0; k < 6; ++k) {
            float au = sAttn[h * 6 + k] * sU[k][c];
            float4 r4 = *(const float4*)&sRad[k][128 + e0];
            acc.x += au * r4.x; acc.y += au * r4.y; acc.z += au * r4.z; acc.w += au * r4.w;
        }
        *(float4*)&o1[(size_t)row * 384 + c * 128 + e0] = acc;
    }
}

// ---------------- state head copy ----------------
__global__ void k_statecp(const float* __restrict__ sout, float* __restrict__ out)
{
    int g = blockIdx.x * 256 + threadIdx.x;
    if (g >= B_ * NC_ * DIN_) return;
    int c = g & 63, r = g >> 6;
    int b = r / NC_, n = r - b * NC_;
    out[g] = sout[(size_t)(b * N_ + n + 1) * 64 + c];
}

// ---------------- force head ----------------
__global__ void k_force1(const float* __restrict__ x1, const float* __restrict__ W,
                         const float* __restrict__ bias, float* __restrict__ frc)
{
    int g = blockIdx.x * 256 + threadIdx.x;
    if (g >= B_ * NC_ * 3) return;
    int c = g % 3, rr = g / 3;
    int b = rr / NC_, n = rr - b * NC_;
    const float* xr = x1 + (size_t)(b * N_ + n + 1) * 384 + c * 128;
    float a = bias[0];
    for (int d = 0; d < 128; ++d) a += xr[d] * W[d];
    frc[g] = a;
}

__global__ __launch_bounds__(256) void k_fsum(const float* __restrict__ frc, float* __restrict__ fsum)
{
    int b = blockIdx.x / 3, c = blockIdx.x % 3;
    __shared__ float red[256];
    float a = 0.f;
    for (int n = threadIdx.x; n < NC_; n += 256) a += frc[(b * NC_ + n) * 3 + c];
    red[threadIdx.x] = a; __syncthreads();
    for (int st = 128; st > 0; st >>= 1) { if (threadIdx.x < st) red[threadIdx.x] += red[threadIdx.x + st]; __syncthreads(); }
    if (threadIdx.x == 0) fsum[blockIdx.x] = red[0] / (float)NC_;
}

__global__ void k_force2(const float* __restrict__ frc, const float* __restrict__ fsum,
                         float* __restrict__ out)
{
    int g = blockIdx.x * 256 + threadIdx.x;
    if (g >= B_ * NC_ * 3) return;
    int c = g % 3;
    int b = g / (NC_ * 3);
    out[g] = frc[g] - fsum[b * 3 + c];
}

} // namespace

extern "C" void kernel_launch(void* const* d_in, const int* in_sizes, int n_in,
                              void* d_out, int out_size, void* d_ws, size_t ws_size,
                              hipStream_t stream)
{
    const float* X       = (const float*)d_in[0];
    const float* W_embed = (const float*)d_in[1];
    const float* b_embed = (const float*)d_in[2];
    const float* Wq      = (const float*)d_in[3];
    const float* Wk      = (const float*)d_in[4];
    const float* Wv      = (const float*)d_in[5];
    const float* Wvv     = (const float*)d_in[6];
    const float* rw1     = (const float*)d_in[7];
    const float* rb1     = (const float*)d_in[8];
    const float* rw2     = (const float*)d_in[9];
    const float* rb2     = (const float*)d_in[10];
    const float* Wo      = (const float*)d_in[11];
    const float* Wov     = (const float*)d_in[12];
    const float* ff_w1   = (const float*)d_in[13];
    const float* ff_b1   = (const float*)d_in[14];
    const float* ff_w2   = (const float*)d_in[15];
    const float* ff_b2   = (const float*)d_in[16];
    const float* gate_w  = (const float*)d_in[17];
    const float* gate_b  = (const float*)d_in[18];
    const float* ln1_s   = (const float*)d_in[19];
    const float* ln1_b   = (const float*)d_in[20];
    const float* ln2_s   = (const float*)d_in[21];
    const float* ln2_b   = (const float*)d_in[22];
    const float* W_state = (const float*)d_in[23];
    const float* b_state = (const float*)d_in[24];
    const float* W_force = (const float*)d_in[25];
    const float* b_force = (const float*)d_in[26];
    (void)in_sizes; (void)n_in; (void)out_size; (void)ws_size;

    float* out = (float*)d_out;
    float* w = (float*)d_ws;

    float* pos   = w;               // 49152
    int*   idxv  = (int*)(w + 49152);         // 98304
    float* uv    = w + 147456;      // 294912
    float* rbfv  = w + 442368;      // 1572864
    float* feats = w + 2015232;     // 1048576   (reused as sout)
    float* x0    = w + 3063808;     // 2097152
    float* hb    = w + 5160960;     // 2097152
    float* qkvb  = w + 7258112;     // 6291456   (first 4194304 reused as t1)
    float* o0    = w + 13549568;    // 2097152   (reused as gate buffer)
    float* o1    = w + 15646720;    // 6291456
    float* x1    = w + 21938176;    // 6291456
    float* Wcat  = w + 28229632;    // 49152
    float* frc   = w + 28278784;    // 49152
    float* fsum  = w + 28327936;    // 16
    float* t1    = qkvb;
    float* gb    = o0;
    float* sout  = feats;

    hipMemsetAsync(x1, 0, (size_t)ROWS_ * 384 * sizeof(float), stream);

    k_prep<<<(ROWS_ + 255) / 256, 256, 0, stream>>>(X, pos);
    k_feats<<<(ROWS_ * DIN_ + 255) / 256, 256, 0, stream>>>(X, feats);
    k_knn<<<ROWS_ / 4, 256, 0, stream>>>(pos, idxv);
    k_geom<<<(ROWS_ * K_ + 255) / 256, 256, 0, stream>>>(pos, idxv, uv, rbfv);
    // x0 = feats @ W_embed + b_embed
    k_tgemm<64, 32, 128, 0, false, true, false><<<dim3(512, 1), 256, 0, stream>>>(
        feats, W_embed, b_embed, nullptr, x0, 128, 128);

    for (int l = 0; l < 2; ++l) {
        const float* Wq_l  = Wq + l * 16384;
        const float* Wk_l  = Wk + l * 16384;
        const float* Wv_l  = Wv + l * 16384;
        const float* Wvv_l = Wvv + l * 16384;
        const float* Wo_l  = Wo + l * 16384;
        const float* Wov_l = Wov + l * 16384;
        const float* rw1_l = rw1 + l * 256;
        const float* rb1_l = rb1 + l * 16;
        const float* rw2_l = rw2 + l * 4096;
        const float* rb2_l = rb2 + l * 256;
        const float* fw1_l = ff_w1 + l * 32768;
        const float* fb1_l = ff_b1 + l * 256;
        const float* fw2_l = ff_w2 + l * 32768;
        const float* fb2_l = ff_b2 + l * 128;
        const float* gw_l  = gate_w + l * 16384;
        const float* gb_l  = gate_b + l * 128;

        // h = LN1(x0)
        k_ln<<<ROWS_ / 4, 256, 0, stream>>>(x0, ln1_s + l * 128, ln1_b + l * 128, hb);
        // qkv = h @ [Wq|Wk|Wv]
        k_catw<<<(128 * 384 + 255) / 256, 256, 0, stream>>>(Wq_l, Wk_l, Wv_l, Wcat);
        k_tgemm<128, 64, 128, 0, false, false, false><<<dim3(256, 3), 512, 0, stream>>>(
            hb, Wcat, nullptr, nullptr, qkvb, 384, 384);
        // attention
        k_attn<<<ROWS_, 256, 0, stream>>>(qkvb, idxv, rbfv, uv, x1,
                                          rw1_l, rb1_l, rw2_l, rb2_l, Wvv_l, o0, o1);
        // x0 += out0 @ Wo
        k_tgemm<128, 32, 128, 0, true, false, false><<<dim3(512, 1), 256, 0, stream>>>(
            o0, Wo_l, nullptr, nullptr, x0, 128, 128);
        // h2 = LN2(x0)
        k_ln<<<ROWS_ / 4, 256, 0, stream>>>(x0, ln2_s + l * 128, ln2_b + l * 128, hb);
        // gate = sigmoid(h2 @ gate_w + gate_b)
        k_tgemm<128, 32, 128, 2, false, true, false><<<dim3(512, 1), 256, 0, stream>>>(
            hb, gw_l, gb_l, nullptr, gb, 128, 128);
        // x1 = (x1 + o1 @ Wov) * gate
        k_tgemm<128, 64, 128, 0, true, false, true><<<dim3(768, 1), 512, 0, stream>>>(
            o1, Wov_l, nullptr, gb, x1, 128, 128);
        // ff
        k_tgemm<128, 64, 128, 1, false, true, false><<<dim3(256, 2), 512, 0, stream>>>(
            hb, fw1_l, fb1_l, nullptr, t1, 256, 256);
        k_tgemm<256, 32, 128, 0, true, true, false><<<dim3(512, 1), 256, 0, stream>>>(
            t1, fw2_l, fb2_l, nullptr, x0, 128, 128);
    }

    // state head
    k_tgemm<128, 32, 64, 0, false, true, false><<<dim3(512, 1), 128, 0, stream>>>(
        x0, W_state, b_state, nullptr, sout, 64, 64);
    k_statecp<<<(B_ * NC_ * DIN_ + 255) / 256, 256, 0, stream>>>(sout, out);
    // force head
    k_force1<<<(B_ * NC_ * 3 + 255) / 256, 256, 0, stream>>>(x1, W_force, b_force, frc);
    k_fsum<<<12, 256, 0, stream>>>(frc, fsum);
    k_force2<<<(B_ * NC_ * 3 + 255) / 256, 256, 0, stream>>>(frc, fsum, out + (size_t)B_ * NC_ * DIN_);
}

// Round 4
// 575.962 us; speedup vs baseline: 3.3888x; 1.2446x over previous
//
#include <hip/hip_runtime.h>
#include <cstdint>
#include <cstddef>

namespace {

constexpr int B_ = 4, NC_ = 4095, N_ = 4096, DIN_ = 64, D_ = 128, K_ = 6;
constexpr int XROW_ = 6 + DIN_;   // 70
constexpr int ROWS_ = B_ * N_;    // 16384

__device__ __forceinline__ float sigm(float x) { return 1.f / (1.f + expf(-x)); }
__device__ __forceinline__ float silu(float x) { return x / (1.f + expf(-x)); }

// ---------------- pos build ----------------
__global__ void k_prep(const float* __restrict__ X, float* __restrict__ pos)
{
    int g = blockIdx.x * 256 + threadIdx.x;
    if (g >= ROWS_) return;
    int b = g >> 12, n = g & (N_ - 1);
    float px = 0.f, py = 0.f, pz = 0.f;
    if (n > 0) {
        const float* xr = X + (size_t)(b * NC_ + n - 1) * XROW_;
        px = xr[0]; py = xr[1]; pz = xr[2];
    }
    pos[g * 3 + 0] = px; pos[g * 3 + 1] = py; pos[g * 3 + 2] = pz;
}

// ---------------- feats build (for embed GEMM) ----------------
__global__ void k_feats(const float* __restrict__ X, float* __restrict__ feats)
{
    int g = blockIdx.x * 256 + threadIdx.x;
    if (g >= ROWS_ * DIN_) return;
    int c = g & 63, row = g >> 6;
    int b = row >> 12, n = row & (N_ - 1);
    feats[g] = (n > 0) ? X[(size_t)(b * NC_ + n - 1) * XROW_ + 6 + c] : 0.f;
}

// ---------------- KNN: one wave per query, top-6 by (d2,idx) ----------------
__device__ __forceinline__ unsigned long long shflxor64(unsigned long long v, int mask)
{
    int lo = __shfl_xor((int)(unsigned)(v & 0xffffffffull), mask, 64);
    int hi = __shfl_xor((int)(unsigned)(v >> 32), mask, 64);
    return ((unsigned long long)(unsigned)hi << 32) | (unsigned)lo;
}

__global__ __launch_bounds__(256) void k_knn(const float* __restrict__ pos, int* __restrict__ idxv)
{
    const int wave = (blockIdx.x << 2) | (threadIdx.x >> 6);
    const int lane = threadIdx.x & 63;
    const int b = wave >> 12, i = wave & (N_ - 1);
    const float* pb = pos + (size_t)b * N_ * 3;
    const float qx = pb[i * 3], qy = pb[i * 3 + 1], qz = pb[i * 3 + 2];

    unsigned long long a0 = ~0ull, a1 = ~0ull, a2 = ~0ull, a3 = ~0ull, a4 = ~0ull, a5 = ~0ull;
    for (int j = lane; j < N_; j += 64) {
        if (j == i) continue;
        float dx = pb[j * 3] - qx, dy = pb[j * 3 + 1] - qy, dz = pb[j * 3 + 2] - qz;
        float d2 = dx * dx + dy * dy + dz * dz;
        unsigned long long key = ((unsigned long long)__float_as_uint(d2) << 32) | (unsigned)j;
        if (key < a5) {
            a5 = key;
            unsigned long long t;
            if (a5 < a4) { t = a5; a5 = a4; a4 = t; }
            if (a4 < a3) { t = a4; a4 = a3; a3 = t; }
            if (a3 < a2) { t = a3; a3 = a2; a2 = t; }
            if (a2 < a1) { t = a2; a2 = a1; a1 = t; }
            if (a1 < a0) { t = a1; a1 = a0; a0 = t; }
        }
    }
    #pragma unroll
    for (int k = 0; k < K_; ++k) {
        unsigned long long m = a0;
        #pragma unroll
        for (int off = 1; off < 64; off <<= 1) {
            unsigned long long o = shflxor64(m, off);
            if (o < m) m = o;
        }
        if (a0 == m) { a0 = a1; a1 = a2; a2 = a3; a3 = a4; a4 = a5; a5 = ~0ull; }
        if (lane == 0) idxv[wave * K_ + k] = (int)(unsigned)(m & 0xffffffffull);
    }
}

// ---------------- geom: u, rbf per edge ----------------
__global__ void k_geom(const float* __restrict__ pos, const int* __restrict__ idxv,
                       float* __restrict__ uv, float* __restrict__ rbfv)
{
    int g = blockIdx.x * 256 + threadIdx.x;
    if (g >= ROWS_ * K_) return;
    int b = g / (N_ * K_);
    int rem = g - b * N_ * K_;
    int n = rem / K_;
    int j = idxv[g];
    const float* pb = pos + (size_t)b * N_ * 3;
    float rx = pb[j * 3] - pb[n * 3];
    float ry = pb[j * 3 + 1] - pb[n * 3 + 1];
    float rz = pb[j * 3 + 2] - pb[n * 3 + 2];
    float dist = sqrtf(rx * rx + ry * ry + rz * rz + 1e-8f);
    float inv = 1.f / dist;
    uv[g * 3 + 0] = rx * inv; uv[g * 3 + 1] = ry * inv; uv[g * 3 + 2] = rz * inv;
    for (int r = 0; r < 16; ++r) {
        float t = (dist - (4.0f / 15.0f) * r) * 4.0f;
        rbfv[g * 16 + r] = expf(-t * t);
    }
}

// ---------------- LayerNorm: wave per row ----------------
__global__ __launch_bounds__(256) void k_ln(const float* __restrict__ x,
                                            const float* __restrict__ s, const float* __restrict__ bb,
                                            float* __restrict__ o)
{
    int w = threadIdx.x >> 6, lane = threadIdx.x & 63;
    size_t row = (size_t)blockIdx.x * 4 + w;
    const float* xr = x + row * 128;
    float v0 = xr[lane], v1 = xr[lane + 64];
    float sm = v0 + v1, sq = v0 * v0 + v1 * v1;
    #pragma unroll
    for (int off = 32; off; off >>= 1) {
        sm += __shfl_xor(sm, off, 64);
        sq += __shfl_xor(sq, off, 64);
    }
    float m = sm * (1.f / 128.f);
    float var = sq * (1.f / 128.f) - m * m;
    float inv = 1.f / sqrtf(var + 1e-5f);
    o[row * 128 + lane]      = (v0 - m) * inv * s[lane]      + bb[lane];
    o[row * 128 + lane + 64] = (v1 - m) * inv * s[lane + 64] + bb[lane + 64];
}

// ---------------- per-layer weight prep: Wcat = [Wq|Wk|Wv]; rwg = head-reduced rw2/rb2 ----------------
__global__ void k_prepw(const float* __restrict__ Wq, const float* __restrict__ Wk,
                        const float* __restrict__ Wv, const float* __restrict__ rw2,
                        const float* __restrict__ rb2,
                        float* __restrict__ Wcat, float* __restrict__ rwg)
{
    int bid = blockIdx.x;
    if (bid < 192) {
        int i = bid * 256 + threadIdx.x;   // < 49152
        int k = i / 384, c = i - k * 384;
        float v;
        if (c < 128)      v = Wq[k * 128 + c];
        else if (c < 256) v = Wk[k * 128 + c - 128];
        else              v = Wv[k * 128 + c - 256];
        Wcat[i] = v;
    } else {
        int t = threadIdx.x;
        if (t < 64) {
            int hh = t >> 2, h = t & 3;
            float a = 0.f;
            #pragma unroll
            for (int dh = 0; dh < 32; ++dh) a += rw2[hh * 256 + h * 32 + dh];
            rwg[t] = a * (1.f / 32.f);
        } else if (t < 68) {
            int h = t - 64;
            float a = 0.f;
            #pragma unroll
            for (int dh = 0; dh < 32; ++dh) a += rb2[h * 32 + dh];
            rwg[64 + h] = a * (1.f / 32.f);
        }
    }
}

// ---------------- tiled fp32 GEMM ----------------
// C[m][n] = post( A[m][0:KD] @ W[:, n0:n0+BN] ), thread = 4x4 outputs.
// post: +bias (HASB), ACT (1=silu, 2=sigmoid), +C_old (ACC), *gate (GATEMUL, gate row = m/3)
template<int KD, int BM, int BN, int ACT, bool ACC, bool HASB, bool GATEMUL>
__global__ __launch_bounds__((BM / 4) * (BN / 4)) void k_tgemm(
    const float* __restrict__ A, const float* __restrict__ W, const float* __restrict__ bias,
    const float* __restrict__ gate, float* __restrict__ C, int ldw, int ldc)
{
    constexpr int NTX = BN / 4, NTY = BM / 4, NTHR = NTX * NTY;
    constexpr int ASTR = BM + 4, WSTR = BN + 4;
    __shared__ __align__(16) float As[32 * ASTR];
    __shared__ __align__(16) float Ws[32 * WSTR];
    const int tid = threadIdx.x;
    const int tx = tid % NTX, ty = tid / NTX;
    const int m0 = blockIdx.x * BM, n0 = blockIdx.y * BN;
    float acc[4][4] = {};
    for (int k0 = 0; k0 < KD; k0 += 32) {
        __syncthreads();
        for (int id = tid; id < BM * 8; id += NTHR) {
            int rrow = id >> 3, kq = id & 7;
            float4 a4 = *(const float4*)&A[(size_t)(m0 + rrow) * KD + k0 + kq * 4];
            As[(kq * 4 + 0) * ASTR + rrow] = a4.x;
            As[(kq * 4 + 1) * ASTR + rrow] = a4.y;
            As[(kq * 4 + 2) * ASTR + rrow] = a4.z;
            As[(kq * 4 + 3) * ASTR + rrow] = a4.w;
        }
        for (int id = tid; id < 8 * BN; id += NTHR) {
            int kr = id / (BN / 4), cq = id - kr * (BN / 4);
            *(float4*)&Ws[kr * WSTR + cq * 4] =
                *(const float4*)&W[(size_t)(k0 + kr) * ldw + n0 + cq * 4];
        }
        __syncthreads();
        #pragma unroll 8
        for (int k = 0; k < 32; ++k) {
            float4 a4 = *(const float4*)&As[k * ASTR + ty * 4];
            float4 w4 = *(const float4*)&Ws[k * WSTR + tx * 4];
            float av[4] = {a4.x, a4.y, a4.z, a4.w};
            float wv[4] = {w4.x, w4.y, w4.z, w4.w};
            #pragma unroll
            for (int r = 0; r < 4; ++r)
                #pragma unroll
                for (int j = 0; j < 4; ++j)
                    acc[r][j] += av[r] * wv[j];
        }
    }
    float bv[4] = {0.f, 0.f, 0.f, 0.f};
    if (HASB) {
        #pragma unroll
        for (int j = 0; j < 4; ++j) bv[j] = bias[n0 + tx * 4 + j];
    }
    #pragma unroll
    for (int r = 0; r < 4; ++r) {
        int m = m0 + ty * 4 + r;
        float* cp = &C[(size_t)m * ldc + n0 + tx * 4];
        float v[4];
        #pragma unroll
        for (int j = 0; j < 4; ++j) {
            float a = acc[r][j] + bv[j];
            if (ACT == 1) a = silu(a);
            if (ACT == 2) a = sigm(a);
            v[j] = a;
        }
        if (ACC) {
            float4 old = *(const float4*)cp;
            v[0] += old.x; v[1] += old.y; v[2] += old.z; v[3] += old.w;
        }
        if (GATEMUL) {
            const float* gp = &gate[(size_t)(m / 3) * 128 + n0 + tx * 4];
            #pragma unroll
            for (int j = 0; j < 4; ++j) v[j] *= gp[j];
        }
        float4 res = {v[0], v[1], v[2], v[3]};
        *(float4*)cp = res;
    }
}

// ---------------- fused attention (y1-hoisted, 2 rows/block) ----------------
// qkvb: [row][384] = q|k|v ; y1,o1: [row][c(3)][128] ; o0: [row][128]
// rwg: [16][4] head-reduced rw2 (+ [4] reduced rb2 at offset 64)
__global__ __launch_bounds__(256) void k_attn(
    const float* __restrict__ qkvb, const int* __restrict__ idxv,
    const float* __restrict__ rbfv, const float* __restrict__ uv,
    const float* __restrict__ y1,
    const float* __restrict__ rw1, const float* __restrict__ rb1,
    const float* __restrict__ rw2, const float* __restrict__ rwg,
    const float* __restrict__ rb2,
    float* __restrict__ o0, float* __restrict__ o1)
{
    const int tid = threadIdx.x;
    const int r = tid >> 7, t = tid & 127;
    const int row = blockIdx.x * 2 + r;
    const int b = row >> 12;

    __shared__ float sQ[2][128];
    __shared__ float sHid[2][6][16];
    __shared__ float sU[2][6][3];
    __shared__ float sLog[2][4][6];
    __shared__ float sAttn[2][4][6];
    __shared__ int sJ[2][6];

    // p0: stage q/idx/u + edge-MLP hidden
    sQ[r][t] = qkvb[(size_t)row * 384 + t];
    if (t < 6) sJ[r][t] = idxv[row * 6 + t];
    if (t >= 8 && t < 26) { int i = t - 8; sU[r][i / 3][i % 3] = uv[(size_t)row * 18 + i]; }
    if (t >= 32) {
        int k = (t - 32) >> 4, hh = (t - 32) & 15;
        float a = rb1[hh];
        const float* rb = rbfv + (size_t)(row * 6 + k) * 16;
        #pragma unroll
        for (int rr = 0; rr < 16; ++rr) a += rb[rr] * rw1[rr * 16 + hh];
        sHid[r][k][hh] = silu(a);
    }
    __syncthreads();

    // p1: logits (t<96, 4 lanes per (h,k)) + rv/vj/y1j prefetch (all threads)
    if (t < 96) {
        int g = t >> 2, o = t & 3;
        int h = g / 6, k = g - h * 6;
        const float* kp = qkvb + (size_t)(b * N_ + sJ[r][k]) * 384 + 128 + h * 32 + o * 8;
        float4 qa = *(const float4*)&sQ[r][h * 32 + o * 8];
        float4 qb4 = *(const float4*)&sQ[r][h * 32 + o * 8 + 4];
        float4 ka = *(const float4*)kp;
        float4 kb4 = *(const float4*)(kp + 4);
        float p = qa.x * ka.x + qa.y * ka.y + qa.z * ka.z + qa.w * ka.w
                + qb4.x * kb4.x + qb4.y * kb4.y + qb4.z * kb4.z + qb4.w * kb4.w;
        p += __shfl_down(p, 2, 4);
        p += __shfl_down(p, 1, 4);
        if (o == 0) {
            float bias = rwg[64 + h];
            #pragma unroll
            for (int hh = 0; hh < 16; ++hh) bias += sHid[r][k][hh] * rwg[hh * 4 + h];
            sLog[r][h][k] = p * 0.17677669529663687f + bias;
        }
    }
    float rvk[6], vj[6], y1j[6][3];
    #pragma unroll
    for (int k = 0; k < 6; ++k) {
        float a = rb2[128 + t];
        #pragma unroll
        for (int hh = 0; hh < 16; ++hh) a += sHid[r][k][hh] * rw2[hh * 256 + 128 + t];
        rvk[k] = a;
        size_t nb = (size_t)(b * N_ + sJ[r][k]);
        vj[k] = qkvb[nb * 384 + 256 + t];
        #pragma unroll
        for (int c = 0; c < 3; ++c) y1j[k][c] = y1[nb * 384 + c * 128 + t];
    }
    __syncthreads();

    // p2: softmax (4 threads per row)
    if (t < 4) {
        int h = t;
        float mx = sLog[r][h][0];
        #pragma unroll
        for (int k = 1; k < 6; ++k) mx = fmaxf(mx, sLog[r][h][k]);
        float e[6], smv = 0.f;
        #pragma unroll
        for (int k = 0; k < 6; ++k) { e[k] = expf(sLog[r][h][k] - mx); smv += e[k]; }
        float inv = 1.f / smv;
        #pragma unroll
        for (int k = 0; k < 6; ++k) sAttn[r][h][k] = e[k] * inv;
    }
    __syncthreads();

    // p3: outputs (all 128 threads per row)
    int h = t >> 5;
    float a[6];
    #pragma unroll
    for (int k = 0; k < 6; ++k) a[k] = sAttn[r][h][k];
    float o0v = 0.f;
    #pragma unroll
    for (int k = 0; k < 6; ++k) o0v += a[k] * vj[k] * silu(rvk[k]);
    o0[(size_t)row * 128 + t] = o0v;
    #pragma unroll
    for (int c = 0; c < 3; ++c) {
        float s = 0.f;
        #pragma unroll
        for (int k = 0; k < 6; ++k) s += a[k] * (y1j[k][c] + rvk[k] * sU[r][k][c]);
        o1[(size_t)row * 384 + c * 128 + t] = s;
    }
}

// ---------------- state head copy ----------------
__global__ void k_statecp(const float* __restrict__ sout, float* __restrict__ out)
{
    int g = blockIdx.x * 256 + threadIdx.x;
    if (g >= B_ * NC_ * DIN_) return;
    int c = g & 63, r = g >> 6;
    int b = r / NC_, n = r - b * NC_;
    out[g] = sout[(size_t)(b * N_ + n + 1) * 64 + c];
}

// ---------------- force head ----------------
__global__ void k_force1(const float* __restrict__ x1, const float* __restrict__ W,
                         const float* __restrict__ bias, float* __restrict__ frc)
{
    int g = blockIdx.x * 256 + threadIdx.x;
    if (g >= B_ * NC_ * 3) return;
    int c = g % 3, rr = g / 3;
    int b = rr / NC_, n = rr - b * NC_;
    const float* xr = x1 + (size_t)(b * N_ + n + 1) * 384 + c * 128;
    float a = bias[0];
    for (int d = 0; d < 128; ++d) a += xr[d] * W[d];
    frc[g] = a;
}

__global__ __launch_bounds__(256) void k_fsum(const float* __restrict__ frc, float* __restrict__ fsum)
{
    int b = blockIdx.x / 3, c = blockIdx.x % 3;
    __shared__ float red[256];
    float a = 0.f;
    for (int n = threadIdx.x; n < NC_; n += 256) a += frc[(b * NC_ + n) * 3 + c];
    red[threadIdx.x] = a; __syncthreads();
    for (int st = 128; st > 0; st >>= 1) { if (threadIdx.x < st) red[threadIdx.x] += red[threadIdx.x + st]; __syncthreads(); }
    if (threadIdx.x == 0) fsum[blockIdx.x] = red[0] / (float)NC_;
}

__global__ void k_force2(const float* __restrict__ frc, const float* __restrict__ fsum,
                         float* __restrict__ out)
{
    int g = blockIdx.x * 256 + threadIdx.x;
    if (g >= B_ * NC_ * 3) return;
    int c = g % 3;
    int b = g / (NC_ * 3);
    out[g] = frc[g] - fsum[b * 3 + c];
}

} // namespace

extern "C" void kernel_launch(void* const* d_in, const int* in_sizes, int n_in,
                              void* d_out, int out_size, void* d_ws, size_t ws_size,
                              hipStream_t stream)
{
    const float* X       = (const float*)d_in[0];
    const float* W_embed = (const float*)d_in[1];
    const float* b_embed = (const float*)d_in[2];
    const float* Wq      = (const float*)d_in[3];
    const float* Wk      = (const float*)d_in[4];
    const float* Wv      = (const float*)d_in[5];
    const float* Wvv     = (const float*)d_in[6];
    const float* rw1     = (const float*)d_in[7];
    const float* rb1     = (const float*)d_in[8];
    const float* rw2     = (const float*)d_in[9];
    const float* rb2     = (const float*)d_in[10];
    const float* Wo      = (const float*)d_in[11];
    const float* Wov     = (const float*)d_in[12];
    const float* ff_w1   = (const float*)d_in[13];
    const float* ff_b1   = (const float*)d_in[14];
    const float* ff_w2   = (const float*)d_in[15];
    const float* ff_b2   = (const float*)d_in[16];
    const float* gate_w  = (const float*)d_in[17];
    const float* gate_b  = (const float*)d_in[18];
    const float* ln1_s   = (const float*)d_in[19];
    const float* ln1_b   = (const float*)d_in[20];
    const float* ln2_s   = (const float*)d_in[21];
    const float* ln2_b   = (const float*)d_in[22];
    const float* W_state = (const float*)d_in[23];
    const float* b_state = (const float*)d_in[24];
    const float* W_force = (const float*)d_in[25];
    const float* b_force = (const float*)d_in[26];
    (void)in_sizes; (void)n_in; (void)out_size; (void)ws_size;

    float* out = (float*)d_out;
    float* w = (float*)d_ws;

    float* pos   = w;                          // 49152
    int*   idxv  = (int*)(w + 49152);          // 98304
    float* uv    = w + 147456;                 // 294912
    float* rbfv  = w + 442368;                 // 1572864
    float* feats = w + 2015232;                // 1048576 (reused as sout)
    float* x0    = w + 3063808;                // 2097152
    float* hb    = w + 5160960;                // 2097152
    float* qkvb  = w + 7258112;                // 6291456 (first 4194304 reused as t1)
    float* o0    = w + 13549568;               // 2097152 (reused as gate buffer)
    float* o1    = w + 15646720;               // 6291456
    float* x1    = w + 21938176;               // 6291456
    float* y1    = w + 28229632;               // 6291456
    float* Wcat  = w + 34521088;               // 49152
    float* rwg   = w + 34570240;               // 128
    float* frc   = w + 34570368;               // 49152
    float* fsum  = w + 34619520;               // 16
    float* t1    = qkvb;
    float* gb    = o0;
    float* sout  = feats;

    hipMemsetAsync(x1, 0, (size_t)ROWS_ * 384 * sizeof(float), stream);
    hipMemsetAsync(y1, 0, (size_t)ROWS_ * 384 * sizeof(float), stream);

    k_prep<<<(ROWS_ + 255) / 256, 256, 0, stream>>>(X, pos);
    k_feats<<<(ROWS_ * DIN_ + 255) / 256, 256, 0, stream>>>(X, feats);
    k_knn<<<ROWS_ / 4, 256, 0, stream>>>(pos, idxv);
    k_geom<<<(ROWS_ * K_ + 255) / 256, 256, 0, stream>>>(pos, idxv, uv, rbfv);
    // x0 = feats @ W_embed + b_embed
    k_tgemm<64, 32, 128, 0, false, true, false><<<dim3(512, 1), 256, 0, stream>>>(
        feats, W_embed, b_embed, nullptr, x0, 128, 128);

    for (int l = 0; l < 2; ++l) {
        const float* Wq_l  = Wq + l * 16384;
        const float* Wk_l  = Wk + l * 16384;
        const float* Wv_l  = Wv + l * 16384;
        const float* Wvv_l = Wvv + l * 16384;
        const float* Wo_l  = Wo + l * 16384;
        const float* Wov_l = Wov + l * 16384;
        const float* rw1_l = rw1 + l * 256;
        const float* rb1_l = rb1 + l * 16;
        const float* rw2_l = rw2 + l * 4096;
        const float* rb2_l = rb2 + l * 256;
        const float* fw1_l = ff_w1 + l * 32768;
        const float* fb1_l = ff_b1 + l * 256;
        const float* fw2_l = ff_w2 + l * 32768;
        const float* fb2_l = ff_b2 + l * 128;
        const float* gw_l  = gate_w + l * 16384;
        const float* gb_l  = gate_b + l * 128;

        // h = LN1(x0)
        k_ln<<<ROWS_ / 4, 256, 0, stream>>>(x0, ln1_s + l * 128, ln1_b + l * 128, hb);
        // weight prep: Wcat = [Wq|Wk|Wv], rwg = head-reduced rw2/rb2
        k_prepw<<<193, 256, 0, stream>>>(Wq_l, Wk_l, Wv_l, rw2_l, rb2_l, Wcat, rwg);
        // qkv = h @ Wcat
        k_tgemm<128, 64, 128, 0, false, false, false><<<dim3(256, 3), 512, 0, stream>>>(
            hb, Wcat, nullptr, nullptr, qkvb, 384, 384);
        // y1 = x1 @ Wvv  (layer 0: x1 = 0 -> y1 memset'd)
        if (l > 0)
            k_tgemm<128, 64, 128, 0, false, false, false><<<dim3(768, 1), 512, 0, stream>>>(
                x1, Wvv_l, nullptr, nullptr, y1, 128, 128);
        // attention
        k_attn<<<ROWS_ / 2, 256, 0, stream>>>(qkvb, idxv, rbfv, uv, y1,
                                              rw1_l, rb1_l, rw2_l, rwg, rb2_l, o0, o1);
        // x0 += out0 @ Wo
        k_tgemm<128, 32, 128, 0, true, false, false><<<dim3(512, 1), 256, 0, stream>>>(
            o0, Wo_l, nullptr, nullptr, x0, 128, 128);
        // h2 = LN2(x0)
        k_ln<<<ROWS_ / 4, 256, 0, stream>>>(x0, ln2_s + l * 128, ln2_b + l * 128, hb);
        // gate = sigmoid(h2 @ gate_w + gate_b)
        k_tgemm<128, 32, 128, 2, false, true, false><<<dim3(512, 1), 256, 0, stream>>>(
            hb, gw_l, gb_l, nullptr, gb, 128, 128);
        // x1 = (x1 + o1 @ Wov) * gate
        k_tgemm<128, 64, 128, 0, true, false, true><<<dim3(768, 1), 512, 0, stream>>>(
            o1, Wov_l, nullptr, gb, x1, 128, 128);
        // ff
        k_tgemm<128, 64, 128, 1, false, true, false><<<dim3(256, 2), 512, 0, stream>>>(
            hb, fw1_l, fb1_l, nullptr, t1, 256, 256);
        k_tgemm<256, 32, 128, 0, true, true, false><<<dim3(512, 1), 256, 0, stream>>>(
            t1, fw2_l, fb2_l, nullptr, x0, 128, 128);
    }

    // state head
    k_tgemm<128, 32, 64, 0, false, true, false><<<dim3(512, 1), 128, 0, stream>>>(
        x0, W_state, b_state, nullptr, sout, 64, 64);
    k_statecp<<<(B_ * NC_ * DIN_ + 255) / 256, 256, 0, stream>>>(sout, out);
    // force head
    k_force1<<<(B_ * NC_ * 3 + 255) / 256, 256, 0, stream>>>(x1, W_force, b_force, frc);
    k_fsum<<<12, 256, 0, stream>>>(frc, fsum);
    k_force2<<<(B_ * NC_ * 3 + 255) / 256, 256, 0, stream>>>(frc, fsum, out + (size_t)B_ * NC_ * DIN_);
}

// Round 5
// 565.721 us; speedup vs baseline: 3.4502x; 1.0181x over previous
//
#include <hip/hip_runtime.h>
#include <cstdint>
#include <cstddef>

namespace {

constexpr int B_ = 4, NC_ = 4095, N_ = 4096, DIN_ = 64, D_ = 128, K_ = 6;
constexpr int XROW_ = 6 + DIN_;   // 70
constexpr int ROWS_ = B_ * N_;    // 16384

__device__ __forceinline__ float sigm(float x) { return 1.f / (1.f + expf(-x)); }
__device__ __forceinline__ float silu(float x) { return x / (1.f + expf(-x)); }

// ---------------- prep: pos4 + feats ----------------
__global__ void k_prep(const float* __restrict__ X, float4* __restrict__ pos4,
                       float* __restrict__ feats)
{
    int g = blockIdx.x * 256 + threadIdx.x;
    if (g >= ROWS_ * 64) return;
    int c = g & 63, row = g >> 6;
    int b = row >> 12, n = row & (N_ - 1);
    const float* xr = X + (size_t)(b * NC_ + n - 1) * XROW_;
    feats[g] = (n > 0) ? xr[6 + c] : 0.f;
    if (c == 0) {
        float4 p = {0.f, 0.f, 0.f, 0.f};
        if (n > 0) { p.x = xr[0]; p.y = xr[1]; p.z = xr[2]; }
        pos4[row] = p;
    }
}

// ---------------- KNN: two-phase (threshold, then gated exact top-6) ----------------
__device__ __forceinline__ unsigned long long shflxor64(unsigned long long v, int mask)
{
    int lo = __shfl_xor((int)(unsigned)(v & 0xffffffffull), mask, 64);
    int hi = __shfl_xor((int)(unsigned)(v >> 32), mask, 64);
    return ((unsigned long long)(unsigned)hi << 32) | (unsigned)lo;
}

__global__ __launch_bounds__(256) void k_knn(const float4* __restrict__ pos4, int* __restrict__ idxv)
{
    const int wave = (blockIdx.x << 2) | (threadIdx.x >> 6);
    const int lane = threadIdx.x & 63;
    const int b = wave >> 12, i = wave & (N_ - 1);
    const float4* pb = pos4 + (size_t)b * N_;
    const float4 q = pb[i];
    const float BIG = 3.4e38f;

    // phase 1: per-lane min d2 (excluding self)
    float dmin = BIG;
    #pragma unroll 8
    for (int it = 0; it < 64; ++it) {
        int j = lane + it * 64;
        float4 p = pb[j];
        float dx = p.x - q.x, dy = p.y - q.y, dz = p.z - q.z;
        float dd = dx * dx + dy * dy + dz * dz;
        if (j != i) dmin = fminf(dmin, dd);
    }
    // T = 6th smallest of lane minima (dup removal only raises T: safe upper bound)
    float T;
    {
        float v = dmin, kth = BIG;
        #pragma unroll
        for (int r = 0; r < 6; ++r) {
            float m = v;
            #pragma unroll
            for (int off = 1; off < 64; off <<= 1) m = fminf(m, __shfl_xor(m, off, 64));
            kth = m;
            if (v == m) v = BIG;
        }
        T = kth * 1.000002f;   // absorb recompute rounding
    }

    // phase 2: exact per-lane sorted top-6, gated by T
    float e0 = BIG, e1 = BIG, e2 = BIG, e3 = BIG, e4 = BIG, e5 = BIG;
    int j0 = 0, j1 = 0, j2 = 0, j3 = 0, j4 = 0, j5 = 0;
    #pragma unroll 4
    for (int it = 0; it < 64; ++it) {
        int j = lane + it * 64;
        float4 p = pb[j];
        float dx = p.x - q.x, dy = p.y - q.y, dz = p.z - q.z;
        float dd = dx * dx + dy * dy + dz * dz;
        if (dd <= T && j != i && dd < e5) {
            e5 = dd; j5 = j;
            float td; int tj;
            if (e5 < e4) { td = e4; e4 = e5; e5 = td; tj = j4; j4 = j5; j5 = tj; }
            if (e4 < e3) { td = e3; e3 = e4; e4 = td; tj = j3; j3 = j4; j4 = tj; }
            if (e3 < e2) { td = e2; e2 = e3; e3 = td; tj = j2; j2 = j3; j3 = tj; }
            if (e2 < e1) { td = e1; e1 = e2; e2 = td; tj = j1; j1 = j2; j2 = tj; }
            if (e1 < e0) { td = e0; e0 = e1; e1 = td; tj = j0; j0 = j1; j1 = tj; }
        }
    }

    // merge across lanes by 64-bit key (d2bits<<32 | j): exact, ties -> smaller j
    unsigned long long a0 = ((unsigned long long)__float_as_uint(e0) << 32) | (unsigned)j0;
    unsigned long long a1 = ((unsigned long long)__float_as_uint(e1) << 32) | (unsigned)j1;
    unsigned long long a2 = ((unsigned long long)__float_as_uint(e2) << 32) | (unsigned)j2;
    unsigned long long a3 = ((unsigned long long)__float_as_uint(e3) << 32) | (unsigned)j3;
    unsigned long long a4 = ((unsigned long long)__float_as_uint(e4) << 32) | (unsigned)j4;
    unsigned long long a5 = ((unsigned long long)__float_as_uint(e5) << 32) | (unsigned)j5;
    #pragma unroll
    for (int k = 0; k < K_; ++k) {
        unsigned long long m = a0;
        #pragma unroll
        for (int off = 1; off < 64; off <<= 1) {
            unsigned long long o = shflxor64(m, off);
            if (o < m) m = o;
        }
        if (a0 == m) { a0 = a1; a1 = a2; a2 = a3; a3 = a4; a4 = a5; a5 = ~0ull; }
        if (lane == 0) idxv[wave * K_ + k] = (int)(unsigned)(m & 0xffffffffull);
    }
}

// ---------------- geom: u, rbf per edge ----------------
__global__ void k_geom(const float4* __restrict__ pos4, const int* __restrict__ idxv,
                       float* __restrict__ uv, float* __restrict__ rbfv)
{
    int g = blockIdx.x * 256 + threadIdx.x;
    if (g >= ROWS_ * K_) return;
    int b = g / (N_ * K_);
    int rem = g - b * N_ * K_;
    int n = rem / K_;
    int j = idxv[g];
    const float4* pb = pos4 + (size_t)b * N_;
    float4 pj = pb[j], pn = pb[n];
    float rx = pj.x - pn.x, ry = pj.y - pn.y, rz = pj.z - pn.z;
    float dist = sqrtf(rx * rx + ry * ry + rz * rz + 1e-8f);
    float inv = 1.f / dist;
    uv[g * 3 + 0] = rx * inv; uv[g * 3 + 1] = ry * inv; uv[g * 3 + 2] = rz * inv;
    for (int r = 0; r < 16; ++r) {
        float t = (dist - (4.0f / 15.0f) * r) * 4.0f;
        rbfv[g * 16 + r] = expf(-t * t);
    }
}

// ---------------- LayerNorm: wave per row ----------------
__global__ __launch_bounds__(256) void k_ln(const float* __restrict__ x,
                                            const float* __restrict__ s, const float* __restrict__ bb,
                                            float* __restrict__ o)
{
    int w = threadIdx.x >> 6, lane = threadIdx.x & 63;
    size_t row = (size_t)blockIdx.x * 4 + w;
    const float* xr = x + row * 128;
    float v0 = xr[lane], v1 = xr[lane + 64];
    float sm = v0 + v1, sq = v0 * v0 + v1 * v1;
    #pragma unroll
    for (int off = 32; off; off >>= 1) {
        sm += __shfl_xor(sm, off, 64);
        sq += __shfl_xor(sq, off, 64);
    }
    float m = sm * (1.f / 128.f);
    float var = sq * (1.f / 128.f) - m * m;
    float inv = 1.f / sqrtf(var + 1e-5f);
    o[row * 128 + lane]      = (v0 - m) * inv * s[lane]      + bb[lane];
    o[row * 128 + lane + 64] = (v1 - m) * inv * s[lane + 64] + bb[lane + 64];
}

// ---------------- per-layer weight prep ----------------
// Wcat=[Wq|Wk|Wv] (128x384); Wcat2=[gate_w|ff_w1] (128x384); bias2=[gate_b|ff_b1]; rwg
__global__ void k_prepw(const float* __restrict__ Wq, const float* __restrict__ Wk,
                        const float* __restrict__ Wv, const float* __restrict__ gw,
                        const float* __restrict__ fw1, const float* __restrict__ gb,
                        const float* __restrict__ fb1, const float* __restrict__ rw2,
                        const float* __restrict__ rb2,
                        float* __restrict__ Wcat, float* __restrict__ Wcat2,
                        float* __restrict__ bias2, float* __restrict__ rwg)
{
    int bid = blockIdx.x;
    if (bid < 192) {
        int i = bid * 256 + threadIdx.x;
        int k = i / 384, c = i - k * 384;
        float v;
        if (c < 128)      v = Wq[k * 128 + c];
        else if (c < 256) v = Wk[k * 128 + c - 128];
        else              v = Wv[k * 128 + c - 256];
        Wcat[i] = v;
    } else if (bid < 384) {
        int i = (bid - 192) * 256 + threadIdx.x;
        int k = i / 384, c = i - k * 384;
        Wcat2[i] = (c < 128) ? gw[k * 128 + c] : fw1[k * 256 + c - 128];
    } else {
        int t = threadIdx.x;
        if (t < 64) {
            int hh = t >> 2, h = t & 3;
            float a = 0.f;
            #pragma unroll
            for (int dh = 0; dh < 32; ++dh) a += rw2[hh * 256 + h * 32 + dh];
            rwg[t] = a * (1.f / 32.f);
        } else if (t < 68) {
            int h = t - 64;
            float a = 0.f;
            #pragma unroll
            for (int dh = 0; dh < 32; ++dh) a += rb2[h * 32 + dh];
            rwg[64 + h] = a * (1.f / 32.f);
        } else if (t >= 128 && t < 128 + 384) {
            int c = t - 128;
            bias2[c] = (c < 128) ? gb[c] : fb1[c - 128];
        }
    }
}

// ---------------- tiled fp32 GEMM: BM=128, BN=64, 256 thr, 8x4/thread ----------------
// ACT: 0 none, 1 silu, 2 sigmoid, 3 split(gate|ff1 -> C:sigmoid ldc128 / C2:silu ldc256)
// aux: gate buffer (GATEMUL) or C2 (ACT==3)
template<int KD, int ACT, bool ACC, bool HASB, bool GATEMUL, bool STATEMAP>
__global__ __launch_bounds__(256) void k_tgemm(
    const float* __restrict__ A, const float* __restrict__ W, const float* __restrict__ bias,
    const float* __restrict__ aux, float* __restrict__ C, int ldw, int ldc)
{
    __shared__ __align__(16) float As[32 * 132];
    __shared__ __align__(16) float Ws[32 * 68];
    const int tid = threadIdx.x;
    const int tx = tid & 15, ty = tid >> 4;
    const int m0 = blockIdx.x * 128, n0 = blockIdx.y * 64;
    float acc[8][4] = {};
    for (int k0 = 0; k0 < KD; k0 += 32) {
        __syncthreads();
        #pragma unroll
        for (int r = 0; r < 4; ++r) {
            int id = tid + r * 256;
            int row = id >> 3, kq = id & 7;
            float4 a4 = *(const float4*)&A[(size_t)(m0 + row) * KD + k0 + kq * 4];
            As[(kq * 4 + 0) * 132 + row] = a4.x;
            As[(kq * 4 + 1) * 132 + row] = a4.y;
            As[(kq * 4 + 2) * 132 + row] = a4.z;
            As[(kq * 4 + 3) * 132 + row] = a4.w;
        }
        #pragma unroll
        for (int r = 0; r < 2; ++r) {
            int id = tid + r * 256;
            int kr = id >> 4, cq = id & 15;
            *(float4*)&Ws[kr * 68 + cq * 4] =
                *(const float4*)&W[(size_t)(k0 + kr) * ldw + n0 + cq * 4];
        }
        __syncthreads();
        #pragma unroll 8
        for (int k = 0; k < 32; ++k) {
            float4 aA = *(const float4*)&As[k * 132 + ty * 8];
            float4 aB = *(const float4*)&As[k * 132 + ty * 8 + 4];
            float4 w4 = *(const float4*)&Ws[k * 68 + tx * 4];
            float av[8] = {aA.x, aA.y, aA.z, aA.w, aB.x, aB.y, aB.z, aB.w};
            float wv[4] = {w4.x, w4.y, w4.z, w4.w};
            #pragma unroll
            for (int r = 0; r < 8; ++r)
                #pragma unroll
                for (int j = 0; j < 4; ++j)
                    acc[r][j] += av[r] * wv[j];
        }
    }
    float bv[4] = {0.f, 0.f, 0.f, 0.f};
    if (HASB) {
        #pragma unroll
        for (int j = 0; j < 4; ++j) bv[j] = bias[n0 + tx * 4 + j];
    }
    #pragma unroll
    for (int r = 0; r < 8; ++r) {
        int m = m0 + ty * 8 + r;
        float v[4];
        #pragma unroll
        for (int j = 0; j < 4; ++j) {
            float a = acc[r][j] + bv[j];
            if (ACT == 1) a = silu(a);
            if (ACT == 2) a = sigm(a);
            if (ACT == 3) a = (n0 < 128) ? sigm(a) : silu(a);
            v[j] = a;
        }
        if (ACT == 3) {
            float* dst = (n0 < 128)
                ? (C + (size_t)m * 128 + n0 + tx * 4)
                : ((float*)aux + (size_t)m * 256 + (n0 - 128) + tx * 4);
            float4 res = {v[0], v[1], v[2], v[3]};
            *(float4*)dst = res;
            continue;
        }
        if (STATEMAP) {
            int n = m & (N_ - 1), bb2 = m >> 12;
            if (n == 0) continue;
            float* dst = C + ((size_t)(bb2 * NC_ + n - 1)) * ldc + n0 + tx * 4;
            float4 res = {v[0], v[1], v[2], v[3]};
            *(float4*)dst = res;
            continue;
        }
        float* cp = &C[(size_t)m * ldc + n0 + tx * 4];
        if (ACC) {
            float4 old = *(const float4*)cp;
            v[0] += old.x; v[1] += old.y; v[2] += old.z; v[3] += old.w;
        }
        if (GATEMUL) {
            const float* gp = &((const float*)aux)[(size_t)(m / 3) * 128 + n0 + tx * 4];
            #pragma unroll
            for (int j = 0; j < 4; ++j) v[j] *= gp[j];
        }
        float4 res = {v[0], v[1], v[2], v[3]};
        *(float4*)cp = res;
    }
}

// ---------------- fused attention (y1-hoisted, 2 rows/block) ----------------
__global__ __launch_bounds__(256) void k_attn(
    const float* __restrict__ qkvb, const int* __restrict__ idxv,
    const float* __restrict__ rbfv, const float* __restrict__ uv,
    const float* __restrict__ y1,
    const float* __restrict__ rw1, const float* __restrict__ rb1,
    const float* __restrict__ rw2, const float* __restrict__ rwg,
    const float* __restrict__ rb2,
    float* __restrict__ o0, float* __restrict__ o1)
{
    const int tid = threadIdx.x;
    const int r = tid >> 7, t = tid & 127;
    const int row = blockIdx.x * 2 + r;
    const int b = row >> 12;

    __shared__ float sQ[2][128];
    __shared__ float sHid[2][6][16];
    __shared__ float sU[2][6][3];
    __shared__ float sLog[2][4][6];
    __shared__ float sAttn[2][4][6];
    __shared__ int sJ[2][6];

    sQ[r][t] = qkvb[(size_t)row * 384 + t];
    if (t < 6) sJ[r][t] = idxv[row * 6 + t];
    if (t >= 8 && t < 26) { int i = t - 8; sU[r][i / 3][i % 3] = uv[(size_t)row * 18 + i]; }
    if (t >= 32) {
        int k = (t - 32) >> 4, hh = (t - 32) & 15;
        float a = rb1[hh];
        const float* rb = rbfv + (size_t)(row * 6 + k) * 16;
        #pragma unroll
        for (int rr = 0; rr < 16; ++rr) a += rb[rr] * rw1[rr * 16 + hh];
        sHid[r][k][hh] = silu(a);
    }
    __syncthreads();

    if (t < 96) {
        int g = t >> 2, o = t & 3;
        int h = g / 6, k = g - h * 6;
        const float* kp = qkvb + (size_t)(b * N_ + sJ[r][k]) * 384 + 128 + h * 32 + o * 8;
        float4 qa = *(const float4*)&sQ[r][h * 32 + o * 8];
        float4 qb4 = *(const float4*)&sQ[r][h * 32 + o * 8 + 4];
        float4 ka = *(const float4*)kp;
        float4 kb4 = *(const float4*)(kp + 4);
        float p = qa.x * ka.x + qa.y * ka.y + qa.z * ka.z + qa.w * ka.w
                + qb4.x * kb4.x + qb4.y * kb4.y + qb4.z * kb4.z + qb4.w * kb4.w;
        p += __shfl_down(p, 2, 4);
        p += __shfl_down(p, 1, 4);
        if (o == 0) {
            float bias = rwg[64 + h];
            #pragma unroll
            for (int hh = 0; hh < 16; ++hh) bias += sHid[r][k][hh] * rwg[hh * 4 + h];
            sLog[r][h][k] = p * 0.17677669529663687f + bias;
        }
    }
    float rw2c[16];
    #pragma unroll
    for (int hh = 0; hh < 16; ++hh) rw2c[hh] = rw2[hh * 256 + 128 + t];
    float rvk[6], vj[6], y1j[6][3];
    float rb2t = rb2[128 + t];
    #pragma unroll
    for (int k = 0; k < 6; ++k) {
        float a = rb2t;
        #pragma unroll
        for (int hh = 0; hh < 16; ++hh) a += sHid[r][k][hh] * rw2c[hh];
        rvk[k] = a;
        size_t nb = (size_t)(b * N_ + sJ[r][k]);
        vj[k] = qkvb[nb * 384 + 256 + t];
        #pragma unroll
        for (int c = 0; c < 3; ++c) y1j[k][c] = y1[nb * 384 + c * 128 + t];
    }
    __syncthreads();

    if (t < 4) {
        int h = t;
        float mx = sLog[r][h][0];
        #pragma unroll
        for (int k = 1; k < 6; ++k) mx = fmaxf(mx, sLog[r][h][k]);
        float e[6], smv = 0.f;
        #pragma unroll
        for (int k = 0; k < 6; ++k) { e[k] = expf(sLog[r][h][k] - mx); smv += e[k]; }
        float inv = 1.f / smv;
        #pragma unroll
        for (int k = 0; k < 6; ++k) sAttn[r][h][k] = e[k] * inv;
    }
    __syncthreads();

    int h = t >> 5;
    float a[6];
    #pragma unroll
    for (int k = 0; k < 6; ++k) a[k] = sAttn[r][h][k];
    float o0v = 0.f;
    #pragma unroll
    for (int k = 0; k < 6; ++k) o0v += a[k] * vj[k] * silu(rvk[k]);
    o0[(size_t)row * 128 + t] = o0v;
    #pragma unroll
    for (int c = 0; c < 3; ++c) {
        float s = 0.f;
        #pragma unroll
        for (int k = 0; k < 6; ++k) s += a[k] * (y1j[k][c] + rvk[k] * sU[r][k][c]);
        o1[(size_t)row * 384 + c * 128 + t] = s;
    }
}

// ---------------- force head ----------------
__global__ void k_force1(const float* __restrict__ x1, const float* __restrict__ W,
                         const float* __restrict__ bias, float* __restrict__ frc)
{
    int g = blockIdx.x * 256 + threadIdx.x;
    if (g >= B_ * NC_ * 3) return;
    int c = g % 3, rr = g / 3;
    int b = rr / NC_, n = rr - b * NC_;
    const float* xr = x1 + (size_t)(b * N_ + n + 1) * 384 + c * 128;
    float a = bias[0];
    for (int d = 0; d < 128; ++d) a += xr[d] * W[d];
    frc[g] = a;
}

__global__ __launch_bounds__(256) void k_fsum(const float* __restrict__ frc, float* __restrict__ fsum)
{
    int b = blockIdx.x / 3, c = blockIdx.x % 3;
    __shared__ float red[256];
    float a = 0.f;
    for (int n = threadIdx.x; n < NC_; n += 256) a += frc[(b * NC_ + n) * 3 + c];
    red[threadIdx.x] = a; __syncthreads();
    for (int st = 128; st > 0; st >>= 1) { if (threadIdx.x < st) red[threadIdx.x] += red[threadIdx.x + st]; __syncthreads(); }
    if (threadIdx.x == 0) fsum[blockIdx.x] = red[0] / (float)NC_;
}

__global__ void k_force2(const float* __restrict__ frc, const float* __restrict__ fsum,
                         float* __restrict__ out)
{
    int g = blockIdx.x * 256 + threadIdx.x;
    if (g >= B_ * NC_ * 3) return;
    int c = g % 3;
    int b = g / (NC_ * 3);
    out[g] = frc[g] - fsum[b * 3 + c];
}

} // namespace

extern "C" void kernel_launch(void* const* d_in, const int* in_sizes, int n_in,
                              void* d_out, int out_size, void* d_ws, size_t ws_size,
                              hipStream_t stream)
{
    const float* X       = (const float*)d_in[0];
    const float* W_embed = (const float*)d_in[1];
    const float* b_embed = (const float*)d_in[2];
    const float* Wq      = (const float*)d_in[3];
    const float* Wk      = (const float*)d_in[4];
    const float* Wv      = (const float*)d_in[5];
    const float* Wvv     = (const float*)d_in[6];
    const float* rw1     = (const float*)d_in[7];
    const float* rb1     = (const float*)d_in[8];
    const float* rw2     = (const float*)d_in[9];
    const float* rb2     = (const float*)d_in[10];
    const float* Wo      = (const float*)d_in[11];
    const float* Wov     = (const float*)d_in[12];
    const float* ff_w1   = (const float*)d_in[13];
    const float* ff_b1   = (const float*)d_in[14];
    const float* ff_w2   = (const float*)d_in[15];
    const float* ff_b2   = (const float*)d_in[16];
    const float* gate_w  = (const float*)d_in[17];
    const float* gate_b  = (const float*)d_in[18];
    const float* ln1_s   = (const float*)d_in[19];
    const float* ln1_b   = (const float*)d_in[20];
    const float* ln2_s   = (const float*)d_in[21];
    const float* ln2_b   = (const float*)d_in[22];
    const float* W_state = (const float*)d_in[23];
    const float* b_state = (const float*)d_in[24];
    const float* W_force = (const float*)d_in[25];
    const float* b_force = (const float*)d_in[26];
    (void)in_sizes; (void)n_in; (void)out_size; (void)ws_size;

    float* out = (float*)d_out;
    float* w = (float*)d_ws;

    float4* pos4 = (float4*)w;                 // 65536 floats
    int*   idxv  = (int*)(w + 65536);          // 98304
    float* uv    = w + 163840;                 // 294912
    float* rbfv  = w + 458752;                 // 1572864
    float* feats = w + 2031616;                // 1048576 (later: frc/fsum)
    float* x0    = w + 3080192;                // 2097152
    float* hb    = w + 5177344;                // 2097152
    float* qkvb  = w + 7274496;                // 6291456 (t1 alias)
    float* o0    = w + 13565952;               // 2097152 (gb alias)
    float* o1    = w + 15663104;               // 6291456
    float* x1    = w + 21954560;               // 6291456
    float* y1    = w + 28246016;               // 6291456
    float* Wcat2 = w + 34537472;               // 49152
    float* bias2 = w + 34586624;               // 384
    float* rwg   = w + 34587008;               // 128
    float* Wcat  = (float*)pos4;               // alias: pos4 dead after k_geom
    float* t1    = qkvb;
    float* gb    = o0;
    float* frc   = feats;                      // alias: feats dead after embed
    float* fsum  = feats + 49152;

    hipMemsetAsync(x1, 0, (size_t)ROWS_ * 384 * sizeof(float), stream);
    hipMemsetAsync(y1, 0, (size_t)ROWS_ * 384 * sizeof(float), stream);

    k_prep<<<(ROWS_ * 64 + 255) / 256, 256, 0, stream>>>(X, pos4, feats);
    k_knn<<<ROWS_ / 4, 256, 0, stream>>>(pos4, idxv);
    k_geom<<<(ROWS_ * K_ + 255) / 256, 256, 0, stream>>>(pos4, idxv, uv, rbfv);
    // x0 = feats @ W_embed + b_embed
    k_tgemm<64, 0, false, true, false, false><<<dim3(128, 2), 256, 0, stream>>>(
        feats, W_embed, b_embed, nullptr, x0, 128, 128);

    for (int l = 0; l < 2; ++l) {
        const float* Wq_l  = Wq + l * 16384;
        const float* Wk_l  = Wk + l * 16384;
        const float* Wv_l  = Wv + l * 16384;
        const float* Wvv_l = Wvv + l * 16384;
        const float* Wo_l  = Wo + l * 16384;
        const float* Wov_l = Wov + l * 16384;
        const float* rw1_l = rw1 + l * 256;
        const float* rb1_l = rb1 + l * 16;
        const float* rw2_l = rw2 + l * 4096;
        const float* rb2_l = rb2 + l * 256;
        const float* fw1_l = ff_w1 + l * 32768;
        const float* fb1_l = ff_b1 + l * 256;
        const float* fw2_l = ff_w2 + l * 32768;
        const float* fb2_l = ff_b2 + l * 128;
        const float* gw_l  = gate_w + l * 16384;
        const float* gb_l  = gate_b + l * 128;

        // h = LN1(x0)
        k_ln<<<ROWS_ / 4, 256, 0, stream>>>(x0, ln1_s + l * 128, ln1_b + l * 128, hb);
        // weight prep
        k_prepw<<<385, 256, 0, stream>>>(Wq_l, Wk_l, Wv_l, gw_l, fw1_l, gb_l, fb1_l,
                                         rw2_l, rb2_l, Wcat, Wcat2, bias2, rwg);
        // qkv = h @ Wcat
        k_tgemm<128, 0, false, false, false, false><<<dim3(128, 6), 256, 0, stream>>>(
            hb, Wcat, nullptr, nullptr, qkvb, 384, 384);
        // y1 = x1 @ Wvv  (layer 0: memset)
        if (l > 0)
            k_tgemm<128, 0, false, false, false, false><<<dim3(384, 2), 256, 0, stream>>>(
                x1, Wvv_l, nullptr, nullptr, y1, 128, 128);
        // attention
        k_attn<<<ROWS_ / 2, 256, 0, stream>>>(qkvb, idxv, rbfv, uv, y1,
                                              rw1_l, rb1_l, rw2_l, rwg, rb2_l, o0, o1);
        // x0 += o0 @ Wo
        k_tgemm<128, 0, true, false, false, false><<<dim3(128, 2), 256, 0, stream>>>(
            o0, Wo_l, nullptr, nullptr, x0, 128, 128);
        // h2 = LN2(x0)
        k_ln<<<ROWS_ / 4, 256, 0, stream>>>(x0, ln2_s + l * 128, ln2_b + l * 128, hb);
        // [gate | t1] = h2 @ Wcat2 (split: sigmoid | silu)
        k_tgemm<128, 3, false, true, false, false><<<dim3(128, 6), 256, 0, stream>>>(
            hb, Wcat2, bias2, t1, gb, 384, 128);
        // x1 = (x1 + o1 @ Wov) * gate
        k_tgemm<128, 0, true, false, true, false><<<dim3(384, 2), 256, 0, stream>>>(
            o1, Wov_l, nullptr, gb, x1, 128, 128);
        // x0 += silu-ff
        k_tgemm<256, 0, true, true, false, false><<<dim3(128, 2), 256, 0, stream>>>(
            t1, fw2_l, fb2_l, nullptr, x0, 128, 128);
    }

    // state head -> out (row-remapped)
    k_tgemm<128, 0, false, true, false, true><<<dim3(128, 1), 256, 0, stream>>>(
        x0, W_state, b_state, nullptr, out, 64, 64);
    // force head
    k_force1<<<(B_ * NC_ * 3 + 255) / 256, 256, 0, stream>>>(x1, W_force, b_force, frc);
    k_fsum<<<12, 256, 0, stream>>>(frc, fsum);
    k_force2<<<(B_ * NC_ * 3 + 255) / 256, 256, 0, stream>>>(frc, fsum, out + (size_t)B_ * NC_ * DIN_);
}

// Round 6
// 471.123 us; speedup vs baseline: 4.1430x; 1.2008x over previous
//
#include <hip/hip_runtime.h>
#include <cstdint>
#include <cstddef>

namespace {

constexpr int B_ = 4, NC_ = 4095, N_ = 4096, DIN_ = 64, D_ = 128, K_ = 6;
constexpr int XROW_ = 6 + DIN_;   // 70
constexpr int ROWS_ = B_ * N_;    // 16384

typedef unsigned short u16;
typedef unsigned int u32;
typedef __attribute__((ext_vector_type(8))) short short8;
typedef __attribute__((ext_vector_type(4))) float f32x4;

__device__ __forceinline__ float sigm(float x) { return 1.f / (1.f + expf(-x)); }
__device__ __forceinline__ float silu(float x) { return x / (1.f + expf(-x)); }
__device__ __forceinline__ u16 f2bf(float x) {
    u32 u = __float_as_uint(x);
    u += 0x7FFFu + ((u >> 16) & 1u);
    return (u16)(u >> 16);
}

// ---------------- prep: pos4 + feats(bf16) ----------------
__global__ void k_prep(const float* __restrict__ X, float4* __restrict__ pos4,
                       u16* __restrict__ featsb)
{
    int g = blockIdx.x * 256 + threadIdx.x;
    if (g >= ROWS_ * 64) return;
    int c = g & 63, row = g >> 6;
    int b = row >> 12, n = row & (N_ - 1);
    const float* xr = X + (size_t)(b * NC_ + n - 1) * XROW_;
    featsb[g] = (n > 0) ? f2bf(xr[6 + c]) : (u16)0;
    if (c == 0) {
        float4 p = {0.f, 0.f, 0.f, 0.f};
        if (n > 0) { p.x = xr[0]; p.y = xr[1]; p.z = xr[2]; }
        pos4[row] = p;
    }
}

// ---------------- KNN: 4 queries per wave, two-phase ----------------
__device__ __forceinline__ unsigned long long shflxor64(unsigned long long v, int mask)
{
    int lo = __shfl_xor((int)(unsigned)(v & 0xffffffffull), mask, 64);
    int hi = __shfl_xor((int)(unsigned)(v >> 32), mask, 64);
    return ((unsigned long long)(unsigned)hi << 32) | (unsigned)lo;
}

__device__ __forceinline__ float kth6min(float v)
{
    const float BIG = 3.4e38f;
    float kth = BIG;
    #pragma unroll
    for (int r = 0; r < 6; ++r) {
        float m = v;
        #pragma unroll
        for (int off = 1; off < 64; off <<= 1) m = fminf(m, __shfl_xor(m, off, 64));
        kth = m;
        if (v == m) v = BIG;   // dedup: only raises the bound (safe)
    }
    return kth;
}

__global__ __launch_bounds__(256) void k_knn(const float4* __restrict__ pos4, int* __restrict__ idxv)
{
    const int w4 = (blockIdx.x << 2) | (threadIdx.x >> 6);
    const int lane = threadIdx.x & 63;
    const int b = w4 >> 10;
    const int i0 = (w4 & 1023) << 2;
    const float4* pb = pos4 + (size_t)b * N_;
    const float BIG = 3.4e38f;

    float4 qv[4];
    #pragma unroll
    for (int qq = 0; qq < 4; ++qq) qv[qq] = pb[i0 + qq];

    // phase 1: per-lane min d2 per query
    float dmin[4] = {BIG, BIG, BIG, BIG};
    #pragma unroll 4
    for (int it = 0; it < 64; ++it) {
        int j = lane + (it << 6);
        float4 p = pb[j];
        #pragma unroll
        for (int qq = 0; qq < 4; ++qq) {
            float dx = p.x - qv[qq].x, dy = p.y - qv[qq].y, dz = p.z - qv[qq].z;
            float dd = dx * dx + dy * dy + dz * dz;
            if (j != i0 + qq) dmin[qq] = fminf(dmin[qq], dd);
        }
    }
    float T[4];
    #pragma unroll
    for (int qq = 0; qq < 4; ++qq) T[qq] = kth6min(dmin[qq]) * 1.000002f;

    // phase 2: exact gated per-lane top-6 per query
    float e[4][6]; int jj[4][6];
    #pragma unroll
    for (int qq = 0; qq < 4; ++qq)
        #pragma unroll
        for (int s = 0; s < 6; ++s) { e[qq][s] = BIG; jj[qq][s] = 0; }
    #pragma unroll 2
    for (int it = 0; it < 64; ++it) {
        int j = lane + (it << 6);
        float4 p = pb[j];
        #pragma unroll
        for (int qq = 0; qq < 4; ++qq) {
            float dx = p.x - qv[qq].x, dy = p.y - qv[qq].y, dz = p.z - qv[qq].z;
            float dd = dx * dx + dy * dy + dz * dz;
            if (dd <= T[qq] && j != i0 + qq && dd < e[qq][5]) {
                e[qq][5] = dd; jj[qq][5] = j;
                float td; int tj;
                if (e[qq][5] < e[qq][4]) { td = e[qq][4]; e[qq][4] = e[qq][5]; e[qq][5] = td; tj = jj[qq][4]; jj[qq][4] = jj[qq][5]; jj[qq][5] = tj; }
                if (e[qq][4] < e[qq][3]) { td = e[qq][3]; e[qq][3] = e[qq][4]; e[qq][4] = td; tj = jj[qq][3]; jj[qq][3] = jj[qq][4]; jj[qq][4] = tj; }
                if (e[qq][3] < e[qq][2]) { td = e[qq][2]; e[qq][2] = e[qq][3]; e[qq][3] = td; tj = jj[qq][2]; jj[qq][2] = jj[qq][3]; jj[qq][3] = tj; }
                if (e[qq][2] < e[qq][1]) { td = e[qq][1]; e[qq][1] = e[qq][2]; e[qq][2] = td; tj = jj[qq][1]; jj[qq][1] = jj[qq][2]; jj[qq][2] = tj; }
                if (e[qq][1] < e[qq][0]) { td = e[qq][0]; e[qq][0] = e[qq][1]; e[qq][1] = td; tj = jj[qq][0]; jj[qq][0] = jj[qq][1]; jj[qq][1] = tj; }
            }
        }
    }

    // merge per query by 64-bit key (exact; ties -> smaller j)
    #pragma unroll
    for (int qq = 0; qq < 4; ++qq) {
        unsigned long long a0 = ((unsigned long long)__float_as_uint(e[qq][0]) << 32) | (unsigned)jj[qq][0];
        unsigned long long a1 = ((unsigned long long)__float_as_uint(e[qq][1]) << 32) | (unsigned)jj[qq][1];
        unsigned long long a2 = ((unsigned long long)__float_as_uint(e[qq][2]) << 32) | (unsigned)jj[qq][2];
        unsigned long long a3 = ((unsigned long long)__float_as_uint(e[qq][3]) << 32) | (unsigned)jj[qq][3];
        unsigned long long a4 = ((unsigned long long)__float_as_uint(e[qq][4]) << 32) | (unsigned)jj[qq][4];
        unsigned long long a5 = ((unsigned long long)__float_as_uint(e[qq][5]) << 32) | (unsigned)jj[qq][5];
        #pragma unroll
        for (int k = 0; k < K_; ++k) {
            unsigned long long m = a0;
            #pragma unroll
            for (int off = 1; off < 64; off <<= 1) {
                unsigned long long o = shflxor64(m, off);
                if (o < m) m = o;
            }
            if (a0 == m) { a0 = a1; a1 = a2; a2 = a3; a3 = a4; a4 = a5; a5 = ~0ull; }
            if (lane == 0) idxv[((size_t)b * N_ + i0 + qq) * K_ + k] = (int)(unsigned)(m & 0xffffffffull);
        }
    }
}

// ---------------- geom: u, rbf per edge ----------------
__global__ void k_geom(const float4* __restrict__ pos4, const int* __restrict__ idxv,
                       float* __restrict__ uv, float* __restrict__ rbfv)
{
    int g = blockIdx.x * 256 + threadIdx.x;
    if (g >= ROWS_ * K_) return;
    int b = g / (N_ * K_);
    int rem = g - b * N_ * K_;
    int n = rem / K_;
    int j = idxv[g];
    const float4* pb = pos4 + (size_t)b * N_;
    float4 pj = pb[j], pn = pb[n];
    float rx = pj.x - pn.x, ry = pj.y - pn.y, rz = pj.z - pn.z;
    float dist = sqrtf(rx * rx + ry * ry + rz * rz + 1e-8f);
    float inv = 1.f / dist;
    uv[g * 3 + 0] = rx * inv; uv[g * 3 + 1] = ry * inv; uv[g * 3 + 2] = rz * inv;
    for (int r = 0; r < 16; ++r) {
        float t = (dist - (4.0f / 15.0f) * r) * 4.0f;
        rbfv[g * 16 + r] = expf(-t * t);
    }
}

// ---------------- LayerNorm: wave per row, bf16 out ----------------
__global__ __launch_bounds__(256) void k_ln(const float* __restrict__ x,
                                            const float* __restrict__ s, const float* __restrict__ bb,
                                            u16* __restrict__ o)
{
    int w = threadIdx.x >> 6, lane = threadIdx.x & 63;
    size_t row = (size_t)blockIdx.x * 4 + w;
    const float* xr = x + row * 128;
    float v0 = xr[lane], v1 = xr[lane + 64];
    float sm = v0 + v1, sq = v0 * v0 + v1 * v1;
    #pragma unroll
    for (int off = 32; off; off >>= 1) {
        sm += __shfl_xor(sm, off, 64);
        sq += __shfl_xor(sq, off, 64);
    }
    float m = sm * (1.f / 128.f);
    float var = sq * (1.f / 128.f) - m * m;
    float inv = 1.f / sqrtf(var + 1e-5f);
    o[row * 128 + lane]      = f2bf((v0 - m) * inv * s[lane]      + bb[lane]);
    o[row * 128 + lane + 64] = f2bf((v1 - m) * inv * s[lane + 64] + bb[lane + 64]);
}

// ---------------- one-time: W_embed^T bf16 ----------------
__global__ void k_prepw0(const float* __restrict__ W_embed, u16* __restrict__ WembT)
{
    int g = blockIdx.x * 256 + threadIdx.x;
    if (g >= 128 * 64) return;
    int n = g >> 6, k = g & 63;
    WembT[g] = f2bf(W_embed[k * 128 + n]);
}

// ---------------- per-layer weight prep: transposed bf16 + rwg/bias2 ----------------
__global__ void k_prepw(const float* __restrict__ Wq, const float* __restrict__ Wk,
                        const float* __restrict__ Wv, const float* __restrict__ gw,
                        const float* __restrict__ fw1, const float* __restrict__ gb_,
                        const float* __restrict__ fb1, const float* __restrict__ Wvv,
                        const float* __restrict__ Wov, const float* __restrict__ Wo_,
                        const float* __restrict__ fw2, const float* __restrict__ rw2,
                        const float* __restrict__ rb2,
                        u16* __restrict__ WqkvT, u16* __restrict__ Wc2T,
                        u16* __restrict__ WvvT, u16* __restrict__ WovT,
                        u16* __restrict__ WoT, u16* __restrict__ fw2T,
                        float* __restrict__ bias2, float* __restrict__ rwg)
{
    int g = blockIdx.x * 256 + threadIdx.x;
    if (g < 49152) {
        int n = g >> 7, k = g & 127;
        const float* src = (n < 128) ? Wq : ((n < 256) ? Wk : Wv);
        WqkvT[g] = f2bf(src[k * 128 + (n & 127)]); return;
    }
    g -= 49152;
    if (g < 49152) {
        int n = g >> 7, k = g & 127;
        Wc2T[g] = f2bf((n < 128) ? gw[k * 128 + n] : fw1[k * 256 + (n - 128)]); return;
    }
    g -= 49152;
    if (g < 16384) { int n = g >> 7, k = g & 127; WvvT[g] = f2bf(Wvv[k * 128 + n]); return; }
    g -= 16384;
    if (g < 16384) { int n = g >> 7, k = g & 127; WovT[g] = f2bf(Wov[k * 128 + n]); return; }
    g -= 16384;
    if (g < 16384) { int n = g >> 7, k = g & 127; WoT[g] = f2bf(Wo_[k * 128 + n]); return; }
    g -= 16384;
    if (g < 32768) { int n = g >> 8, k = g & 255; fw2T[g] = f2bf(fw2[k * 128 + n]); return; }
    g -= 32768;
    if (g < 384) { bias2[g] = (g < 128) ? gb_[g] : fb1[g - 128]; return; }
    g -= 384;
    if (g < 64) {
        int hh = g >> 2, h = g & 3;
        float a = 0.f;
        #pragma unroll
        for (int dh = 0; dh < 32; ++dh) a += rw2[hh * 256 + h * 32 + dh];
        rwg[g] = a * (1.f / 32.f); return;
    }
    g -= 64;
    if (g < 4) {
        float a = 0.f;
        #pragma unroll
        for (int dh = 0; dh < 32; ++dh) a += rb2[g * 32 + dh];
        rwg[64 + g] = a * (1.f / 32.f);
    }
}

// ---------------- MFMA bf16 GEMM: 128x128 tile, 4 waves x (64x64) ----------------
// A [M][KD] bf16, WT [N][KD] bf16 (pre-transposed).
// EPI 0: C=acc(+bias)        (fp32, ldc)
// EPI 1: C+=acc(+bias)       (fp32, ldc)
// EPI 2: split: n0==0 -> C=sigm(acc+bias) fp32 ldc128 ; n0>0 -> Cb=bf16(silu(acc+bias)) ldc256
// EPI 3: v=(C+acc)*aux[(m/3)*128+col]; C=v; Cb=bf16(v)   (ldc128)
template<int KD, int EPI>
__global__ __launch_bounds__(256) void k_mgemm(
    const u16* __restrict__ A, const u16* __restrict__ WT,
    const float* __restrict__ bias, const float* __restrict__ aux,
    float* __restrict__ C, u16* __restrict__ Cb, int ldc)
{
    __shared__ u16 sA[128 * 40];   // row stride 40 u16 = 80 B
    __shared__ u16 sB[128 * 40];
    const int tid = threadIdx.x;
    const int lane = tid & 63, wid = tid >> 6;
    const int wm = wid >> 1, wn = wid & 1;
    const int m0 = blockIdx.x * 128, n0 = blockIdx.y * 128;
    f32x4 acc[4][4] = {};

    for (int k0 = 0; k0 < KD; k0 += 32) {
        __syncthreads();
        #pragma unroll
        for (int cc = 0; cc < 2; ++cc) {
            int c = tid * 2 + cc;
            int row = c >> 2, gk = c & 3;
            uint4 va = *(const uint4*)&A[(size_t)(m0 + row) * KD + k0 + gk * 8];
            *(uint4*)&sA[row * 40 + gk * 8] = va;
            uint4 vb = *(const uint4*)&WT[(size_t)(n0 + row) * KD + k0 + gk * 8];
            *(uint4*)&sB[row * 40 + gk * 8] = vb;
        }
        __syncthreads();
        const int gk = lane >> 4, lr = lane & 15;
        short8 af[4], bfr[4];
        #pragma unroll
        for (int i = 0; i < 4; ++i) {
            af[i]  = *(const short8*)&sA[(wm * 64 + i * 16 + lr) * 40 + gk * 8];
            bfr[i] = *(const short8*)&sB[(wn * 64 + i * 16 + lr) * 40 + gk * 8];
        }
        #pragma unroll
        for (int mi = 0; mi < 4; ++mi)
            #pragma unroll
            for (int ni = 0; ni < 4; ++ni)
                acc[mi][ni] = __builtin_amdgcn_mfma_f32_16x16x32_bf16(af[mi], bfr[ni], acc[mi][ni], 0, 0, 0);
    }

    const int lr4 = (lane >> 4) * 4, lc = lane & 15;
    #pragma unroll
    for (int mi = 0; mi < 4; ++mi) {
        int rbase = m0 + wm * 64 + mi * 16 + lr4;
        #pragma unroll
        for (int ni = 0; ni < 4; ++ni) {
            int col = n0 + wn * 64 + ni * 16 + lc;
            if (EPI == 0) {
                float bc = bias ? bias[col] : 0.f;
                #pragma unroll
                for (int ee = 0; ee < 4; ++ee)
                    C[(size_t)(rbase + ee) * ldc + col] = acc[mi][ni][ee] + bc;
            } else if (EPI == 1) {
                float bc = bias ? bias[col] : 0.f;
                #pragma unroll
                for (int ee = 0; ee < 4; ++ee) {
                    size_t o = (size_t)(rbase + ee) * ldc + col;
                    C[o] += acc[mi][ni][ee] + bc;
                }
            } else if (EPI == 2) {
                float bc = bias[col];
                if (n0 == 0) {
                    #pragma unroll
                    for (int ee = 0; ee < 4; ++ee)
                        C[(size_t)(rbase + ee) * 128 + col] = sigm(acc[mi][ni][ee] + bc);
                } else {
                    int c2 = col - 128;
                    #pragma unroll
                    for (int ee = 0; ee < 4; ++ee)
                        Cb[(size_t)(rbase + ee) * 256 + c2] = f2bf(silu(acc[mi][ni][ee] + bc));
                }
            } else {
                #pragma unroll
                for (int ee = 0; ee < 4; ++ee) {
                    int m = rbase + ee;
                    size_t o = (size_t)m * 128 + col;
                    float v = C[o] + acc[mi][ni][ee];
                    v *= aux[(size_t)(m / 3) * 128 + col];
                    C[o] = v;
                    Cb[o] = f2bf(v);
                }
            }
        }
    }
}

// ---------------- fp32 tiled GEMM (state head only) ----------------
template<int KD, int ACT, bool ACC, bool HASB, bool GATEMUL, bool STATEMAP>
__global__ __launch_bounds__(256) void k_tgemm(
    const float* __restrict__ A, const float* __restrict__ W, const float* __restrict__ bias,
    const float* __restrict__ aux, float* __restrict__ C, int ldw, int ldc)
{
    __shared__ __align__(16) float As[32 * 132];
    __shared__ __align__(16) float Ws[32 * 68];
    const int tid = threadIdx.x;
    const int tx = tid & 15, ty = tid >> 4;
    const int m0 = blockIdx.x * 128, n0 = blockIdx.y * 64;
    float acc[8][4] = {};
    for (int k0 = 0; k0 < KD; k0 += 32) {
        __syncthreads();
        #pragma unroll
        for (int r = 0; r < 4; ++r) {
            int id = tid + r * 256;
            int row = id >> 3, kq = id & 7;
            float4 a4 = *(const float4*)&A[(size_t)(m0 + row) * KD + k0 + kq * 4];
            As[(kq * 4 + 0) * 132 + row] = a4.x;
            As[(kq * 4 + 1) * 132 + row] = a4.y;
            As[(kq * 4 + 2) * 132 + row] = a4.z;
            As[(kq * 4 + 3) * 132 + row] = a4.w;
        }
        #pragma unroll
        for (int r = 0; r < 2; ++r) {
            int id = tid + r * 256;
            int kr = id >> 4, cq = id & 15;
            *(float4*)&Ws[kr * 68 + cq * 4] =
                *(const float4*)&W[(size_t)(k0 + kr) * ldw + n0 + cq * 4];
        }
        __syncthreads();
        #pragma unroll 8
        for (int k = 0; k < 32; ++k) {
            float4 aA = *(const float4*)&As[k * 132 + ty * 8];
            float4 aB = *(const float4*)&As[k * 132 + ty * 8 + 4];
            float4 w4 = *(const float4*)&Ws[k * 68 + tx * 4];
            float av[8] = {aA.x, aA.y, aA.z, aA.w, aB.x, aB.y, aB.z, aB.w};
            float wv[4] = {w4.x, w4.y, w4.z, w4.w};
            #pragma unroll
            for (int r = 0; r < 8; ++r)
                #pragma unroll
                for (int j = 0; j < 4; ++j)
                    acc[r][j] += av[r] * wv[j];
        }
    }
    float bv[4] = {0.f, 0.f, 0.f, 0.f};
    if (HASB) {
        #pragma unroll
        for (int j = 0; j < 4; ++j) bv[j] = bias[n0 + tx * 4 + j];
    }
    #pragma unroll
    for (int r = 0; r < 8; ++r) {
        int m = m0 + ty * 8 + r;
        float v[4];
        #pragma unroll
        for (int j = 0; j < 4; ++j) {
            float a = acc[r][j] + bv[j];
            if (ACT == 1) a = silu(a);
            if (ACT == 2) a = sigm(a);
            v[j] = a;
        }
        if (STATEMAP) {
            int n = m & (N_ - 1), bb2 = m >> 12;
            if (n == 0) continue;
            float* dst = C + ((size_t)(bb2 * NC_ + n - 1)) * ldc + n0 + tx * 4;
            float4 res = {v[0], v[1], v[2], v[3]};
            *(float4*)dst = res;
            continue;
        }
        float* cp = &C[(size_t)m * ldc + n0 + tx * 4];
        if (ACC) {
            float4 old = *(const float4*)cp;
            v[0] += old.x; v[1] += old.y; v[2] += old.z; v[3] += old.w;
        }
        if (GATEMUL) {
            const float* gp = &aux[(size_t)(m / 3) * 128 + n0 + tx * 4];
            #pragma unroll
            for (int j = 0; j < 4; ++j) v[j] *= gp[j];
        }
        float4 res = {v[0], v[1], v[2], v[3]};
        *(float4*)cp = res;
    }
}

// ---------------- fused attention (y1-hoisted, 2 rows/block, bf16 outs) ----------------
__global__ __launch_bounds__(256) void k_attn(
    const float* __restrict__ qkvb, const int* __restrict__ idxv,
    const float* __restrict__ rbfv, const float* __restrict__ uv,
    const float* __restrict__ y1,
    const float* __restrict__ rw1, const float* __restrict__ rb1,
    const float* __restrict__ rw2, const float* __restrict__ rwg,
    const float* __restrict__ rb2,
    u16* __restrict__ o0b, u16* __restrict__ o1b)
{
    const int tid = threadIdx.x;
    const int r = tid >> 7, t = tid & 127;
    const int row = blockIdx.x * 2 + r;
    const int b = row >> 12;

    __shared__ float sQ[2][128];
    __shared__ float sHid[2][6][16];
    __shared__ float sU[2][6][3];
    __shared__ float sLog[2][4][6];
    __shared__ float sAttn[2][4][6];
    __shared__ int sJ[2][6];

    sQ[r][t] = qkvb[(size_t)row * 384 + t];
    if (t < 6) sJ[r][t] = idxv[row * 6 + t];
    if (t >= 8 && t < 26) { int i = t - 8; sU[r][i / 3][i % 3] = uv[(size_t)row * 18 + i]; }
    if (t >= 32) {
        int k = (t - 32) >> 4, hh = (t - 32) & 15;
        float a = rb1[hh];
        const float* rb = rbfv + (size_t)(row * 6 + k) * 16;
        #pragma unroll
        for (int rr = 0; rr < 16; ++rr) a += rb[rr] * rw1[rr * 16 + hh];
        sHid[r][k][hh] = silu(a);
    }
    __syncthreads();

    if (t < 96) {
        int g = t >> 2, o = t & 3;
        int h = g / 6, k = g - h * 6;
        const float* kp = qkvb + (size_t)(b * N_ + sJ[r][k]) * 384 + 128 + h * 32 + o * 8;
        float4 qa = *(const float4*)&sQ[r][h * 32 + o * 8];
        float4 qb4 = *(const float4*)&sQ[r][h * 32 + o * 8 + 4];
        float4 ka = *(const float4*)kp;
        float4 kb4 = *(const float4*)(kp + 4);
        float p = qa.x * ka.x + qa.y * ka.y + qa.z * ka.z + qa.w * ka.w
                + qb4.x * kb4.x + qb4.y * kb4.y + qb4.z * kb4.z + qb4.w * kb4.w;
        p += __shfl_down(p, 2, 4);
        p += __shfl_down(p, 1, 4);
        if (o == 0) {
            float bias = rwg[64 + h];
            #pragma unroll
            for (int hh = 0; hh < 16; ++hh) bias += sHid[r][k][hh] * rwg[hh * 4 + h];
            sLog[r][h][k] = p * 0.17677669529663687f + bias;
        }
    }
    float rw2c[16];
    #pragma unroll
    for (int hh = 0; hh < 16; ++hh) rw2c[hh] = rw2[hh * 256 + 128 + t];
    float rvk[6], vj[6], y1j[6][3];
    float rb2t = rb2[128 + t];
    #pragma unroll
    for (int k = 0; k < 6; ++k) {
        float a = rb2t;
        #pragma unroll
        for (int hh = 0; hh < 16; ++hh) a += sHid[r][k][hh] * rw2c[hh];
        rvk[k] = a;
        size_t nb = (size_t)(b * N_ + sJ[r][k]);
        vj[k] = qkvb[nb * 384 + 256 + t];
        #pragma unroll
        for (int c = 0; c < 3; ++c) y1j[k][c] = y1[nb * 384 + c * 128 + t];
    }
    __syncthreads();

    if (t < 4) {
        int h = t;
        float mx = sLog[r][h][0];
        #pragma unroll
        for (int k = 1; k < 6; ++k) mx = fmaxf(mx, sLog[r][h][k]);
        float ex[6], smv = 0.f;
        #pragma unroll
        for (int k = 0; k < 6; ++k) { ex[k] = expf(sLog[r][h][k] - mx); smv += ex[k]; }
        float inv = 1.f / smv;
        #pragma unroll
        for (int k = 0; k < 6; ++k) sAttn[r][h][k] = ex[k] * inv;
    }
    __syncthreads();

    int h = t >> 5;
    float a[6];
    #pragma unroll
    for (int k = 0; k < 6; ++k) a[k] = sAttn[r][h][k];
    float o0v = 0.f;
    #pragma unroll
    for (int k = 0; k < 6; ++k) o0v += a[k] * vj[k] * silu(rvk[k]);
    o0b[(size_t)row * 128 + t] = f2bf(o0v);
    #pragma unroll
    for (int c = 0; c < 3; ++c) {
        float s = 0.f;
        #pragma unroll
        for (int k = 0; k < 6; ++k) s += a[k] * (y1j[k][c] + rvk[k] * sU[r][k][c]);
        o1b[(size_t)(row * 3 + c) * 128 + t] = f2bf(s);
    }
}

// ---------------- force head ----------------
__global__ void k_force1(const float* __restrict__ x1, const float* __restrict__ W,
                         const float* __restrict__ bias, float* __restrict__ frc)
{
    int g = blockIdx.x * 256 + threadIdx.x;
    if (g >= B_ * NC_ * 3) return;
    int c = g % 3, rr = g / 3;
    int b = rr / NC_, n = rr - b * NC_;
    const float* xr = x1 + (size_t)(b * N_ + n + 1) * 384 + c * 128;
    float a = bias[0];
    for (int d = 0; d < 128; ++d) a += xr[d] * W[d];
    frc[g] = a;
}

__global__ __launch_bounds__(256) void k_fsum(const float* __restrict__ frc, float* __restrict__ fsum)
{
    int b = blockIdx.x / 3, c = blockIdx.x % 3;
    __shared__ float red[256];
    float a = 0.f;
    for (int n = threadIdx.x; n < NC_; n += 256) a += frc[(b * NC_ + n) * 3 + c];
    red[threadIdx.x] = a; __syncthreads();
    for (int st = 128; st > 0; st >>= 1) { if (threadIdx.x < st) red[threadIdx.x] += red[threadIdx.x + st]; __syncthreads(); }
    if (threadIdx.x == 0) fsum[blockIdx.x] = red[0] / (float)NC_;
}

__global__ void k_force2(const float* __restrict__ frc, const float* __restrict__ fsum,
                         float* __restrict__ out)
{
    int g = blockIdx.x * 256 + threadIdx.x;
    if (g >= B_ * NC_ * 3) return;
    int c = g % 3;
    int b = g / (NC_ * 3);
    out[g] = frc[g] - fsum[b * 3 + c];
}

} // namespace

extern "C" void kernel_launch(void* const* d_in, const int* in_sizes, int n_in,
                              void* d_out, int out_size, void* d_ws, size_t ws_size,
                              hipStream_t stream)
{
    const float* X       = (const float*)d_in[0];
    const float* W_embed = (const float*)d_in[1];
    const float* b_embed = (const float*)d_in[2];
    const float* Wq      = (const float*)d_in[3];
    const float* Wk      = (const float*)d_in[4];
    const float* Wv      = (const float*)d_in[5];
    const float* Wvv     = (const float*)d_in[6];
    const float* rw1     = (const float*)d_in[7];
    const float* rb1     = (const float*)d_in[8];
    const float* rw2     = (const float*)d_in[9];
    const float* rb2     = (const float*)d_in[10];
    const float* Wo      = (const float*)d_in[11];
    const float* Wov     = (const float*)d_in[12];
    const float* ff_w1   = (const float*)d_in[13];
    const float* ff_b1   = (const float*)d_in[14];
    const float* ff_w2   = (const float*)d_in[15];
    const float* ff_b2   = (const float*)d_in[16];
    const float* gate_w  = (const float*)d_in[17];
    const float* gate_b  = (const float*)d_in[18];
    const float* ln1_s   = (const float*)d_in[19];
    const float* ln1_b   = (const float*)d_in[20];
    const float* ln2_s   = (const float*)d_in[21];
    const float* ln2_b   = (const float*)d_in[22];
    const float* W_state = (const float*)d_in[23];
    const float* b_state = (const float*)d_in[24];
    const float* W_force = (const float*)d_in[25];
    const float* b_force = (const float*)d_in[26];
    (void)in_sizes; (void)n_in; (void)out_size; (void)ws_size;

    float* out = (float*)d_out;
    float* w = (float*)d_ws;

    float4* pos4  = (float4*)w;                    // 65536 f
    int*    idxv  = (int*)(w + 65536);             // 98304
    float*  uv    = w + 163840;                    // 294912
    float*  rbfv  = w + 458752;                    // 1572864
    u16*    featsb= (u16*)(w + 2031616);           // 524288 f   (later aliased: frc/fsum)
    float*  x0    = w + 2555904;                   // 2097152
    u16*    hbb   = (u16*)(w + 4653056);           // 1048576 f
    float*  qkvb  = w + 5701632;                   // 6291456
    float*  gb    = w + 11993088;                  // 2097152
    u16*    o0b   = (u16*)(w + 14090240);          // 1048576 f
    u16*    o1b   = (u16*)(w + 15138816);          // 3145728 f
    float*  x1    = w + 18284544;                  // 6291456
    u16*    x1b   = (u16*)(w + 24576000);          // 3145728 f
    float*  y1    = w + 27721728;                  // 6291456 (aliased as t1b u16)
    u16*    t1b   = (u16*)y1;
    u16*    WqkvT = (u16*)(w + 34013184);          // 24576 f
    u16*    Wc2T  = (u16*)(w + 34037760);          // 24576 f
    u16*    WvvT  = (u16*)(w + 34062336);          // 8192 f
    u16*    WovT  = (u16*)(w + 34070528);          // 8192 f
    u16*    WoT   = (u16*)(w + 34078720);          // 8192 f
    u16*    fw2T  = (u16*)(w + 34086912);          // 16384 f
    u16*    WembT = (u16*)(w + 34103296);          // 4096 f
    float*  bias2 = w + 34107392;                  // 384
    float*  rwg   = w + 34107776;                  // 128
    float*  frc   = (float*)featsb;                // alias (feats dead after embed)
    float*  fsum  = ((float*)featsb) + 49152;

    hipMemsetAsync(x1, 0, (size_t)ROWS_ * 384 * sizeof(float), stream);
    hipMemsetAsync(y1, 0, (size_t)ROWS_ * 384 * sizeof(float), stream);

    k_prep<<<(ROWS_ * 64 + 255) / 256, 256, 0, stream>>>(X, pos4, featsb);
    k_prepw0<<<(128 * 64 + 255) / 256, 256, 0, stream>>>(W_embed, WembT);
    k_knn<<<ROWS_ / 16, 256, 0, stream>>>(pos4, idxv);
    k_geom<<<(ROWS_ * K_ + 255) / 256, 256, 0, stream>>>(pos4, idxv, uv, rbfv);
    // x0 = feats @ W_embed + b_embed
    k_mgemm<64, 0><<<dim3(128, 1), 256, 0, stream>>>(featsb, WembT, b_embed, nullptr, x0, nullptr, 128);

    for (int l = 0; l < 2; ++l) {
        const float* rw1_l = rw1 + l * 256;
        const float* rb1_l = rb1 + l * 16;
        const float* rw2_l = rw2 + l * 4096;
        const float* rb2_l = rb2 + l * 256;
        const float* fb2_l = ff_b2 + l * 128;

        // h = LN1(x0) -> bf16
        k_ln<<<ROWS_ / 4, 256, 0, stream>>>(x0, ln1_s + l * 128, ln1_b + l * 128, hbb);
        // per-layer weight prep (bf16 transposed)
        k_prepw<<<707, 256, 0, stream>>>(Wq + l * 16384, Wk + l * 16384, Wv + l * 16384,
                                         gate_w + l * 16384, ff_w1 + l * 32768,
                                         gate_b + l * 128, ff_b1 + l * 256,
                                         Wvv + l * 16384, Wov + l * 16384, Wo + l * 16384,
                                         ff_w2 + l * 32768, rw2_l, rb2_l,
                                         WqkvT, Wc2T, WvvT, WovT, WoT, fw2T, bias2, rwg);
        // qkv = h @ Wqkv   (fp32 out)
        k_mgemm<128, 0><<<dim3(128, 3), 256, 0, stream>>>(hbb, WqkvT, nullptr, nullptr, qkvb, nullptr, 384);
        // y1 = x1 @ Wvv  (layer 0: memset)
        if (l > 0)
            k_mgemm<128, 0><<<dim3(384, 1), 256, 0, stream>>>(x1b, WvvT, nullptr, nullptr, y1, nullptr, 128);
        // attention -> o0b, o1b (bf16)
        k_attn<<<ROWS_ / 2, 256, 0, stream>>>(qkvb, idxv, rbfv, uv, y1,
                                              rw1_l, rb1_l, rw2_l, rwg, rb2_l, o0b, o1b);
        // x0 += o0 @ Wo
        k_mgemm<128, 1><<<dim3(128, 1), 256, 0, stream>>>(o0b, WoT, nullptr, nullptr, x0, nullptr, 128);
        // h2 = LN2(x0) -> bf16
        k_ln<<<ROWS_ / 4, 256, 0, stream>>>(x0, ln2_s + l * 128, ln2_b + l * 128, hbb);
        // [gate fp32 | t1 bf16] = h2 @ [gate_w|ff_w1]
        k_mgemm<128, 2><<<dim3(128, 3), 256, 0, stream>>>(hbb, Wc2T, bias2, nullptr, gb, t1b, 128);
        // x1 = (x1 + o1 @ Wov) * gate ; x1b = bf16(x1)
        k_mgemm<128, 3><<<dim3(384, 1), 256, 0, stream>>>(o1b, WovT, nullptr, gb, x1, x1b, 128);
        // x0 += t1 @ ff_w2 + fb2
        k_mgemm<256, 1><<<dim3(128, 1), 256, 0, stream>>>(t1b, fw2T, fb2_l, nullptr, x0, nullptr, 128);
    }

    // state head -> out (row-remapped, fp32 path)
    k_tgemm<128, 0, false, true, false, true><<<dim3(128, 1), 256, 0, stream>>>(
        x0, W_state, b_state, nullptr, out, 64, 64);
    // force head
    k_force1<<<(B_ * NC_ * 3 + 255) / 256, 256, 0, stream>>>(x1, W_force, b_force, frc);
    k_fsum<<<12, 256, 0, stream>>>(frc, fsum);
    k_force2<<<(B_ * NC_ * 3 + 255) / 256, 256, 0, stream>>>(frc, fsum, out + (size_t)B_ * NC_ * DIN_);
}

// Round 7
// 409.384 us; speedup vs baseline: 4.7678x; 1.1508x over previous
//
#include <hip/hip_runtime.h>
#include <cstdint>
#include <cstddef>

namespace {

constexpr int B_ = 4, NC_ = 4095, N_ = 4096, DIN_ = 64, D_ = 128, K_ = 6;
constexpr int XROW_ = 6 + DIN_;   // 70
constexpr int ROWS_ = B_ * N_;    // 16384
constexpr int KNQ = 8;            // queries per wave in knn
constexpr int KCAP = 40;          // hit-list capacity per query

typedef unsigned short u16;
typedef unsigned int u32;
typedef unsigned long long u64;
typedef __attribute__((ext_vector_type(8))) short short8;
typedef __attribute__((ext_vector_type(4))) float f32x4;

__device__ __forceinline__ float sigm(float x) { return 1.f / (1.f + expf(-x)); }
__device__ __forceinline__ float silu(float x) { return x / (1.f + expf(-x)); }
__device__ __forceinline__ u16 f2bf(float x) {
    u32 u = __float_as_uint(x);
    u += 0x7FFFu + ((u >> 16) & 1u);
    return (u16)(u >> 16);
}

// ---------------- prep: pos4 + feats(bf16) ----------------
__global__ void k_prep(const float* __restrict__ X, float4* __restrict__ pos4,
                       u16* __restrict__ featsb)
{
    int g = blockIdx.x * 256 + threadIdx.x;
    if (g >= ROWS_ * 64) return;
    int c = g & 63, row = g >> 6;
    int b = row >> 12, n = row & (N_ - 1);
    const float* xr = X + (size_t)(b * NC_ + n - 1) * XROW_;
    featsb[g] = (n > 0) ? f2bf(xr[6 + c]) : (u16)0;
    if (c == 0) {
        float4 p = {0.f, 0.f, 0.f, 0.f};
        if (n > 0) { p.x = xr[0]; p.y = xr[1]; p.z = xr[2]; }
        pos4[row] = p;
    }
}

// ---------------- knn helpers ----------------
__device__ __forceinline__ u64 shflxor64(u64 v, int mask)
{
    int lo = __shfl_xor((int)(u32)(v & 0xffffffffull), mask, 64);
    int hi = __shfl_xor((int)(u32)(v >> 32), mask, 64);
    return ((u64)(u32)hi << 32) | (u32)lo;
}

__device__ __forceinline__ float kth6min(float v)
{
    const float BIG = 3.4e38f;
    float kth = BIG;
    #pragma unroll
    for (int r = 0; r < 6; ++r) {
        float m = v;
        #pragma unroll
        for (int off = 1; off < 64; off <<= 1) m = fminf(m, __shfl_xor(m, off, 64));
        kth = m;
        if (v == m) v = BIG;   // dedup only raises bound (safe)
    }
    return kth;
}

__device__ __forceinline__ void geom_write(const float4* __restrict__ pb, int q, int j,
                                           size_t e, float* __restrict__ uv,
                                           float* __restrict__ rbfv)
{
    float4 pj = pb[j], pn = pb[q];
    float rx = pj.x - pn.x, ry = pj.y - pn.y, rz = pj.z - pn.z;
    float dist = sqrtf(rx * rx + ry * ry + rz * rz + 1e-8f);
    float inv = 1.f / dist;
    uv[e * 3 + 0] = rx * inv; uv[e * 3 + 1] = ry * inv; uv[e * 3 + 2] = rz * inv;
    #pragma unroll
    for (int r = 0; r < 16; ++r) {
        float t = (dist - (4.0f / 15.0f) * r) * 4.0f;
        rbfv[e * 16 + r] = expf(-t * t);
    }
}

// ---------------- KNN: 8 q/wave, threshold + LDS compaction + exact extract; fused geom ----------------
__global__ __launch_bounds__(256) void k_knn(const float4* __restrict__ pos4,
                                             int* __restrict__ idxv,
                                             float* __restrict__ uv,
                                             float* __restrict__ rbfv)
{
    __shared__ u64 sHits[4][KNQ][KCAP];
    __shared__ int sCnt[4][KNQ];
    const int w = threadIdx.x >> 6, lane = threadIdx.x & 63;
    const int wave = (blockIdx.x << 2) | w;
    const int b = wave >> 9;
    const int i0 = (wave & 511) << 3;
    const float4* pb = pos4 + (size_t)b * N_;
    const float BIG = 3.4e38f;

    if (lane < KNQ) sCnt[w][lane] = 0;
    __syncthreads();

    float4 qv[KNQ];
    #pragma unroll
    for (int qq = 0; qq < KNQ; ++qq) qv[qq] = pb[i0 + qq];

    // phase 1: per-lane min d2 per query
    float dmin[KNQ];
    #pragma unroll
    for (int qq = 0; qq < KNQ; ++qq) dmin[qq] = BIG;
    #pragma unroll 2
    for (int it = 0; it < 64; ++it) {
        int j = lane + (it << 6);
        float4 p = pb[j];
        #pragma unroll
        for (int qq = 0; qq < KNQ; ++qq) {
            float dx = p.x - qv[qq].x, dy = p.y - qv[qq].y, dz = p.z - qv[qq].z;
            float dd = dx * dx + dy * dy + dz * dz;
            if (j != i0 + qq) dmin[qq] = fminf(dmin[qq], dd);
        }
    }
    float T[KNQ];
    #pragma unroll
    for (int qq = 0; qq < KNQ; ++qq) T[qq] = kth6min(dmin[qq]) * 1.000002f;

    // phase 2: compact hits (dd <= T) into LDS
    #pragma unroll 2
    for (int it = 0; it < 64; ++it) {
        int j = lane + (it << 6);
        float4 p = pb[j];
        #pragma unroll
        for (int qq = 0; qq < KNQ; ++qq) {
            float dx = p.x - qv[qq].x, dy = p.y - qv[qq].y, dz = p.z - qv[qq].z;
            float dd = dx * dx + dy * dy + dz * dz;
            if (dd <= T[qq] && j != i0 + qq) {
                int slot = atomicAdd(&sCnt[w][qq], 1);
                if (slot < KCAP)
                    sHits[w][qq][slot] = ((u64)__float_as_uint(dd) << 32) | (u32)j;
            }
        }
    }
    __syncthreads();

    // extraction: 8-lane group g handles query g; exact 6x min over hit list
    const int g = lane >> 3, li = lane & 7;
    const int cnt = sCnt[w][g];
    const int q = i0 + g;
    u64 ent[KCAP / 8];
    #pragma unroll
    for (int e = 0; e < KCAP / 8; ++e) {
        int slot = li + e * 8;
        ent[e] = (slot < (cnt < KCAP ? cnt : KCAP)) ? sHits[w][g][slot] : ~0ull;
    }
    int myj = -1;
    #pragma unroll
    for (int k = 0; k < 6; ++k) {
        u64 m = ent[0];
        #pragma unroll
        for (int e = 1; e < KCAP / 8; ++e) m = (ent[e] < m) ? ent[e] : m;
        #pragma unroll
        for (int off = 1; off < 8; off <<= 1) {
            u64 o = shflxor64(m, off);
            if (o < m) m = o;
        }
        if (li == k) myj = (int)(u32)(m & 0xffffffffull);
        #pragma unroll
        for (int e = 0; e < KCAP / 8; ++e) if (ent[e] == m) ent[e] = ~0ull;
    }
    if (cnt <= KCAP && li < 6) {
        size_t e = (size_t)(b * N_ + q) * 6 + li;
        idxv[e] = myj;
        geom_write(pb, q, myj, e, uv, rbfv);
    }

    // fallback for overflowed queries (exact per-lane insert; essentially never taken)
    u64 ovf = __ballot(li == 0 && cnt > KCAP);
    while (ovf) {
        int gl = __ffsll(ovf) - 1; ovf &= ovf - 1;
        int qq = gl >> 3;
        int qx = i0 + qq;
        float4 qp = pb[qx];
        float Tq = T[0];
        #pragma unroll
        for (int z = 1; z < KNQ; ++z) if (z == qq) Tq = T[z];
        float e0 = BIG, e1 = BIG, e2 = BIG, e3 = BIG, e4 = BIG, e5 = BIG;
        int j0 = 0, j1 = 0, j2 = 0, j3 = 0, j4 = 0, j5 = 0;
        for (int it = 0; it < 64; ++it) {
            int j = lane + (it << 6);
            float4 p = pb[j];
            float dx = p.x - qp.x, dy = p.y - qp.y, dz = p.z - qp.z;
            float dd = dx * dx + dy * dy + dz * dz;
            if (dd <= Tq && j != qx && dd < e5) {
                e5 = dd; j5 = j;
                float td; int tj;
                if (e5 < e4) { td = e4; e4 = e5; e5 = td; tj = j4; j4 = j5; j5 = tj; }
                if (e4 < e3) { td = e3; e3 = e4; e4 = td; tj = j3; j3 = j4; j4 = tj; }
                if (e3 < e2) { td = e2; e2 = e3; e3 = td; tj = j2; j2 = j3; j3 = tj; }
                if (e2 < e1) { td = e1; e1 = e2; e2 = td; tj = j1; j1 = j2; j2 = tj; }
                if (e1 < e0) { td = e0; e0 = e1; e1 = td; tj = j0; j0 = j1; j1 = tj; }
            }
        }
        u64 a0 = ((u64)__float_as_uint(e0) << 32) | (u32)j0;
        u64 a1 = ((u64)__float_as_uint(e1) << 32) | (u32)j1;
        u64 a2 = ((u64)__float_as_uint(e2) << 32) | (u32)j2;
        u64 a3 = ((u64)__float_as_uint(e3) << 32) | (u32)j3;
        u64 a4 = ((u64)__float_as_uint(e4) << 32) | (u32)j4;
        u64 a5 = ((u64)__float_as_uint(e5) << 32) | (u32)j5;
        int fj = -1;
        #pragma unroll
        for (int k = 0; k < 6; ++k) {
            u64 m = a0;
            #pragma unroll
            for (int off = 1; off < 64; off <<= 1) {
                u64 o = shflxor64(m, off);
                if (o < m) m = o;
            }
            if (a0 == m) { a0 = a1; a1 = a2; a2 = a3; a3 = a4; a4 = a5; a5 = ~0ull; }
            if (lane == k) fj = (int)(u32)(m & 0xffffffffull);
        }
        if (lane < 6) {
            size_t e = (size_t)(b * N_ + qx) * 6 + lane;
            idxv[e] = fj;
            geom_write(pb, qx, fj, e, uv, rbfv);
        }
    }
}

// ---------------- one-time weight prep (both layers): transposed bf16 + rwg/bias2 + WembT ----------------
__global__ void k_prepw(const float* __restrict__ Wq, const float* __restrict__ Wk,
                        const float* __restrict__ Wv, const float* __restrict__ gw,
                        const float* __restrict__ fw1, const float* __restrict__ gb_,
                        const float* __restrict__ fb1, const float* __restrict__ Wvv,
                        const float* __restrict__ Wov, const float* __restrict__ Wo_,
                        const float* __restrict__ fw2, const float* __restrict__ rw2,
                        const float* __restrict__ rb2, const float* __restrict__ W_embed,
                        u16* __restrict__ WqkvT, u16* __restrict__ Wc2T,
                        u16* __restrict__ WvvT, u16* __restrict__ WovT,
                        u16* __restrict__ WoT, u16* __restrict__ fw2T,
                        u16* __restrict__ WembT,
                        float* __restrict__ bias2, float* __restrict__ rwg)
{
    const int l = blockIdx.y;
    int g = blockIdx.x * 256 + threadIdx.x;
    const float* Wq_l = Wq + l * 16384;  const float* Wk_l = Wk + l * 16384;
    const float* Wv_l = Wv + l * 16384;  const float* gw_l = gw + l * 16384;
    const float* fw1_l = fw1 + l * 32768; const float* gb_l = gb_ + l * 128;
    const float* fb1_l = fb1 + l * 256;  const float* Wvv_l = Wvv + l * 16384;
    const float* Wov_l = Wov + l * 16384; const float* Wo_ll = Wo_ + l * 16384;
    const float* fw2_l = fw2 + l * 32768; const float* rw2_l = rw2 + l * 4096;
    const float* rb2_l = rb2 + l * 256;

    if (g < 49152) {
        int n = g >> 7, k = g & 127;
        const float* src = (n < 128) ? Wq_l : ((n < 256) ? Wk_l : Wv_l);
        WqkvT[l * 49152 + g] = f2bf(src[k * 128 + (n & 127)]); return;
    }
    g -= 49152;
    if (g < 49152) {
        int n = g >> 7, k = g & 127;
        Wc2T[l * 49152 + g] = f2bf((n < 128) ? gw_l[k * 128 + n] : fw1_l[k * 256 + (n - 128)]); return;
    }
    g -= 49152;
    if (g < 16384) { int n = g >> 7, k = g & 127; WvvT[l * 16384 + g] = f2bf(Wvv_l[k * 128 + n]); return; }
    g -= 16384;
    if (g < 16384) { int n = g >> 7, k = g & 127; WovT[l * 16384 + g] = f2bf(Wov_l[k * 128 + n]); return; }
    g -= 16384;
    if (g < 16384) { int n = g >> 7, k = g & 127; WoT[l * 16384 + g] = f2bf(Wo_ll[k * 128 + n]); return; }
    g -= 16384;
    if (g < 32768) { int n = g >> 8, k = g & 255; fw2T[l * 32768 + g] = f2bf(fw2_l[k * 128 + n]); return; }
    g -= 32768;
    if (g < 384) { bias2[l * 384 + g] = (g < 128) ? gb_l[g] : fb1_l[g - 128]; return; }
    g -= 384;
    if (g < 64) {
        int hh = g >> 2, h = g & 3;
        float a = 0.f;
        #pragma unroll
        for (int dh = 0; dh < 32; ++dh) a += rw2_l[hh * 256 + h * 32 + dh];
        rwg[l * 128 + g] = a * (1.f / 32.f); return;
    }
    g -= 64;
    if (g < 4) {
        float a = 0.f;
        #pragma unroll
        for (int dh = 0; dh < 32; ++dh) a += rb2_l[g * 32 + dh];
        rwg[l * 128 + 64 + g] = a * (1.f / 32.f); return;
    }
    g -= 4;
    if (g < 8192 && l == 0) {
        int n = g >> 6, k = g & 63;
        WembT[g] = f2bf(W_embed[k * 128 + n]);
    }
}

// ---------------- MFMA bf16 GEMM: 128x128 tile, 4 waves x (64x64) ----------------
// EPI 0: C=acc(+bias)  | EPI 1: C+=acc(+bias)
// EPI 2: split gate|ff1: n0==0 -> C=sigm fp32 ldc128 ; n0>0 -> Cb=bf16(silu) ldc256
// EPI 3: v=(X1ACC?C:0)+acc, v*=aux[(m/3)*128+col]; C=v; Cb=bf16(v)
// LN: after EPI 0/1 (n0==0, ldc==128): also write lnout = bf16(LN(v)) with lns/lnb
template<int KD, int EPI, bool LN, bool X1ACC>
__global__ __launch_bounds__(256) void k_mgemm(
    const u16* __restrict__ A, const u16* __restrict__ WT,
    const float* __restrict__ bias, const float* __restrict__ aux,
    float* __restrict__ C, u16* __restrict__ Cb, int ldc,
    const float* __restrict__ lns, const float* __restrict__ lnb,
    u16* __restrict__ lnout)
{
    __shared__ u16 sA[128 * 40];
    __shared__ u16 sB[128 * 40];
    const int tid = threadIdx.x;
    const int lane = tid & 63, wid = tid >> 6;
    const int wm = wid >> 1, wn = wid & 1;
    const int m0 = blockIdx.x * 128, n0 = blockIdx.y * 128;
    f32x4 acc[4][4] = {};

    for (int k0 = 0; k0 < KD; k0 += 32) {
        __syncthreads();
        #pragma unroll
        for (int cc = 0; cc < 2; ++cc) {
            int c = tid * 2 + cc;
            int row = c >> 2, gk = c & 3;
            uint4 va = *(const uint4*)&A[(size_t)(m0 + row) * KD + k0 + gk * 8];
            *(uint4*)&sA[row * 40 + gk * 8] = va;
            uint4 vb = *(const uint4*)&WT[(size_t)(n0 + row) * KD + k0 + gk * 8];
            *(uint4*)&sB[row * 40 + gk * 8] = vb;
        }
        __syncthreads();
        const int gk = lane >> 4, lr = lane & 15;
        short8 af[4], bfr[4];
        #pragma unroll
        for (int i = 0; i < 4; ++i) {
            af[i]  = *(const short8*)&sA[(wm * 64 + i * 16 + lr) * 40 + gk * 8];
            bfr[i] = *(const short8*)&sB[(wn * 64 + i * 16 + lr) * 40 + gk * 8];
        }
        #pragma unroll
        for (int mi = 0; mi < 4; ++mi)
            #pragma unroll
            for (int ni = 0; ni < 4; ++ni)
                acc[mi][ni] = __builtin_amdgcn_mfma_f32_16x16x32_bf16(af[mi], bfr[ni], acc[mi][ni], 0, 0, 0);
    }

    const int lg = lane >> 4;         // 0..3 row-group
    const int lc = lane & 15;         // col within 16
    if (LN) {
        __shared__ float sLN[2][64][2][2];
        float s1[4][4], s2[4][4];
        #pragma unroll
        for (int mi = 0; mi < 4; ++mi) {
            int rbase = m0 + wm * 64 + mi * 16 + lg * 4;
            #pragma unroll
            for (int ee = 0; ee < 4; ++ee) { s1[mi][ee] = 0.f; s2[mi][ee] = 0.f; }
            #pragma unroll
            for (int ni = 0; ni < 4; ++ni) {
                int col = wn * 64 + ni * 16 + lc;
                float bc = bias ? bias[col] : 0.f;
                #pragma unroll
                for (int ee = 0; ee < 4; ++ee) {
                    float v = acc[mi][ni][ee] + bc;
                    if (EPI == 1) v += C[(size_t)(rbase + ee) * 128 + col];
                    acc[mi][ni][ee] = v;
                    s1[mi][ee] += v;
                    s2[mi][ee] += v * v;
                }
            }
        }
        #pragma unroll
        for (int mi = 0; mi < 4; ++mi)
            #pragma unroll
            for (int ee = 0; ee < 4; ++ee)
                #pragma unroll
                for (int off = 1; off < 16; off <<= 1) {
                    s1[mi][ee] += __shfl_xor(s1[mi][ee], off, 64);
                    s2[mi][ee] += __shfl_xor(s2[mi][ee], off, 64);
                }
        if (lc == 0) {
            #pragma unroll
            for (int mi = 0; mi < 4; ++mi)
                #pragma unroll
                for (int ee = 0; ee < 4; ++ee) {
                    int r = mi * 16 + lg * 4 + ee;
                    sLN[wm][r][wn][0] = s1[mi][ee];
                    sLN[wm][r][wn][1] = s2[mi][ee];
                }
        }
        __syncthreads();
        #pragma unroll
        for (int mi = 0; mi < 4; ++mi) {
            int rbase = m0 + wm * 64 + mi * 16 + lg * 4;
            #pragma unroll
            for (int ee = 0; ee < 4; ++ee) {
                int r = mi * 16 + lg * 4 + ee;
                float sum = s1[mi][ee] + sLN[wm][r][wn ^ 1][0];
                float sq  = s2[mi][ee] + sLN[wm][r][wn ^ 1][1];
                float mean = sum * (1.f / 128.f);
                float var = sq * (1.f / 128.f) - mean * mean;
                float inv = 1.f / sqrtf(var + 1e-5f);
                #pragma unroll
                for (int ni = 0; ni < 4; ++ni) {
                    int col = wn * 64 + ni * 16 + lc;
                    float v = acc[mi][ni][ee];
                    size_t o = (size_t)(rbase + ee) * 128 + col;
                    C[o] = v;
                    lnout[o] = f2bf((v - mean) * inv * lns[col] + lnb[col]);
                }
            }
        }
        return;
    }

    const int lr4 = lg * 4;
    #pragma unroll
    for (int mi = 0; mi < 4; ++mi) {
        int rbase = m0 + wm * 64 + mi * 16 + lr4;
        #pragma unroll
        for (int ni = 0; ni < 4; ++ni) {
            int col = n0 + wn * 64 + ni * 16 + lc;
            if (EPI == 0) {
                float bc = bias ? bias[col] : 0.f;
                #pragma unroll
                for (int ee = 0; ee < 4; ++ee)
                    C[(size_t)(rbase + ee) * ldc + col] = acc[mi][ni][ee] + bc;
            } else if (EPI == 1) {
                float bc = bias ? bias[col] : 0.f;
                #pragma unroll
                for (int ee = 0; ee < 4; ++ee) {
                    size_t o = (size_t)(rbase + ee) * ldc + col;
                    C[o] += acc[mi][ni][ee] + bc;
                }
            } else if (EPI == 2) {
                float bc = bias[col];
                if (n0 == 0) {
                    #pragma unroll
                    for (int ee = 0; ee < 4; ++ee)
                        C[(size_t)(rbase + ee) * 128 + col] = sigm(acc[mi][ni][ee] + bc);
                } else {
                    int c2 = col - 128;
                    #pragma unroll
                    for (int ee = 0; ee < 4; ++ee)
                        Cb[(size_t)(rbase + ee) * 256 + c2] = f2bf(silu(acc[mi][ni][ee] + bc));
                }
            } else {
                #pragma unroll
                for (int ee = 0; ee < 4; ++ee) {
                    int m = rbase + ee;
                    size_t o = (size_t)m * 128 + col;
                    float v = acc[mi][ni][ee];
                    if (X1ACC) v += C[o];
                    v *= aux[(size_t)(m / 3) * 128 + col];
                    C[o] = v;
                    Cb[o] = f2bf(v);
                }
            }
        }
    }
}

// ---------------- fp32 tiled GEMM (state head only) ----------------
template<int KD>
__global__ __launch_bounds__(256) void k_tgemm(
    const float* __restrict__ A, const float* __restrict__ W, const float* __restrict__ bias,
    float* __restrict__ C, int ldw, int ldc)
{
    __shared__ __align__(16) float As[32 * 132];
    __shared__ __align__(16) float Ws[32 * 68];
    const int tid = threadIdx.x;
    const int tx = tid & 15, ty = tid >> 4;
    const int m0 = blockIdx.x * 128, n0 = blockIdx.y * 64;
    float acc[8][4] = {};
    for (int k0 = 0; k0 < KD; k0 += 32) {
        __syncthreads();
        #pragma unroll
        for (int r = 0; r < 4; ++r) {
            int id = tid + r * 256;
            int row = id >> 3, kq = id & 7;
            float4 a4 = *(const float4*)&A[(size_t)(m0 + row) * KD + k0 + kq * 4];
            As[(kq * 4 + 0) * 132 + row] = a4.x;
            As[(kq * 4 + 1) * 132 + row] = a4.y;
            As[(kq * 4 + 2) * 132 + row] = a4.z;
            As[(kq * 4 + 3) * 132 + row] = a4.w;
        }
        #pragma unroll
        for (int r = 0; r < 2; ++r) {
            int id = tid + r * 256;
            int kr = id >> 4, cq = id & 15;
            *(float4*)&Ws[kr * 68 + cq * 4] =
                *(const float4*)&W[(size_t)(k0 + kr) * ldw + n0 + cq * 4];
        }
        __syncthreads();
        #pragma unroll 8
        for (int k = 0; k < 32; ++k) {
            float4 aA = *(const float4*)&As[k * 132 + ty * 8];
            float4 aB = *(const float4*)&As[k * 132 + ty * 8 + 4];
            float4 w4 = *(const float4*)&Ws[k * 68 + tx * 4];
            float av[8] = {aA.x, aA.y, aA.z, aA.w, aB.x, aB.y, aB.z, aB.w};
            float wv[4] = {w4.x, w4.y, w4.z, w4.w};
            #pragma unroll
            for (int r = 0; r < 8; ++r)
                #pragma unroll
                for (int j = 0; j < 4; ++j)
                    acc[r][j] += av[r] * wv[j];
        }
    }
    float bv[4];
    #pragma unroll
    for (int j = 0; j < 4; ++j) bv[j] = bias[n0 + tx * 4 + j];
    #pragma unroll
    for (int r = 0; r < 8; ++r) {
        int m = m0 + ty * 8 + r;
        int n = m & (N_ - 1), bb2 = m >> 12;
        if (n == 0) continue;
        float* dst = C + ((size_t)(bb2 * NC_ + n - 1)) * ldc + n0 + tx * 4;
        float4 res = {acc[r][0] + bv[0], acc[r][1] + bv[1], acc[r][2] + bv[2], acc[r][3] + bv[3]};
        *(float4*)dst = res;
    }
}

// ---------------- fused attention (y1-hoisted, 2 rows/block, bf16 outs) ----------------
template<bool HASY1>
__global__ __launch_bounds__(256) void k_attn(
    const float* __restrict__ qkvb, const int* __restrict__ idxv,
    const float* __restrict__ rbfv, const float* __restrict__ uv,
    const float* __restrict__ y1,
    const float* __restrict__ rw1, const float* __restrict__ rb1,
    const float* __restrict__ rw2, const float* __restrict__ rwg,
    const float* __restrict__ rb2,
    u16* __restrict__ o0b, u16* __restrict__ o1b)
{
    const int tid = threadIdx.x;
    const int r = tid >> 7, t = tid & 127;
    const int row = blockIdx.x * 2 + r;
    const int b = row >> 12;

    __shared__ float sQ[2][128];
    __shared__ float sHid[2][6][16];
    __shared__ float sU[2][6][3];
    __shared__ float sLog[2][4][6];
    __shared__ float sAttn[2][4][6];
    __shared__ int sJ[2][6];

    sQ[r][t] = qkvb[(size_t)row * 384 + t];
    if (t < 6) sJ[r][t] = idxv[row * 6 + t];
    if (t >= 8 && t < 26) { int i = t - 8; sU[r][i / 3][i % 3] = uv[(size_t)row * 18 + i]; }
    if (t >= 32) {
        int k = (t - 32) >> 4, hh = (t - 32) & 15;
        float a = rb1[hh];
        const float* rb = rbfv + (size_t)(row * 6 + k) * 16;
        #pragma unroll
        for (int rr = 0; rr < 16; ++rr) a += rb[rr] * rw1[rr * 16 + hh];
        sHid[r][k][hh] = silu(a);
    }
    __syncthreads();

    if (t < 96) {
        int g = t >> 2, o = t & 3;
        int h = g / 6, k = g - h * 6;
        const float* kp = qkvb + (size_t)(b * N_ + sJ[r][k]) * 384 + 128 + h * 32 + o * 8;
        float4 qa = *(const float4*)&sQ[r][h * 32 + o * 8];
        float4 qb4 = *(const float4*)&sQ[r][h * 32 + o * 8 + 4];
        float4 ka = *(const float4*)kp;
        float4 kb4 = *(const float4*)(kp + 4);
        float p = qa.x * ka.x + qa.y * ka.y + qa.z * ka.z + qa.w * ka.w
                + qb4.x * kb4.x + qb4.y * kb4.y + qb4.z * kb4.z + qb4.w * kb4.w;
        p += __shfl_down(p, 2, 4);
        p += __shfl_down(p, 1, 4);
        if (o == 0) {
            float bias = rwg[64 + h];
            #pragma unroll
            for (int hh = 0; hh < 16; ++hh) bias += sHid[r][k][hh] * rwg[hh * 4 + h];
            sLog[r][h][k] = p * 0.17677669529663687f + bias;
        }
    }
    float rw2c[16];
    #pragma unroll
    for (int hh = 0; hh < 16; ++hh) rw2c[hh] = rw2[hh * 256 + 128 + t];
    float rvk[6], vj[6], y1j[6][3];
    float rb2t = rb2[128 + t];
    #pragma unroll
    for (int k = 0; k < 6; ++k) {
        float a = rb2t;
        #pragma unroll
        for (int hh = 0; hh < 16; ++hh) a += sHid[r][k][hh] * rw2c[hh];
        rvk[k] = a;
        size_t nb = (size_t)(b * N_ + sJ[r][k]);
        vj[k] = qkvb[nb * 384 + 256 + t];
        if (HASY1) {
            #pragma unroll
            for (int c = 0; c < 3; ++c) y1j[k][c] = y1[nb * 384 + c * 128 + t];
        }
    }
    __syncthreads();

    if (t < 4) {
        int h = t;
        float mx = sLog[r][h][0];
        #pragma unroll
        for (int k = 1; k < 6; ++k) mx = fmaxf(mx, sLog[r][h][k]);
        float ex[6], smv = 0.f;
        #pragma unroll
        for (int k = 0; k < 6; ++k) { ex[k] = expf(sLog[r][h][k] - mx); smv += ex[k]; }
        float inv = 1.f / smv;
        #pragma unroll
        for (int k = 0; k < 6; ++k) sAttn[r][h][k] = ex[k] * inv;
    }
    __syncthreads();

    int h = t >> 5;
    float a[6];
    #pragma unroll
    for (int k = 0; k < 6; ++k) a[k] = sAttn[r][h][k];
    float o0v = 0.f;
    #pragma unroll
    for (int k = 0; k < 6; ++k) o0v += a[k] * vj[k] * silu(rvk[k]);
    o0b[(size_t)row * 128 + t] = f2bf(o0v);
    #pragma unroll
    for (int c = 0; c < 3; ++c) {
        float s = 0.f;
        #pragma unroll
        for (int k = 0; k < 6; ++k) {
            float base = HASY1 ? y1j[k][c] : 0.f;
            s += a[k] * (base + rvk[k] * sU[r][k][c]);
        }
        o1b[(size_t)(row * 3 + c) * 128 + t] = f2bf(s);
    }
}

// ---------------- force head ----------------
__global__ void k_force1(const float* __restrict__ x1, const float* __restrict__ W,
                         const float* __restrict__ bias, float* __restrict__ frc)
{
    int g = blockIdx.x * 256 + threadIdx.x;
    if (g >= B_ * NC_ * 3) return;
    int c = g % 3, rr = g / 3;
    int b = rr / NC_, n = rr - b * NC_;
    const float* xr = x1 + (size_t)(b * N_ + n + 1) * 384 + c * 128;
    float a = bias[0];
    for (int d = 0; d < 128; ++d) a += xr[d] * W[d];
    frc[g] = a;
}

__global__ __launch_bounds__(256) void k_fsum(const float* __restrict__ frc, float* __restrict__ fsum)
{
    int b = blockIdx.x / 3, c = blockIdx.x % 3;
    __shared__ float red[256];
    float a = 0.f;
    for (int n = threadIdx.x; n < NC_; n += 256) a += frc[(b * NC_ + n) * 3 + c];
    red[threadIdx.x] = a; __syncthreads();
    for (int st = 128; st > 0; st >>= 1) { if (threadIdx.x < st) red[threadIdx.x] += red[threadIdx.x + st]; __syncthreads(); }
    if (threadIdx.x == 0) fsum[blockIdx.x] = red[0] / (float)NC_;
}

__global__ void k_force2(const float* __restrict__ frc, const float* __restrict__ fsum,
                         float* __restrict__ out)
{
    int g = blockIdx.x * 256 + threadIdx.x;
    if (g >= B_ * NC_ * 3) return;
    int c = g % 3;
    int b = g / (NC_ * 3);
    out[g] = frc[g] - fsum[b * 3 + c];
}

} // namespace

extern "C" void kernel_launch(void* const* d_in, const int* in_sizes, int n_in,
                              void* d_out, int out_size, void* d_ws, size_t ws_size,
                              hipStream_t stream)
{
    const float* X       = (const float*)d_in[0];
    const float* W_embed = (const float*)d_in[1];
    const float* b_embed = (const float*)d_in[2];
    const float* Wq      = (const float*)d_in[3];
    const float* Wk      = (const float*)d_in[4];
    const float* Wv      = (const float*)d_in[5];
    const float* Wvv     = (const float*)d_in[6];
    const float* rw1     = (const float*)d_in[7];
    const float* rb1     = (const float*)d_in[8];
    const float* rw2     = (const float*)d_in[9];
    const float* rb2     = (const float*)d_in[10];
    const float* Wo      = (const float*)d_in[11];
    const float* Wov     = (const float*)d_in[12];
    const float* ff_w1   = (const float*)d_in[13];
    const float* ff_b1   = (const float*)d_in[14];
    const float* ff_w2   = (const float*)d_in[15];
    const float* ff_b2   = (const float*)d_in[16];
    const float* gate_w  = (const float*)d_in[17];
    const float* gate_b  = (const float*)d_in[18];
    const float* ln1_s   = (const float*)d_in[19];
    const float* ln1_b   = (const float*)d_in[20];
    const float* ln2_s   = (const float*)d_in[21];
    const float* ln2_b   = (const float*)d_in[22];
    const float* W_state = (const float*)d_in[23];
    const float* b_state = (const float*)d_in[24];
    const float* W_force = (const float*)d_in[25];
    const float* b_force = (const float*)d_in[26];
    (void)in_sizes; (void)n_in; (void)out_size; (void)ws_size;

    float* out = (float*)d_out;
    float* w = (float*)d_ws;

    float4* pos4  = (float4*)w;                    // -> 65536
    int*    idxv  = (int*)(w + 65536);             // -> 163840
    float*  uv    = w + 163840;                    // -> 458752
    float*  rbfv  = w + 458752;                    // -> 2031616
    u16*    featsb= (u16*)(w + 2031616);           // -> 2555904 (frc/fsum alias later)
    float*  x0    = w + 2555904;                   // -> 4653056
    u16*    hbb   = (u16*)(w + 4653056);           // -> 5701632
    float*  qkvb  = w + 5701632;                   // -> 11993088
    float*  gb    = w + 11993088;                  // -> 14090240
    u16*    o0b   = (u16*)(w + 14090240);          // -> 15138816
    u16*    o1b   = (u16*)(w + 15138816);          // -> 18284544
    float*  x1    = w + 18284544;                  // -> 24576000
    u16*    x1b   = (u16*)(w + 24576000);          // -> 27721728
    float*  y1    = w + 27721728;                  // -> 34013184 (t1b alias)
    u16*    t1b   = (u16*)y1;
    u16*    WqkvT = (u16*)(w + 34013184);          // 2x49152 u16 -> +49152 f
    u16*    Wc2T  = (u16*)(w + 34062336);
    u16*    WvvT  = (u16*)(w + 34111488);
    u16*    WovT  = (u16*)(w + 34127872);
    u16*    WoT   = (u16*)(w + 34144256);
    u16*    fw2T  = (u16*)(w + 34160640);          // 2x32768 u16
    u16*    WembT = (u16*)(w + 34193408);          // 8192 u16
    float*  bias2 = w + 34197504;                  // 2x384
    float*  rwg   = w + 34198272;                  // 2x128
    float*  frc   = (float*)featsb;
    float*  fsum  = ((float*)featsb) + 49152;

    // one-time prep (both layers) + inputs
    k_prepw<<<dim3(738, 2), 256, 0, stream>>>(Wq, Wk, Wv, gate_w, ff_w1, gate_b, ff_b1,
                                              Wvv, Wov, Wo, ff_w2, rw2, rb2, W_embed,
                                              WqkvT, Wc2T, WvvT, WovT, WoT, fw2T, WembT,
                                              bias2, rwg);
    k_prep<<<(ROWS_ * 64 + 255) / 256, 256, 0, stream>>>(X, pos4, featsb);
    k_knn<<<ROWS_ / 32, 256, 0, stream>>>(pos4, idxv, uv, rbfv);
    // x0 = feats @ W_embed + b_embed ; hbb = LN1(x0)
    k_mgemm<64, 0, true, true><<<dim3(128, 1), 256, 0, stream>>>(
        featsb, WembT, b_embed, nullptr, x0, nullptr, 128, ln1_s, ln1_b, hbb);

    for (int l = 0; l < 2; ++l) {
        const float* rw1_l = rw1 + l * 256;
        const float* rb1_l = rb1 + l * 16;
        const float* rw2_l = rw2 + l * 4096;
        const float* rb2_l = rb2 + l * 256;
        const float* fb2_l = ff_b2 + l * 128;

        // qkv = h @ Wqkv (fp32 out)
        k_mgemm<128, 0, false, true><<<dim3(128, 3), 256, 0, stream>>>(
            hbb, WqkvT + l * 49152, nullptr, nullptr, qkvb, nullptr, 384, nullptr, nullptr, nullptr);
        // y1 = x1 @ Wvv (layer 1 only)
        if (l > 0)
            k_mgemm<128, 0, false, true><<<dim3(384, 1), 256, 0, stream>>>(
                x1b, WvvT + l * 16384, nullptr, nullptr, y1, nullptr, 128, nullptr, nullptr, nullptr);
        // attention
        if (l == 0)
            k_attn<false><<<ROWS_ / 2, 256, 0, stream>>>(qkvb, idxv, rbfv, uv, nullptr,
                rw1_l, rb1_l, rw2_l, rwg + l * 128, rb2_l, o0b, o1b);
        else
            k_attn<true><<<ROWS_ / 2, 256, 0, stream>>>(qkvb, idxv, rbfv, uv, y1,
                rw1_l, rb1_l, rw2_l, rwg + l * 128, rb2_l, o0b, o1b);
        // x0 += o0 @ Wo ; hbb = LN2(x0)
        k_mgemm<128, 1, true, true><<<dim3(128, 1), 256, 0, stream>>>(
            o0b, WoT + l * 16384, nullptr, nullptr, x0, nullptr, 128,
            ln2_s + l * 128, ln2_b + l * 128, hbb);
        // [gate fp32 | t1 bf16] = h2 @ [gate_w|ff_w1]
        k_mgemm<128, 2, false, true><<<dim3(128, 3), 256, 0, stream>>>(
            hbb, Wc2T + l * 49152, bias2 + l * 384, nullptr, gb, t1b, 128, nullptr, nullptr, nullptr);
        // x1 = ((l? x1:0) + o1 @ Wov) * gate ; x1b = bf16(x1)
        if (l == 0)
            k_mgemm<128, 3, false, false><<<dim3(384, 1), 256, 0, stream>>>(
                o1b, WovT + l * 16384, nullptr, gb, x1, x1b, 128, nullptr, nullptr, nullptr);
        else
            k_mgemm<128, 3, false, true><<<dim3(384, 1), 256, 0, stream>>>(
                o1b, WovT + l * 16384, nullptr, gb, x1, x1b, 128, nullptr, nullptr, nullptr);
        // x0 += t1 @ ff_w2 + fb2 ; (l==0: hbb = LN1_{l+1}(x0))
        if (l == 0)
            k_mgemm<256, 1, true, true><<<dim3(128, 1), 256, 0, stream>>>(
                t1b, fw2T + l * 32768, fb2_l, nullptr, x0, nullptr, 128,
                ln1_s + 128, ln1_b + 128, hbb);
        else
            k_mgemm<256, 1, false, true><<<dim3(128, 1), 256, 0, stream>>>(
                t1b, fw2T + l * 32768, fb2_l, nullptr, x0, nullptr, 128, nullptr, nullptr, nullptr);
    }

    // state head -> out (row-remapped)
    k_tgemm<128><<<dim3(128, 1), 256, 0, stream>>>(x0, W_state, b_state, out, 64, 64);
    // force head
    k_force1<<<(B_ * NC_ * 3 + 255) / 256, 256, 0, stream>>>(x1, W_force, b_force, frc);
    k_fsum<<<12, 256, 0, stream>>>(frc, fsum);
    k_force2<<<(B_ * NC_ * 3 + 255) / 256, 256, 0, stream>>>(frc, fsum, out + (size_t)B_ * NC_ * DIN_);
}

// Round 8
// 390.950 us; speedup vs baseline: 4.9926x; 1.0472x over previous
//
#include <hip/hip_runtime.h>
#include <cstdint>
#include <cstddef>

namespace {

constexpr int B_ = 4, NC_ = 4095, N_ = 4096, DIN_ = 64, D_ = 128, K_ = 6;
constexpr int XROW_ = 6 + DIN_;   // 70
constexpr int ROWS_ = B_ * N_;    // 16384
constexpr int KNQ = 4;            // queries per wave in knn
constexpr int KCAP = 32;          // hit-list capacity per query

typedef unsigned short u16;
typedef unsigned int u32;
typedef unsigned long long u64;
typedef __attribute__((ext_vector_type(8))) short short8;
typedef __attribute__((ext_vector_type(4))) float f32x4;

__device__ __forceinline__ float sigm(float x) { return 1.f / (1.f + expf(-x)); }
__device__ __forceinline__ float silu(float x) { return x / (1.f + expf(-x)); }
__device__ __forceinline__ u16 f2bf(float x) {
    u32 u = __float_as_uint(x);
    u += 0x7FFFu + ((u >> 16) & 1u);
    return (u16)(u >> 16);
}

// ---------------- prep: pos4 + feats(bf16) ----------------
__global__ void k_prep(const float* __restrict__ X, float4* __restrict__ pos4,
                       u16* __restrict__ featsb)
{
    int g = blockIdx.x * 256 + threadIdx.x;
    if (g >= ROWS_ * 64) return;
    int c = g & 63, row = g >> 6;
    int b = row >> 12, n = row & (N_ - 1);
    const float* xr = X + (size_t)(b * NC_ + n - 1) * XROW_;
    featsb[g] = (n > 0) ? f2bf(xr[6 + c]) : (u16)0;
    if (c == 0) {
        float4 p = {0.f, 0.f, 0.f, 0.f};
        if (n > 0) { p.x = xr[0]; p.y = xr[1]; p.z = xr[2]; }
        pos4[row] = p;
    }
}

// ---------------- knn helpers ----------------
__device__ __forceinline__ u64 shflxor64(u64 v, int mask)
{
    int lo = __shfl_xor((int)(u32)(v & 0xffffffffull), mask, 64);
    int hi = __shfl_xor((int)(u32)(v >> 32), mask, 64);
    return ((u64)(u32)hi << 32) | (u32)lo;
}

__device__ __forceinline__ float kth6min(float v)
{
    const float BIG = 3.4e38f;
    float kth = BIG;
    #pragma unroll
    for (int r = 0; r < 6; ++r) {
        float m = v;
        #pragma unroll
        for (int off = 1; off < 64; off <<= 1) m = fminf(m, __shfl_xor(m, off, 64));
        kth = m;
        if (v == m) v = BIG;   // dedup only raises bound (safe)
    }
    return kth;
}

__device__ __forceinline__ void geom_write(const float4* __restrict__ pb, int q, int j,
                                           size_t e, float* __restrict__ uv,
                                           float* __restrict__ rbfv)
{
    float4 pj = pb[j], pn = pb[q];
    float rx = pj.x - pn.x, ry = pj.y - pn.y, rz = pj.z - pn.z;
    float dist = sqrtf(rx * rx + ry * ry + rz * rz + 1e-8f);
    float inv = 1.f / dist;
    uv[e * 3 + 0] = rx * inv; uv[e * 3 + 1] = ry * inv; uv[e * 3 + 2] = rz * inv;
    #pragma unroll
    for (int r = 0; r < 16; ++r) {
        float t = (dist - (4.0f / 15.0f) * r) * 4.0f;
        rbfv[e * 16 + r] = expf(-t * t);
    }
}

// ---------------- KNN: 4 q/wave, threshold + LDS compaction + exact extract; fused geom ----------------
__global__ __launch_bounds__(256) void k_knn(const float4* __restrict__ pos4,
                                             int* __restrict__ idxv,
                                             float* __restrict__ uv,
                                             float* __restrict__ rbfv)
{
    __shared__ u64 sHits[4][KNQ][KCAP];
    __shared__ int sCnt[4][KNQ];
    const int w = threadIdx.x >> 6, lane = threadIdx.x & 63;
    const int wave = (blockIdx.x << 2) | w;
    const int b = wave >> 10;
    const int i0 = (wave & 1023) << 2;
    const float4* pb = pos4 + (size_t)b * N_;
    const float BIG = 3.4e38f;

    if (lane < KNQ) sCnt[w][lane] = 0;
    __syncthreads();

    float4 qv[KNQ];
    #pragma unroll
    for (int qq = 0; qq < KNQ; ++qq) qv[qq] = pb[i0 + qq];

    // phase 1: per-lane min d2 per query
    float dmin[KNQ];
    #pragma unroll
    for (int qq = 0; qq < KNQ; ++qq) dmin[qq] = BIG;
    #pragma unroll 4
    for (int it = 0; it < 64; ++it) {
        int j = lane + (it << 6);
        float4 p = pb[j];
        #pragma unroll
        for (int qq = 0; qq < KNQ; ++qq) {
            float dx = p.x - qv[qq].x, dy = p.y - qv[qq].y, dz = p.z - qv[qq].z;
            float dd = dx * dx + dy * dy + dz * dz;
            if (j != i0 + qq) dmin[qq] = fminf(dmin[qq], dd);
        }
    }
    float T[KNQ];
    #pragma unroll
    for (int qq = 0; qq < KNQ; ++qq) T[qq] = kth6min(dmin[qq]) * 1.000002f;

    // phase 2: compact hits (dd <= T) into LDS
    #pragma unroll 4
    for (int it = 0; it < 64; ++it) {
        int j = lane + (it << 6);
        float4 p = pb[j];
        #pragma unroll
        for (int qq = 0; qq < KNQ; ++qq) {
            float dx = p.x - qv[qq].x, dy = p.y - qv[qq].y, dz = p.z - qv[qq].z;
            float dd = dx * dx + dy * dy + dz * dz;
            if (dd <= T[qq] && j != i0 + qq) {
                int slot = atomicAdd(&sCnt[w][qq], 1);
                if (slot < KCAP)
                    sHits[w][qq][slot] = ((u64)__float_as_uint(dd) << 32) | (u32)j;
            }
        }
    }
    __syncthreads();

    // extraction: 16-lane group g handles query g; exact 6x min over hit list
    const int g = lane >> 4, li = lane & 15;
    const int cnt = sCnt[w][g];
    const int q = i0 + g;
    u64 ent[KCAP / 16];
    #pragma unroll
    for (int e = 0; e < KCAP / 16; ++e) {
        int slot = li + e * 16;
        ent[e] = (slot < (cnt < KCAP ? cnt : KCAP)) ? sHits[w][g][slot] : ~0ull;
    }
    int myj = -1;
    #pragma unroll
    for (int k = 0; k < 6; ++k) {
        u64 m = ent[0];
        #pragma unroll
        for (int e = 1; e < KCAP / 16; ++e) m = (ent[e] < m) ? ent[e] : m;
        #pragma unroll
        for (int off = 1; off < 16; off <<= 1) {
            u64 o = shflxor64(m, off);
            if (o < m) m = o;
        }
        if (li == k) myj = (int)(u32)(m & 0xffffffffull);
        #pragma unroll
        for (int e = 0; e < KCAP / 16; ++e) if (ent[e] == m) ent[e] = ~0ull;
    }
    if (cnt <= KCAP && li < 6) {
        size_t e = (size_t)(b * N_ + q) * 6 + li;
        idxv[e] = myj;
        geom_write(pb, q, myj, e, uv, rbfv);
    }

    // fallback for overflowed queries (exact per-lane insert; essentially never taken)
    u64 ovf = __ballot(li == 0 && cnt > KCAP);
    while (ovf) {
        int gl = __ffsll(ovf) - 1; ovf &= ovf - 1;
        int qq = gl >> 4;
        int qx = i0 + qq;
        float4 qp = pb[qx];
        float Tq = T[0];
        #pragma unroll
        for (int z = 1; z < KNQ; ++z) if (z == qq) Tq = T[z];
        float e0 = BIG, e1 = BIG, e2 = BIG, e3 = BIG, e4 = BIG, e5 = BIG;
        int j0 = 0, j1 = 0, j2 = 0, j3 = 0, j4 = 0, j5 = 0;
        for (int it = 0; it < 64; ++it) {
            int j = lane + (it << 6);
            float4 p = pb[j];
            float dx = p.x - qp.x, dy = p.y - qp.y, dz = p.z - qp.z;
            float dd = dx * dx + dy * dy + dz * dz;
            if (dd <= Tq && j != qx && dd < e5) {
                e5 = dd; j5 = j;
                float td; int tj;
                if (e5 < e4) { td = e4; e4 = e5; e5 = td; tj = j4; j4 = j5; j5 = tj; }
                if (e4 < e3) { td = e3; e3 = e4; e4 = td; tj = j3; j3 = j4; j4 = tj; }
                if (e3 < e2) { td = e2; e2 = e3; e3 = td; tj = j2; j2 = j3; j3 = tj; }
                if (e2 < e1) { td = e1; e1 = e2; e2 = td; tj = j1; j1 = j2; j2 = tj; }
                if (e1 < e0) { td = e0; e0 = e1; e1 = td; tj = j0; j0 = j1; j1 = tj; }
            }
        }
        u64 a0 = ((u64)__float_as_uint(e0) << 32) | (u32)j0;
        u64 a1 = ((u64)__float_as_uint(e1) << 32) | (u32)j1;
        u64 a2 = ((u64)__float_as_uint(e2) << 32) | (u32)j2;
        u64 a3 = ((u64)__float_as_uint(e3) << 32) | (u32)j3;
        u64 a4 = ((u64)__float_as_uint(e4) << 32) | (u32)j4;
        u64 a5 = ((u64)__float_as_uint(e5) << 32) | (u32)j5;
        int fj = -1;
        #pragma unroll
        for (int k = 0; k < 6; ++k) {
            u64 m = a0;
            #pragma unroll
            for (int off = 1; off < 64; off <<= 1) {
                u64 o = shflxor64(m, off);
                if (o < m) m = o;
            }
            if (a0 == m) { a0 = a1; a1 = a2; a2 = a3; a3 = a4; a4 = a5; a5 = ~0ull; }
            if (lane == k) fj = (int)(u32)(m & 0xffffffffull);
        }
        if (lane < 6) {
            size_t e = (size_t)(b * N_ + qx) * 6 + lane;
            idxv[e] = fj;
            geom_write(pb, qx, fj, e, uv, rbfv);
        }
    }
}

// ---------------- one-time weight prep (both layers): transposed bf16 + rwg/bias2 + WembT ----------------
__global__ void k_prepw(const float* __restrict__ Wq, const float* __restrict__ Wk,
                        const float* __restrict__ Wv, const float* __restrict__ gw,
                        const float* __restrict__ fw1, const float* __restrict__ gb_,
                        const float* __restrict__ fb1, const float* __restrict__ Wvv,
                        const float* __restrict__ Wov, const float* __restrict__ Wo_,
                        const float* __restrict__ fw2, const float* __restrict__ rw2,
                        const float* __restrict__ rb2, const float* __restrict__ W_embed,
                        u16* __restrict__ WqkvT, u16* __restrict__ Wc2T,
                        u16* __restrict__ WvvT, u16* __restrict__ WovT,
                        u16* __restrict__ WoT, u16* __restrict__ fw2T,
                        u16* __restrict__ WembT,
                        float* __restrict__ bias2, float* __restrict__ rwg)
{
    const int l = blockIdx.y;
    int g = blockIdx.x * 256 + threadIdx.x;
    const float* Wq_l = Wq + l * 16384;  const float* Wk_l = Wk + l * 16384;
    const float* Wv_l = Wv + l * 16384;  const float* gw_l = gw + l * 16384;
    const float* fw1_l = fw1 + l * 32768; const float* gb_l = gb_ + l * 128;
    const float* fb1_l = fb1 + l * 256;  const float* Wvv_l = Wvv + l * 16384;
    const float* Wov_l = Wov + l * 16384; const float* Wo_ll = Wo_ + l * 16384;
    const float* fw2_l = fw2 + l * 32768; const float* rw2_l = rw2 + l * 4096;
    const float* rb2_l = rb2 + l * 256;

    if (g < 49152) {
        int n = g >> 7, k = g & 127;
        const float* src = (n < 128) ? Wq_l : ((n < 256) ? Wk_l : Wv_l);
        WqkvT[l * 49152 + g] = f2bf(src[k * 128 + (n & 127)]); return;
    }
    g -= 49152;
    if (g < 49152) {
        int n = g >> 7, k = g & 127;
        Wc2T[l * 49152 + g] = f2bf((n < 128) ? gw_l[k * 128 + n] : fw1_l[k * 256 + (n - 128)]); return;
    }
    g -= 49152;
    if (g < 16384) { int n = g >> 7, k = g & 127; WvvT[l * 16384 + g] = f2bf(Wvv_l[k * 128 + n]); return; }
    g -= 16384;
    if (g < 16384) { int n = g >> 7, k = g & 127; WovT[l * 16384 + g] = f2bf(Wov_l[k * 128 + n]); return; }
    g -= 16384;
    if (g < 16384) { int n = g >> 7, k = g & 127; WoT[l * 16384 + g] = f2bf(Wo_ll[k * 128 + n]); return; }
    g -= 16384;
    if (g < 32768) { int n = g >> 8, k = g & 255; fw2T[l * 32768 + g] = f2bf(fw2_l[k * 128 + n]); return; }
    g -= 32768;
    if (g < 384) { bias2[l * 384 + g] = (g < 128) ? gb_l[g] : fb1_l[g - 128]; return; }
    g -= 384;
    if (g < 64) {
        int hh = g >> 2, h = g & 3;
        float a = 0.f;
        #pragma unroll
        for (int dh = 0; dh < 32; ++dh) a += rw2_l[hh * 256 + h * 32 + dh];
        rwg[l * 128 + g] = a * (1.f / 32.f); return;
    }
    g -= 64;
    if (g < 4) {
        float a = 0.f;
        #pragma unroll
        for (int dh = 0; dh < 32; ++dh) a += rb2_l[g * 32 + dh];
        rwg[l * 128 + 64 + g] = a * (1.f / 32.f); return;
    }
    g -= 4;
    if (g < 8192 && l == 0) {
        int n = g >> 6, k = g & 63;
        WembT[g] = f2bf(W_embed[k * 128 + n]);
    }
}

// ---------------- MFMA bf16 GEMM: 128x128 tile, 4 waves x (64x64) ----------------
// EPI 0: C=acc(+bias)  | EPI 1: C+=acc(+bias)
// EPI 2: split gate|ff1: n0==0 -> C=sigm fp32 ldc128 ; n0>0 -> Cb=bf16(silu) ldc256
// EPI 3: v=(X1ACC?C:0)+acc, v*=aux[(m/3)*128+col]; C=v; Cb=bf16(v)
// LN: after EPI 0/1 (n0==0, ldc==128): also write lnout = bf16(LN(v)) with lns/lnb
template<int KD, int EPI, bool LN, bool X1ACC>
__global__ __launch_bounds__(256) void k_mgemm(
    const u16* __restrict__ A, const u16* __restrict__ WT,
    const float* __restrict__ bias, const float* __restrict__ aux,
    float* __restrict__ C, u16* __restrict__ Cb, int ldc,
    const float* __restrict__ lns, const float* __restrict__ lnb,
    u16* __restrict__ lnout)
{
    __shared__ u16 sA[128 * 40];
    __shared__ u16 sB[128 * 40];
    const int tid = threadIdx.x;
    const int lane = tid & 63, wid = tid >> 6;
    const int wm = wid >> 1, wn = wid & 1;
    const int m0 = blockIdx.x * 128, n0 = blockIdx.y * 128;
    f32x4 acc[4][4] = {};

    for (int k0 = 0; k0 < KD; k0 += 32) {
        __syncthreads();
        #pragma unroll
        for (int cc = 0; cc < 2; ++cc) {
            int c = tid * 2 + cc;
            int row = c >> 2, gk = c & 3;
            uint4 va = *(const uint4*)&A[(size_t)(m0 + row) * KD + k0 + gk * 8];
            *(uint4*)&sA[row * 40 + gk * 8] = va;
            uint4 vb = *(const uint4*)&WT[(size_t)(n0 + row) * KD + k0 + gk * 8];
            *(uint4*)&sB[row * 40 + gk * 8] = vb;
        }
        __syncthreads();
        const int gk = lane >> 4, lr = lane & 15;
        short8 af[4], bfr[4];
        #pragma unroll
        for (int i = 0; i < 4; ++i) {
            af[i]  = *(const short8*)&sA[(wm * 64 + i * 16 + lr) * 40 + gk * 8];
            bfr[i] = *(const short8*)&sB[(wn * 64 + i * 16 + lr) * 40 + gk * 8];
        }
        #pragma unroll
        for (int mi = 0; mi < 4; ++mi)
            #pragma unroll
            for (int ni = 0; ni < 4; ++ni)
                acc[mi][ni] = __builtin_amdgcn_mfma_f32_16x16x32_bf16(af[mi], bfr[ni], acc[mi][ni], 0, 0, 0);
    }

    const int lg = lane >> 4;         // 0..3 row-group
    const int lc = lane & 15;         // col within 16
    if (LN) {
        __shared__ float sLN[2][64][2][2];
        float s1[4][4], s2[4][4];
        #pragma unroll
        for (int mi = 0; mi < 4; ++mi) {
            int rbase = m0 + wm * 64 + mi * 16 + lg * 4;
            #pragma unroll
            for (int ee = 0; ee < 4; ++ee) { s1[mi][ee] = 0.f; s2[mi][ee] = 0.f; }
            #pragma unroll
            for (int ni = 0; ni < 4; ++ni) {
                int col = wn * 64 + ni * 16 + lc;
                float bc = bias ? bias[col] : 0.f;
                #pragma unroll
                for (int ee = 0; ee < 4; ++ee) {
                    float v = acc[mi][ni][ee] + bc;
                    if (EPI == 1) v += C[(size_t)(rbase + ee) * 128 + col];
                    acc[mi][ni][ee] = v;
                    s1[mi][ee] += v;
                    s2[mi][ee] += v * v;
                }
            }
        }
        #pragma unroll
        for (int mi = 0; mi < 4; ++mi)
            #pragma unroll
            for (int ee = 0; ee < 4; ++ee)
                #pragma unroll
                for (int off = 1; off < 16; off <<= 1) {
                    s1[mi][ee] += __shfl_xor(s1[mi][ee], off, 64);
                    s2[mi][ee] += __shfl_xor(s2[mi][ee], off, 64);
                }
        if (lc == 0) {
            #pragma unroll
            for (int mi = 0; mi < 4; ++mi)
                #pragma unroll
                for (int ee = 0; ee < 4; ++ee) {
                    int r = mi * 16 + lg * 4 + ee;
                    sLN[wm][r][wn][0] = s1[mi][ee];
                    sLN[wm][r][wn][1] = s2[mi][ee];
                }
        }
        __syncthreads();
        #pragma unroll
        for (int mi = 0; mi < 4; ++mi) {
            int rbase = m0 + wm * 64 + mi * 16 + lg * 4;
            #pragma unroll
            for (int ee = 0; ee < 4; ++ee) {
                int r = mi * 16 + lg * 4 + ee;
                float sum = s1[mi][ee] + sLN[wm][r][wn ^ 1][0];
                float sq  = s2[mi][ee] + sLN[wm][r][wn ^ 1][1];
                float mean = sum * (1.f / 128.f);
                float var = sq * (1.f / 128.f) - mean * mean;
                float inv = 1.f / sqrtf(var + 1e-5f);
                #pragma unroll
                for (int ni = 0; ni < 4; ++ni) {
                    int col = wn * 64 + ni * 16 + lc;
                    float v = acc[mi][ni][ee];
                    size_t o = (size_t)(rbase + ee) * 128 + col;
                    C[o] = v;
                    lnout[o] = f2bf((v - mean) * inv * lns[col] + lnb[col]);
                }
            }
        }
        return;
    }

    const int lr4 = lg * 4;
    #pragma unroll
    for (int mi = 0; mi < 4; ++mi) {
        int rbase = m0 + wm * 64 + mi * 16 + lr4;
        #pragma unroll
        for (int ni = 0; ni < 4; ++ni) {
            int col = n0 + wn * 64 + ni * 16 + lc;
            if (EPI == 0) {
                float bc = bias ? bias[col] : 0.f;
                #pragma unroll
                for (int ee = 0; ee < 4; ++ee)
                    C[(size_t)(rbase + ee) * ldc + col] = acc[mi][ni][ee] + bc;
            } else if (EPI == 1) {
                float bc = bias ? bias[col] : 0.f;
                #pragma unroll
                for (int ee = 0; ee < 4; ++ee) {
                    size_t o = (size_t)(rbase + ee) * ldc + col;
                    C[o] += acc[mi][ni][ee] + bc;
                }
            } else if (EPI == 2) {
                float bc = bias[col];
                if (n0 == 0) {
                    #pragma unroll
                    for (int ee = 0; ee < 4; ++ee)
                        C[(size_t)(rbase + ee) * 128 + col] = sigm(acc[mi][ni][ee] + bc);
                } else {
                    int c2 = col - 128;
                    #pragma unroll
                    for (int ee = 0; ee < 4; ++ee)
                        Cb[(size_t)(rbase + ee) * 256 + c2] = f2bf(silu(acc[mi][ni][ee] + bc));
                }
            } else {
                #pragma unroll
                for (int ee = 0; ee < 4; ++ee) {
                    int m = rbase + ee;
                    size_t o = (size_t)m * 128 + col;
                    float v = acc[mi][ni][ee];
                    if (X1ACC) v += C[o];
                    v *= aux[(size_t)(m / 3) * 128 + col];
                    C[o] = v;
                    Cb[o] = f2bf(v);
                }
            }
        }
    }
}

// ---------------- fp32 tiled GEMM (state head only) ----------------
template<int KD>
__global__ __launch_bounds__(256) void k_tgemm(
    const float* __restrict__ A, const float* __restrict__ W, const float* __restrict__ bias,
    float* __restrict__ C, int ldw, int ldc)
{
    __shared__ __align__(16) float As[32 * 132];
    __shared__ __align__(16) float Ws[32 * 68];
    const int tid = threadIdx.x;
    const int tx = tid & 15, ty = tid >> 4;
    const int m0 = blockIdx.x * 128, n0 = blockIdx.y * 64;
    float acc[8][4] = {};
    for (int k0 = 0; k0 < KD; k0 += 32) {
        __syncthreads();
        #pragma unroll
        for (int r = 0; r < 4; ++r) {
            int id = tid + r * 256;
            int row = id >> 3, kq = id & 7;
            float4 a4 = *(const float4*)&A[(size_t)(m0 + row) * KD + k0 + kq * 4];
            As[(kq * 4 + 0) * 132 + row] = a4.x;
            As[(kq * 4 + 1) * 132 + row] = a4.y;
            As[(kq * 4 + 2) * 132 + row] = a4.z;
            As[(kq * 4 + 3) * 132 + row] = a4.w;
        }
        #pragma unroll
        for (int r = 0; r < 2; ++r) {
            int id = tid + r * 256;
            int kr = id >> 4, cq = id & 15;
            *(float4*)&Ws[kr * 68 + cq * 4] =
                *(const float4*)&W[(size_t)(k0 + kr) * ldw + n0 + cq * 4];
        }
        __syncthreads();
        #pragma unroll 8
        for (int k = 0; k < 32; ++k) {
            float4 aA = *(const float4*)&As[k * 132 + ty * 8];
            float4 aB = *(const float4*)&As[k * 132 + ty * 8 + 4];
            float4 w4 = *(const float4*)&Ws[k * 68 + tx * 4];
            float av[8] = {aA.x, aA.y, aA.z, aA.w, aB.x, aB.y, aB.z, aB.w};
            float wv[4] = {w4.x, w4.y, w4.z, w4.w};
            #pragma unroll
            for (int r = 0; r < 8; ++r)
                #pragma unroll
                for (int j = 0; j < 4; ++j)
                    acc[r][j] += av[r] * wv[j];
        }
    }
    float bv[4];
    #pragma unroll
    for (int j = 0; j < 4; ++j) bv[j] = bias[n0 + tx * 4 + j];
    #pragma unroll
    for (int r = 0; r < 8; ++r) {
        int m = m0 + ty * 8 + r;
        int n = m & (N_ - 1), bb2 = m >> 12;
        if (n == 0) continue;
        float* dst = C + ((size_t)(bb2 * NC_ + n - 1)) * ldc + n0 + tx * 4;
        float4 res = {acc[r][0] + bv[0], acc[r][1] + bv[1], acc[r][2] + bv[2], acc[r][3] + bv[3]};
        *(float4*)dst = res;
    }
}

// ---------------- fused attention (y1-hoisted, 2 rows/block, bf16 outs) ----------------
template<bool HASY1>
__global__ __launch_bounds__(256) void k_attn(
    const float* __restrict__ qkvb, const int* __restrict__ idxv,
    const float* __restrict__ rbfv, const float* __restrict__ uv,
    const float* __restrict__ y1,
    const float* __restrict__ rw1, const float* __restrict__ rb1,
    const float* __restrict__ rw2, const float* __restrict__ rwg,
    const float* __restrict__ rb2,
    u16* __restrict__ o0b, u16* __restrict__ o1b)
{
    const int tid = threadIdx.x;
    const int r = tid >> 7, t = tid & 127;
    const int row = blockIdx.x * 2 + r;
    const int b = row >> 12;

    __shared__ float sQ[2][128];
    __shared__ float sHid[2][6][16];
    __shared__ float sU[2][6][3];
    __shared__ float sLog[2][4][6];
    __shared__ float sAttn[2][4][6];
    __shared__ int sJ[2][6];

    sQ[r][t] = qkvb[(size_t)row * 384 + t];
    if (t < 6) sJ[r][t] = idxv[row * 6 + t];
    if (t >= 8 && t < 26) { int i = t - 8; sU[r][i / 3][i % 3] = uv[(size_t)row * 18 + i]; }
    if (t >= 32) {
        int k = (t - 32) >> 4, hh = (t - 32) & 15;
        float a = rb1[hh];
        const float* rb = rbfv + (size_t)(row * 6 + k) * 16;
        #pragma unroll
        for (int rr = 0; rr < 16; ++rr) a += rb[rr] * rw1[rr * 16 + hh];
        sHid[r][k][hh] = silu(a);
    }
    __syncthreads();

    if (t < 96) {
        int g = t >> 2, o = t & 3;
        int h = g / 6, k = g - h * 6;
        const float* kp = qkvb + (size_t)(b * N_ + sJ[r][k]) * 384 + 128 + h * 32 + o * 8;
        float4 qa = *(const float4*)&sQ[r][h * 32 + o * 8];
        float4 qb4 = *(const float4*)&sQ[r][h * 32 + o * 8 + 4];
        float4 ka = *(const float4*)kp;
        float4 kb4 = *(const float4*)(kp + 4);
        float p = qa.x * ka.x + qa.y * ka.y + qa.z * ka.z + qa.w * ka.w
                + qb4.x * kb4.x + qb4.y * kb4.y + qb4.z * kb4.z + qb4.w * kb4.w;
        p += __shfl_down(p, 2, 4);
        p += __shfl_down(p, 1, 4);
        if (o == 0) {
            float bias = rwg[64 + h];
            #pragma unroll
            for (int hh = 0; hh < 16; ++hh) bias += sHid[r][k][hh] * rwg[hh * 4 + h];
            sLog[r][h][k] = p * 0.17677669529663687f + bias;
        }
    }
    float rw2c[16];
    #pragma unroll
    for (int hh = 0; hh < 16; ++hh) rw2c[hh] = rw2[hh * 256 + 128 + t];
    float rvk[6], vj[6], y1j[6][3];
    float rb2t = rb2[128 + t];
    #pragma unroll
    for (int k = 0; k < 6; ++k) {
        float a = rb2t;
        #pragma unroll
        for (int hh = 0; hh < 16; ++hh) a += sHid[r][k][hh] * rw2c[hh];
        rvk[k] = a;
        size_t nb = (size_t)(b * N_ + sJ[r][k]);
        vj[k] = qkvb[nb * 384 + 256 + t];
        if (HASY1) {
            #pragma unroll
            for (int c = 0; c < 3; ++c) y1j[k][c] = y1[nb * 384 + c * 128 + t];
        }
    }
    __syncthreads();

    if (t < 4) {
        int h = t;
        float mx = sLog[r][h][0];
        #pragma unroll
        for (int k = 1; k < 6; ++k) mx = fmaxf(mx, sLog[r][h][k]);
        float ex[6], smv = 0.f;
        #pragma unroll
        for (int k = 0; k < 6; ++k) { ex[k] = expf(sLog[r][h][k] - mx); smv += ex[k]; }
        float inv = 1.f / smv;
        #pragma unroll
        for (int k = 0; k < 6; ++k) sAttn[r][h][k] = ex[k] * inv;
    }
    __syncthreads();

    int h = t >> 5;
    float a[6];
    #pragma unroll
    for (int k = 0; k < 6; ++k) a[k] = sAttn[r][h][k];
    float o0v = 0.f;
    #pragma unroll
    for (int k = 0; k < 6; ++k) o0v += a[k] * vj[k] * silu(rvk[k]);
    o0b[(size_t)row * 128 + t] = f2bf(o0v);
    #pragma unroll
    for (int c = 0; c < 3; ++c) {
        float s = 0.f;
        #pragma unroll
        for (int k = 0; k < 6; ++k) {
            float base = HASY1 ? y1j[k][c] : 0.f;
            s += a[k] * (base + rvk[k] * sU[r][k][c]);
        }
        o1b[(size_t)(row * 3 + c) * 128 + t] = f2bf(s);
    }
}

// ---------------- force head ----------------
__global__ void k_force1(const float* __restrict__ x1, const float* __restrict__ W,
                         const float* __restrict__ bias, float* __restrict__ frc)
{
    int g = blockIdx.x * 256 + threadIdx.x;
    if (g >= B_ * NC_ * 3) return;
    int c = g % 3, rr = g / 3;
    int b = rr / NC_, n = rr - b * NC_;
    const float* xr = x1 + (size_t)(b * N_ + n + 1) * 384 + c * 128;
    float a = bias[0];
    for (int d = 0; d < 128; ++d) a += xr[d] * W[d];
    frc[g] = a;
}

__global__ __launch_bounds__(256) void k_fsum(const float* __restrict__ frc, float* __restrict__ fsum)
{
    int b = blockIdx.x / 3, c = blockIdx.x % 3;
    __shared__ float red[256];
    float a = 0.f;
    for (int n = threadIdx.x; n < NC_; n += 256) a += frc[(b * NC_ + n) * 3 + c];
    red[threadIdx.x] = a; __syncthreads();
    for (int st = 128; st > 0; st >>= 1) { if (threadIdx.x < st) red[threadIdx.x] += red[threadIdx.x + st]; __syncthreads(); }
    if (threadIdx.x == 0) fsum[blockIdx.x] = red[0] / (float)NC_;
}

__global__ void k_force2(const float* __restrict__ frc, const float* __restrict__ fsum,
                         float* __restrict__ out)
{
    int g = blockIdx.x * 256 + threadIdx.x;
    if (g >= B_ * NC_ * 3) return;
    int c = g % 3;
    int b = g / (NC_ * 3);
    out[g] = frc[g] - fsum[b * 3 + c];
}

} // namespace

extern "C" void kernel_launch(void* const* d_in, const int* in_sizes, int n_in,
                              void* d_out, int out_size, void* d_ws, size_t ws_size,
                              hipStream_t stream)
{
    const float* X       = (const float*)d_in[0];
    const float* W_embed = (const float*)d_in[1];
    const float* b_embed = (const float*)d_in[2];
    const float* Wq      = (const float*)d_in[3];
    const float* Wk      = (const float*)d_in[4];
    const float* Wv      = (const float*)d_in[5];
    const float* Wvv     = (const float*)d_in[6];
    const float* rw1     = (const float*)d_in[7];
    const float* rb1     = (const float*)d_in[8];
    const float* rw2     = (const float*)d_in[9];
    const float* rb2     = (const float*)d_in[10];
    const float* Wo      = (const float*)d_in[11];
    const float* Wov     = (const float*)d_in[12];
    const float* ff_w1   = (const float*)d_in[13];
    const float* ff_b1   = (const float*)d_in[14];
    const float* ff_w2   = (const float*)d_in[15];
    const float* ff_b2   = (const float*)d_in[16];
    const float* gate_w  = (const float*)d_in[17];
    const float* gate_b  = (const float*)d_in[18];
    const float* ln1_s   = (const float*)d_in[19];
    const float* ln1_b   = (const float*)d_in[20];
    const float* ln2_s   = (const float*)d_in[21];
    const float* ln2_b   = (const float*)d_in[22];
    const float* W_state = (const float*)d_in[23];
    const float* b_state = (const float*)d_in[24];
    const float* W_force = (const float*)d_in[25];
    const float* b_force = (const float*)d_in[26];
    (void)in_sizes; (void)n_in; (void)out_size; (void)ws_size;

    float* out = (float*)d_out;
    float* w = (float*)d_ws;

    float4* pos4  = (float4*)w;                    // -> 65536
    int*    idxv  = (int*)(w + 65536);             // -> 163840
    float*  uv    = w + 163840;                    // -> 458752
    float*  rbfv  = w + 458752;                    // -> 2031616
    u16*    featsb= (u16*)(w + 2031616);           // -> 2555904 (frc/fsum alias later)
    float*  x0    = w + 2555904;                   // -> 4653056
    u16*    hbb   = (u16*)(w + 4653056);           // -> 5701632
    float*  qkvb  = w + 5701632;                   // -> 11993088
    float*  gb    = w + 11993088;                  // -> 14090240
    u16*    o0b   = (u16*)(w + 14090240);          // -> 15138816
    u16*    o1b   = (u16*)(w + 15138816);          // -> 18284544
    float*  x1    = w + 18284544;                  // -> 24576000
    u16*    x1b   = (u16*)(w + 24576000);          // -> 27721728
    float*  y1    = w + 27721728;                  // -> 34013184 (t1b alias)
    u16*    t1b   = (u16*)y1;
    u16*    WqkvT = (u16*)(w + 34013184);
    u16*    Wc2T  = (u16*)(w + 34062336);
    u16*    WvvT  = (u16*)(w + 34111488);
    u16*    WovT  = (u16*)(w + 34127872);
    u16*    WoT   = (u16*)(w + 34144256);
    u16*    fw2T  = (u16*)(w + 34160640);
    u16*    WembT = (u16*)(w + 34193408);
    float*  bias2 = w + 34197504;
    float*  rwg   = w + 34198272;
    float*  frc   = (float*)featsb;
    float*  fsum  = ((float*)featsb) + 49152;

    // one-time prep (both layers) + inputs
    k_prepw<<<dim3(738, 2), 256, 0, stream>>>(Wq, Wk, Wv, gate_w, ff_w1, gate_b, ff_b1,
                                              Wvv, Wov, Wo, ff_w2, rw2, rb2, W_embed,
                                              WqkvT, Wc2T, WvvT, WovT, WoT, fw2T, WembT,
                                              bias2, rwg);
    k_prep<<<(ROWS_ * 64 + 255) / 256, 256, 0, stream>>>(X, pos4, featsb);
    k_knn<<<ROWS_ / 16, 256, 0, stream>>>(pos4, idxv, uv, rbfv);
    // x0 = feats @ W_embed + b_embed ; hbb = LN1(x0)
    k_mgemm<64, 0, true, true><<<dim3(128, 1), 256, 0, stream>>>(
        featsb, WembT, b_embed, nullptr, x0, nullptr, 128, ln1_s, ln1_b, hbb);

    for (int l = 0; l < 2; ++l) {
        const float* rw1_l = rw1 + l * 256;
        const float* rb1_l = rb1 + l * 16;
        const float* rw2_l = rw2 + l * 4096;
        const float* rb2_l = rb2 + l * 256;
        const float* fb2_l = ff_b2 + l * 128;

        // qkv = h @ Wqkv (fp32 out)
        k_mgemm<128, 0, false, true><<<dim3(128, 3), 256, 0, stream>>>(
            hbb, WqkvT + l * 49152, nullptr, nullptr, qkvb, nullptr, 384, nullptr, nullptr, nullptr);
        // y1 = x1 @ Wvv (layer 1 only)
        if (l > 0)
            k_mgemm<128, 0, false, true><<<dim3(384, 1), 256, 0, stream>>>(
                x1b, WvvT + l * 16384, nullptr, nullptr, y1, nullptr, 128, nullptr, nullptr, nullptr);
        // attention
        if (l == 0)
            k_attn<false><<<ROWS_ / 2, 256, 0, stream>>>(qkvb, idxv, rbfv, uv, nullptr,
                rw1_l, rb1_l, rw2_l, rwg + l * 128, rb2_l, o0b, o1b);
        else
            k_attn<true><<<ROWS_ / 2, 256, 0, stream>>>(qkvb, idxv, rbfv, uv, y1,
                rw1_l, rb1_l, rw2_l, rwg + l * 128, rb2_l, o0b, o1b);
        // x0 += o0 @ Wo ; hbb = LN2(x0)
        k_mgemm<128, 1, true, true><<<dim3(128, 1), 256, 0, stream>>>(
            o0b, WoT + l * 16384, nullptr, nullptr, x0, nullptr, 128,
            ln2_s + l * 128, ln2_b + l * 128, hbb);
        // [gate fp32 | t1 bf16] = h2 @ [gate_w|ff_w1]
        k_mgemm<128, 2, false, true><<<dim3(128, 3), 256, 0, stream>>>(
            hbb, Wc2T + l * 49152, bias2 + l * 384, nullptr, gb, t1b, 128, nullptr, nullptr, nullptr);
        // x1 = ((l? x1:0) + o1 @ Wov) * gate ; x1b = bf16(x1)
        if (l == 0)
            k_mgemm<128, 3, false, false><<<dim3(384, 1), 256, 0, stream>>>(
                o1b, WovT + l * 16384, nullptr, gb, x1, x1b, 128, nullptr, nullptr, nullptr);
        else
            k_mgemm<128, 3, false, true><<<dim3(384, 1), 256, 0, stream>>>(
                o1b, WovT + l * 16384, nullptr, gb, x1, x1b, 128, nullptr, nullptr, nullptr);
        // x0 += t1 @ ff_w2 + fb2 ; (l==0: hbb = LN1_{l+1}(x0))
        if (l == 0)
            k_mgemm<256, 1, true, true><<<dim3(128, 1), 256, 0, stream>>>(
                t1b, fw2T + l * 32768, fb2_l, nullptr, x0, nullptr, 128,
                ln1_s + 128, ln1_b + 128, hbb);
        else
            k_mgemm<256, 1, false, true><<<dim3(128, 1), 256, 0, stream>>>(
                t1b, fw2T + l * 32768, fb2_l, nullptr, x0, nullptr, 128, nullptr, nullptr, nullptr);
    }

    // state head -> out (row-remapped)
    k_tgemm<128><<<dim3(128, 1), 256, 0, stream>>>(x0, W_state, b_state, out, 64, 64);
    // force head
    k_force1<<<(B_ * NC_ * 3 + 255) / 256, 256, 0, stream>>>(x1, W_force, b_force, frc);
    k_fsum<<<12, 256, 0, stream>>>(frc, fsum);
    k_force2<<<(B_ * NC_ * 3 + 255) / 256, 256, 0, stream>>>(frc, fsum, out + (size_t)B_ * NC_ * DIN_);
}